// Round 1
// baseline (7233.634 us; speedup 1.0000x reference)
//
#include <hip/hip_runtime.h>
#include <hip/hip_bf16.h>

#define T 4096
#define BT (16*4096)
#define NL 20

typedef __bf16 bf16;
typedef __bf16 v8bf __attribute__((ext_vector_type(8)));
typedef float v4f __attribute__((ext_vector_type(4)));

#define MFMA(a,b,c) __builtin_amdgcn_mfma_f32_16x16x32_bf16((a),(b),(c),0,0,0)

// ---------------- prep kernels: cast weights to bf16 ----------------
__global__ void prep_w2(const float* __restrict__ Wf, const float* __restrict__ Wg,
                        bf16* __restrict__ wf0, bf16* __restrict__ wf1,
                        bf16* __restrict__ wg0, bf16* __restrict__ wg1) {
    int idx = blockIdx.x * 256 + threadIdx.x;       // NL*256*256
    const float* pf = Wf + (size_t)idx * 2;
    wf0[idx] = (bf16)pf[0]; wf1[idx] = (bf16)pf[1];
    const float* pg = Wg + (size_t)idx * 2;
    wg0[idx] = (bf16)pg[0]; wg1[idx] = (bf16)pg[1];
}

__global__ void prep_w1(const float* __restrict__ Wr, const float* __restrict__ Ws,
                        bf16* __restrict__ wr, bf16* __restrict__ ws) {
    int idx = blockIdx.x * 256 + threadIdx.x;       // NL*256*256
    wr[idx] = (bf16)Wr[idx]; ws[idx] = (bf16)Ws[idx];
}

__global__ void prep_misc(const float* __restrict__ x, const float* __restrict__ W_in,
                          const float* __restrict__ W1, const float* __restrict__ W2,
                          bf16* __restrict__ xb, bf16* __restrict__ winb,
                          bf16* __restrict__ w1b, bf16* __restrict__ w2b) {
    int idx = blockIdx.x * 256 + threadIdx.x;       // 983040 total
    if (idx < 524288) {
        xb[idx] = (bf16)x[idx];
    } else if (idx < 589824) {
        int j = idx - 524288;                       // winb[c][k*8+ci] = W_in[c][ci][k]
        int c = j >> 8, jj = j & 255, k = jj >> 3, ci = jj & 7;
        winb[j] = (bf16)W_in[c * 256 + ci * 32 + k];
    } else if (idx < 851968) {
        int j = idx - 589824; w1b[j] = (bf16)W1[j];
    } else {
        int j = idx - 851968; w2b[j] = (bf16)W2[j];
    }
}

// ---------------- RMSNorm kernels (wave per token) ----------------
__global__ void rms_kernel(const float* __restrict__ z, bf16* __restrict__ zn,
                           const float* __restrict__ w) {
    int gw = (blockIdx.x * blockDim.x + threadIdx.x) >> 6;
    int lane = threadIdx.x & 63;
    float4 v = ((const float4*)(z + (size_t)gw * 256))[lane];
    float ss = v.x*v.x + v.y*v.y + v.z*v.z + v.w*v.w;
    for (int off = 32; off > 0; off >>= 1) ss += __shfl_xor(ss, off);
    float inv = rsqrtf(ss * (1.f/256.f) + 1e-6f);
    float4 wv = ((const float4*)w)[lane];
    bf16 o[4] = {(bf16)(v.x*inv*wv.x), (bf16)(v.y*inv*wv.y),
                 (bf16)(v.z*inv*wv.z), (bf16)(v.w*inv*wv.w)};
    *(uint2*)(zn + (size_t)gw * 256 + lane * 4) = *(uint2*)o;
}

__global__ void head_norm_kernel(const float* __restrict__ s, bf16* __restrict__ on,
                                 const float* __restrict__ w) {
    int gw = (blockIdx.x * blockDim.x + threadIdx.x) >> 6;
    int lane = threadIdx.x & 63;
    float4 v = ((const float4*)(s + (size_t)gw * 256))[lane];
    v.x = fmaxf(v.x, 0.f); v.y = fmaxf(v.y, 0.f); v.z = fmaxf(v.z, 0.f); v.w = fmaxf(v.w, 0.f);
    float ss = v.x*v.x + v.y*v.y + v.z*v.z + v.w*v.w;
    for (int off = 32; off > 0; off >>= 1) ss += __shfl_xor(ss, off);
    float inv = rsqrtf(ss * (1.f/256.f) + 1e-6f);
    float4 wv = ((const float4*)w)[lane];
    bf16 o[4] = {(bf16)(v.x*inv*wv.x), (bf16)(v.y*inv*wv.y),
                 (bf16)(v.z*inv*wv.z), (bf16)(v.w*inv*wv.w)};
    *(uint2*)(on + (size_t)gw * 256 + lane * 4) = *(uint2*)o;
}

// swizzled LDS addressing: row stride 512B, XOR row-bits into 16B-slot bits (G4)
__device__ __forceinline__ int swz(int row, int bytecol) {
    return (row * 512 + bytecol) ^ ((row & 7) << 4);
}

// ---------------- input conv as GEMM (A rows = sliding 256-elem windows of x) -------
__global__ __launch_bounds__(256, 2) void in_conv_kernel(
    const bf16* __restrict__ xb, const bf16* __restrict__ winb,
    const float* __restrict__ b_in, float* __restrict__ z) {
    __shared__ uint4 sA[2048];
    char* cA = (char*)sA;
    const int tid = threadIdx.x;
    const int g0 = blockIdx.x * 64;
    const int tl0 = g0 & (T - 1);
    for (int i = 0; i < 8; ++i) {
        int ch = tid + i * 256;
        int r = ch >> 5, c16 = ch & 31;
        uint4 v = make_uint4(0, 0, 0, 0);
        if (tl0 + r - 31 + c16 >= 0)
            v = ((const uint4*)(xb + (size_t)(g0 + r - 31 + c16) * 8))[0];
        *(uint4*)(cA + swz(r, c16 * 16)) = v;
    }
    __syncthreads();
    const int lane = tid & 63, w = tid >> 6;
    const int wm = w >> 1, wn = w & 1;
    const int l15 = lane & 15, l4 = lane >> 4;
    v4f acc[2][8] = {};
    for (int ks = 0; ks < 8; ++ks) {
        v8bf a[2];
        for (int m = 0; m < 2; ++m) {
            int row = wm * 32 + m * 16 + l15;
            a[m] = *(const v8bf*)(cA + swz(row, ks * 64 + l4 * 16));
        }
        for (int nf = 0; nf < 8; ++nf) {
            int n = wn * 128 + nf * 16 + l15;
            v8bf b = *(const v8bf*)(winb + (size_t)n * 256 + ks * 32 + l4 * 8);
            for (int m = 0; m < 2; ++m) acc[m][nf] = MFMA(a[m], b, acc[m][nf]);
        }
    }
    for (int m = 0; m < 2; ++m)
        for (int nf = 0; nf < 8; ++nf) {
            int col = wn * 128 + nf * 16 + l15;
            float bv = b_in[col];
            for (int j = 0; j < 4; ++j) {
                int row = wm * 32 + m * 16 + l4 * 4 + j;
                z[(size_t)(g0 + row) * 256 + col] = acc[m][nf][j] + bv;
            }
        }
}

// ---------------- fused gated-residual layer ----------------
__global__ __launch_bounds__(256, 2) void layer_kernel(
    const bf16* __restrict__ zn, float* __restrict__ z, float* __restrict__ sum,
    const bf16* __restrict__ wf0, const bf16* __restrict__ wf1,
    const bf16* __restrict__ wg0, const bf16* __restrict__ wg1,
    const bf16* __restrict__ wr, const bf16* __restrict__ wsm,
    const float* __restrict__ bfp, const float* __restrict__ bgp,
    const float* __restrict__ brp, const float* __restrict__ bsp, int dil) {
    __shared__ uint4 sA0[2048];   // zn[t-d] tile; reused as U tile
    __shared__ uint4 sA1[2048];   // zn[t] tile
    char* cA0 = (char*)sA0; char* cA1 = (char*)sA1;
    const int tid = threadIdx.x;
    const int g0 = blockIdx.x * 64;
    const int tl0 = g0 & (T - 1);
    for (int i = 0; i < 8; ++i) {
        int ch = tid + i * 256;
        int r = ch >> 5, c16 = ch & 31;
        int dst = swz(r, c16 * 16);
        *(uint4*)(cA1 + dst) = ((const uint4*)(zn + (size_t)(g0 + r) * 256))[c16];
        uint4 v = make_uint4(0, 0, 0, 0);
        if (tl0 + r - dil >= 0)
            v = ((const uint4*)(zn + (size_t)(g0 + r - dil) * 256))[c16];
        *(uint4*)(cA0 + dst) = v;
    }
    __syncthreads();
    const int lane = tid & 63, w = tid >> 6;
    const int wm = w >> 1, wn = w & 1;
    const int l15 = lane & 15, l4 = lane >> 4;

    v4f accf[2][8] = {}, accg[2][8] = {};
    for (int ks = 0; ks < 8; ++ks) {
        v8bf a0[2], a1[2];
        for (int m = 0; m < 2; ++m) {
            int row = wm * 32 + m * 16 + l15;
            int off = swz(row, ks * 64 + l4 * 16);
            a0[m] = *(const v8bf*)(cA0 + off);
            a1[m] = *(const v8bf*)(cA1 + off);
        }
        for (int nf = 0; nf < 8; ++nf) {
            int n = wn * 128 + nf * 16 + l15;
            size_t bo = (size_t)n * 256 + ks * 32 + l4 * 8;
            v8bf b0 = *(const v8bf*)(wf0 + bo);
            v8bf b1 = *(const v8bf*)(wf1 + bo);
            v8bf b2 = *(const v8bf*)(wg0 + bo);
            v8bf b3 = *(const v8bf*)(wg1 + bo);
            for (int m = 0; m < 2; ++m) {
                accf[m][nf] = MFMA(a0[m], b0, accf[m][nf]);
                accf[m][nf] = MFMA(a1[m], b1, accf[m][nf]);
                accg[m][nf] = MFMA(a0[m], b2, accg[m][nf]);
                accg[m][nf] = MFMA(a1[m], b3, accg[m][nf]);
            }
        }
    }
    __syncthreads();   // all LDS reads done before overwriting sA0 with U
    for (int m = 0; m < 2; ++m)
        for (int nf = 0; nf < 8; ++nf) {
            int col = wn * 128 + nf * 16 + l15;
            float bfv = bfp[col], bgv = bgp[col];
            for (int j = 0; j < 4; ++j) {
                int row = wm * 32 + m * 16 + l4 * 4 + j;
                float fv = accf[m][nf][j] + bfv;
                float gv = accg[m][nf][j] + bgv;
                float u = tanhf(fv) * (1.f / (1.f + __expf(-gv)));
                *(bf16*)(cA0 + swz(row, col * 2)) = (bf16)u;
            }
        }
    __syncthreads();
    v4f accr[2][8] = {}, accs[2][8] = {};
    for (int ks = 0; ks < 8; ++ks) {
        v8bf a[2];
        for (int m = 0; m < 2; ++m) {
            int row = wm * 32 + m * 16 + l15;
            a[m] = *(const v8bf*)(cA0 + swz(row, ks * 64 + l4 * 16));
        }
        for (int nf = 0; nf < 8; ++nf) {
            int n = wn * 128 + nf * 16 + l15;
            size_t bo = (size_t)n * 256 + ks * 32 + l4 * 8;
            v8bf b0 = *(const v8bf*)(wr + bo);
            v8bf b1 = *(const v8bf*)(wsm + bo);
            for (int m = 0; m < 2; ++m) {
                accr[m][nf] = MFMA(a[m], b0, accr[m][nf]);
                accs[m][nf] = MFMA(a[m], b1, accs[m][nf]);
            }
        }
    }
    for (int m = 0; m < 2; ++m)
        for (int nf = 0; nf < 8; ++nf) {
            int col = wn * 128 + nf * 16 + l15;
            float brv = brp[col], bsv = bsp[col];
            for (int j = 0; j < 4; ++j) {
                int row = wm * 32 + m * 16 + l4 * 4 + j;
                size_t idx = (size_t)(g0 + row) * 256 + col;
                z[idx] += accr[m][nf][j] + brv;
                sum[idx] += accs[m][nf][j] + bsv;
            }
        }
}

// ---------------- fused head: on @ W1 -> relu -> @ W2 ----------------
__global__ __launch_bounds__(256, 2) void head_kernel(
    const bf16* __restrict__ on, const bf16* __restrict__ w1b, const float* __restrict__ b1,
    const bf16* __restrict__ w2b, const float* __restrict__ b2, float* __restrict__ out) {
    __shared__ uint4 sOn[2048];
    __shared__ uint4 sH[2048];
    char* cOn = (char*)sOn; char* cH = (char*)sH;
    const int tid = threadIdx.x;
    const int g0 = blockIdx.x * 64;
    for (int i = 0; i < 8; ++i) {
        int ch = tid + i * 256;
        int r = ch >> 5, c16 = ch & 31;
        *(uint4*)(cOn + swz(r, c16 * 16)) = ((const uint4*)(on + (size_t)(g0 + r) * 256))[c16];
    }
    __syncthreads();
    const int lane = tid & 63, w = tid >> 6;
    const int wm = w >> 1, wn = w & 1;
    const int l15 = lane & 15, l4 = lane >> 4;
    v4f acc2[2][4] = {};
    for (int hc = 0; hc < 4; ++hc) {
        v4f acch[2][8] = {};
        for (int ks = 0; ks < 8; ++ks) {
            v8bf a[2];
            for (int m = 0; m < 2; ++m) {
                int row = wm * 32 + m * 16 + l15;
                a[m] = *(const v8bf*)(cOn + swz(row, ks * 64 + l4 * 16));
            }
            for (int nf = 0; nf < 8; ++nf) {
                int h = hc * 256 + wn * 128 + nf * 16 + l15;
                v8bf b = *(const v8bf*)(w1b + (size_t)h * 256 + ks * 32 + l4 * 8);
                for (int m = 0; m < 2; ++m) acch[m][nf] = MFMA(a[m], b, acch[m][nf]);
            }
        }
        __syncthreads();   // previous GEMM2 reads of sH complete
        for (int m = 0; m < 2; ++m)
            for (int nf = 0; nf < 8; ++nf) {
                int coll = wn * 128 + nf * 16 + l15;
                float b1v = b1[hc * 256 + coll];
                for (int j = 0; j < 4; ++j) {
                    int row = wm * 32 + m * 16 + l4 * 4 + j;
                    float hv = fmaxf(acch[m][nf][j] + b1v, 0.f);
                    *(bf16*)(cH + swz(row, coll * 2)) = (bf16)hv;
                }
            }
        __syncthreads();
        for (int ks = 0; ks < 8; ++ks) {
            v8bf a[2];
            for (int m = 0; m < 2; ++m) {
                int row = wm * 32 + m * 16 + l15;
                a[m] = *(const v8bf*)(cH + swz(row, ks * 64 + l4 * 16));
            }
            for (int nf = 0; nf < 4; ++nf) {
                int o = wn * 64 + nf * 16 + l15;
                v8bf b = *(const v8bf*)(w2b + (size_t)o * 1024 + hc * 256 + ks * 32 + l4 * 8);
                for (int m = 0; m < 2; ++m) acc2[m][nf] = MFMA(a[m], b, acc2[m][nf]);
            }
        }
    }
    for (int m = 0; m < 2; ++m)
        for (int nf = 0; nf < 4; ++nf) {
            int o = wn * 64 + nf * 16 + l15;
            float b2v = b2[o];
            for (int j = 0; j < 4; ++j) {
                int row = wm * 32 + m * 16 + l4 * 4 + j;
                out[(size_t)(g0 + row) * 128 + o] = acc2[m][nf][j] + b2v;
            }
        }
}

extern "C" void kernel_launch(void* const* d_in, const int* in_sizes, int n_in,
                              void* d_out, int out_size, void* d_ws, size_t ws_size,
                              hipStream_t stream) {
    const float* x      = (const float*)d_in[0];
    const float* W_in   = (const float*)d_in[1];
    const float* b_in   = (const float*)d_in[2];
    const float* W_f    = (const float*)d_in[3];
    const float* b_f    = (const float*)d_in[4];
    const float* W_g    = (const float*)d_in[5];
    const float* b_g    = (const float*)d_in[6];
    const float* W_r    = (const float*)d_in[7];
    const float* b_r    = (const float*)d_in[8];
    const float* W_s    = (const float*)d_in[9];
    const float* b_s    = (const float*)d_in[10];
    const float* norm_w = (const float*)d_in[11];
    const float* hnw    = (const float*)d_in[12];
    const float* W1     = (const float*)d_in[13];
    const float* b1     = (const float*)d_in[14];
    const float* W2     = (const float*)d_in[15];
    const float* b2     = (const float*)d_in[16];

    char* p = (char*)d_ws;
    float* z   = (float*)p;            p += (size_t)BT * 256 * 4;
    float* sum = (float*)p;            p += (size_t)BT * 256 * 4;
    bf16* zn   = (bf16*)p;             p += (size_t)BT * 256 * 2;
    bf16* xb   = (bf16*)p;             p += (size_t)BT * 8 * 2;
    bf16* wf0  = (bf16*)p;             p += (size_t)NL * 65536 * 2;
    bf16* wf1  = (bf16*)p;             p += (size_t)NL * 65536 * 2;
    bf16* wg0  = (bf16*)p;             p += (size_t)NL * 65536 * 2;
    bf16* wg1  = (bf16*)p;             p += (size_t)NL * 65536 * 2;
    bf16* wr   = (bf16*)p;             p += (size_t)NL * 65536 * 2;
    bf16* ws   = (bf16*)p;             p += (size_t)NL * 65536 * 2;
    bf16* winb = (bf16*)p;             p += 65536 * 2;
    bf16* w1b  = (bf16*)p;             p += 262144 * 2;
    bf16* w2b  = (bf16*)p;             p += 131072 * 2;

    hipMemsetAsync(sum, 0, (size_t)BT * 256 * 4, stream);
    prep_w2<<<NL * 256, 256, 0, stream>>>(W_f, W_g, wf0, wf1, wg0, wg1);
    prep_w1<<<NL * 256, 256, 0, stream>>>(W_r, W_s, wr, ws);
    prep_misc<<<3840, 256, 0, stream>>>(x, W_in, W1, W2, xb, winb, w1b, w2b);
    in_conv_kernel<<<BT / 64, 256, 0, stream>>>(xb, winb, b_in, z);

    static const int dil[NL] = {1,2,4,8,16,32,64,128,256,512,
                                1,2,4,8,16,32,64,128,256,512};
    for (int i = 0; i < NL; ++i) {
        rms_kernel<<<BT / 4 / 64 * 64, 256, 0, stream>>>(z, zn, norm_w + i * 256);
        layer_kernel<<<BT / 64, 256, 0, stream>>>(zn, z, sum,
            wf0 + (size_t)i * 65536, wf1 + (size_t)i * 65536,
            wg0 + (size_t)i * 65536, wg1 + (size_t)i * 65536,
            wr + (size_t)i * 65536, ws + (size_t)i * 65536,
            b_f + i * 256, b_g + i * 256, b_r + i * 256, b_s + i * 256, dil[i]);
    }
    head_norm_kernel<<<BT / 4, 256, 0, stream>>>(sum, zn, hnw);
    head_kernel<<<BT / 64, 256, 0, stream>>>(zn, w1b, b1, w2b, b2, (float*)d_out);
}

// Round 2
// 6063.637 us; speedup vs baseline: 1.1930x; 1.1930x over previous
//
#include <hip/hip_runtime.h>
#include <hip/hip_bf16.h>

#define T 4096
#define BT (16*4096)
#define NL 20

typedef __bf16 bf16;
typedef __bf16 v8bf __attribute__((ext_vector_type(8)));
typedef float v4f __attribute__((ext_vector_type(4)));

#define MFMA(a,b,c) __builtin_amdgcn_mfma_f32_16x16x32_bf16((a),(b),(c),0,0,0)

__device__ __forceinline__ int swz512(int row, int bc)  { return row*512  + (bc ^ ((row&7)<<4)); }
__device__ __forceinline__ int swz1024(int row, int bc) { return row*1024 + (bc ^ ((row&7)<<4)); }

// ---------------- prep kernels: cast/reorder weights to bf16 ----------------
__global__ void prep_w2(const float* __restrict__ Wf, const float* __restrict__ Wg,
                        bf16* __restrict__ wf0, bf16* __restrict__ wf1,
                        bf16* __restrict__ wg0, bf16* __restrict__ wg1) {
    int idx = blockIdx.x * 256 + threadIdx.x;       // NL*256*256
    const float* pf = Wf + (size_t)idx * 2;
    wf0[idx] = (bf16)pf[0]; wf1[idx] = (bf16)pf[1];
    const float* pg = Wg + (size_t)idx * 2;
    wg0[idx] = (bf16)pg[0]; wg1[idx] = (bf16)pg[1];
}

__global__ void prep_w1(const float* __restrict__ Wr, const float* __restrict__ Ws,
                        bf16* __restrict__ wr, bf16* __restrict__ ws) {
    int idx = blockIdx.x * 256 + threadIdx.x;       // NL*256*256
    wr[idx] = (bf16)Wr[idx]; ws[idx] = (bf16)Ws[idx];
}

__global__ void prep_misc(const float* __restrict__ W_in, const float* __restrict__ W1,
                          const float* __restrict__ W2,
                          bf16* __restrict__ winb, bf16* __restrict__ w1b, bf16* __restrict__ w2b) {
    int idx = blockIdx.x * 256 + threadIdx.x;       // 458752 total
    if (idx < 65536) {
        int c = idx >> 8, jj = idx & 255, k = jj >> 3, ci = jj & 7;
        winb[idx] = (bf16)W_in[c * 256 + ci * 32 + k];   // winb[c][k*8+ci]
    } else if (idx < 327680) {
        int j = idx - 65536; w1b[j] = (bf16)W1[j];
    } else {
        int j = idx - 327680; w2b[j] = (bf16)W2[j];
    }
}

// ---------------- fused input conv + RMSNorm(norm_w[0]) ----------------
__global__ __launch_bounds__(512, 4) void in_conv_kernel(
    const float* __restrict__ x, const bf16* __restrict__ winb,
    const float* __restrict__ b_in, const float* __restrict__ nw0,
    float* __restrict__ z, bf16* __restrict__ znout) {
    __shared__ __align__(16) char smem[66816];
    char* cA = smem + 32768;           // window tile 32KB (upper half)
    char* cZ = smem;                   // 64KB f32 staging (overlaps; sync-separated)
    float* rsq = (float*)(smem + 65536);
    const int tid = threadIdx.x;
    const int g0 = blockIdx.x * 64;
    const int tl0 = g0 & (T - 1);
    for (int i = 0; i < 4; ++i) {
        int ch = tid + i * 512;
        int r = ch >> 5, c16 = ch & 31;
        int tok = tl0 + r - 31 + c16;
        bf16 t8[8] = {};
        if (tok >= 0) {
            const float* xr = x + (size_t)(g0 + r - 31 + c16) * 8;
            float4 xa = ((const float4*)xr)[0];
            float4 xb4 = ((const float4*)xr)[1];
            t8[0]=(bf16)xa.x; t8[1]=(bf16)xa.y; t8[2]=(bf16)xa.z; t8[3]=(bf16)xa.w;
            t8[4]=(bf16)xb4.x; t8[5]=(bf16)xb4.y; t8[6]=(bf16)xb4.z; t8[7]=(bf16)xb4.w;
        }
        *(uint4*)(cA + swz512(r, c16 * 16)) = *(uint4*)t8;
    }
    __syncthreads();
    const int lane = tid & 63, w = tid >> 6;
    const int wm = w >> 2, wn = w & 3;
    const int l15 = lane & 15, l4 = lane >> 4;
    const int r0 = wm * 32, c0 = wn * 64;
    v4f acc[2][4] = {};
    for (int ks = 0; ks < 8; ++ks) {
        v8bf a[2];
        for (int m = 0; m < 2; ++m)
            a[m] = *(const v8bf*)(cA + swz512(r0 + m*16 + l15, ks*64 + l4*16));
        for (int nf = 0; nf < 4; ++nf) {
            v8bf b = *(const v8bf*)(winb + (size_t)(c0 + nf*16 + l15)*256 + ks*32 + l4*8);
            for (int m = 0; m < 2; ++m) acc[m][nf] = MFMA(a[m], b, acc[m][nf]);
        }
    }
    __syncthreads();        // GEMM reads done; cZ (overlapping cA) may be written
    float zvv[2][4][4];
    for (int m = 0; m < 2; ++m)
        for (int nf = 0; nf < 4; ++nf) {
            int col = c0 + nf*16 + l15;
            float bv = b_in[col];
            for (int j = 0; j < 4; ++j) zvv[m][nf][j] = acc[m][nf][j] + bv;
        }
    for (int m = 0; m < 2; ++m)
        for (int j = 0; j < 4; ++j) {
            int row = r0 + m*16 + l4*4 + j;
            float p = 0.f;
            for (int nf = 0; nf < 4; ++nf) { float v = zvv[m][nf][j]; p += v*v; }
            p += __shfl_xor(p,1); p += __shfl_xor(p,2); p += __shfl_xor(p,4); p += __shfl_xor(p,8);
            if (l15 == 0) rsq[row*5 + wn] = p;
        }
    for (int m = 0; m < 2; ++m)
        for (int nf = 0; nf < 4; ++nf) {
            int col = c0 + nf*16 + l15;
            for (int j = 0; j < 4; ++j) {
                int row = r0 + m*16 + l4*4 + j;
                *(float*)(cZ + swz1024(row, col*4)) = zvv[m][nf][j];
            }
        }
    __syncthreads();
    for (int k = 0; k < 8; ++k) {
        int idx = tid + k * 512;
        int row = idx >> 6, c16 = idx & 63;
        uint4 v = *(uint4*)(cZ + swz1024(row, c16*16));
        ((uint4*)z)[(size_t)(g0+row)*64 + c16] = v;
        float iv = rsqrtf((rsq[row*5]+rsq[row*5+1]+rsq[row*5+2]+rsq[row*5+3])*(1.f/256.f) + 1e-6f);
        float4 nwv = ((const float4*)nw0)[c16];
        float4 f = *(float4*)&v;
        bf16 o4[4] = {(bf16)(f.x*iv*nwv.x), (bf16)(f.y*iv*nwv.y),
                      (bf16)(f.z*iv*nwv.z), (bf16)(f.w*iv*nwv.w)};
        ((uint2*)znout)[(size_t)(g0+row)*64 + c16] = *(uint2*)o4;
    }
}

// ---------------- fused gated-residual layer + next-layer RMSNorm ----------------
// mode: 0 = first (no sum read), 1 = mid, 2 = last (no z; relu+head-norm -> on)
__global__ __launch_bounds__(512, 4) void layer_kernel(
    const bf16* __restrict__ znin, bf16* __restrict__ znout,
    float* __restrict__ z, float* __restrict__ sum,
    const bf16* __restrict__ wf0, const bf16* __restrict__ wf1,
    const bf16* __restrict__ wg0, const bf16* __restrict__ wg1,
    const bf16* __restrict__ wr, const bf16* __restrict__ wsm,
    const float* __restrict__ bfp, const float* __restrict__ bgp,
    const float* __restrict__ brp, const float* __restrict__ bsp,
    const float* __restrict__ nw, int dil, int mode) {
    __shared__ __align__(16) char smem[66816];
    char* cA0 = smem;                  // zn[t-d] tile, then U tile
    char* cA1 = smem + 32768;          // zn[t] tile
    char* cZ  = smem;                  // 64KB f32 staging (overlaps; sync-separated)
    float* rsq = (float*)(smem + 65536);
    const int tid = threadIdx.x;
    const int g0 = blockIdx.x * 64;
    const int tl0 = g0 & (T - 1);

    for (int i = 0; i < 4; ++i) {
        int ch = tid + i * 512;
        int r = ch >> 5, c16 = ch & 31;
        uint4 v1 = ((const uint4*)(znin + (size_t)(g0 + r) * 256))[c16];
        uint4 v0 = make_uint4(0, 0, 0, 0);
        if (tl0 + r - dil >= 0)
            v0 = ((const uint4*)(znin + (size_t)(g0 + r - dil) * 256))[c16];
        int dst = swz512(r, c16 * 16);
        *(uint4*)(cA1 + dst) = v1;
        *(uint4*)(cA0 + dst) = v0;
    }
    __syncthreads();                               // S1

    const int lane = tid & 63, w = tid >> 6;
    const int wm = w >> 2, wn = w & 3;
    const int l15 = lane & 15, l4 = lane >> 4;
    const int r0 = wm * 32, c0 = wn * 64;

    v4f accf[2][4] = {}, accg[2][4] = {};
    for (int ks = 0; ks < 8; ++ks) {
        v8bf a0[2], a1[2];
        for (int m = 0; m < 2; ++m) {
            int off = swz512(r0 + m*16 + l15, ks*64 + l4*16);
            a0[m] = *(const v8bf*)(cA0 + off);
            a1[m] = *(const v8bf*)(cA1 + off);
        }
        for (int nf = 0; nf < 4; ++nf) {
            size_t bo = (size_t)(c0 + nf*16 + l15) * 256 + ks*32 + l4*8;
            v8bf b0 = *(const v8bf*)(wf0 + bo);
            v8bf b1 = *(const v8bf*)(wf1 + bo);
            v8bf b2 = *(const v8bf*)(wg0 + bo);
            v8bf b3 = *(const v8bf*)(wg1 + bo);
            for (int m = 0; m < 2; ++m) {
                accf[m][nf] = MFMA(a0[m], b0, accf[m][nf]);
                accf[m][nf] = MFMA(a1[m], b1, accf[m][nf]);
                accg[m][nf] = MFMA(a0[m], b2, accg[m][nf]);
                accg[m][nf] = MFMA(a1[m], b3, accg[m][nf]);
            }
        }
    }
    __syncthreads();                               // S2: tile reads done

    // prefetch old accumulator values: z_old (modes 0,1) or sum_old (mode 2)
    float zo[2][4][4];
    {
        const float* pre = (mode == 2) ? sum : z;
        for (int m = 0; m < 2; ++m)
            for (int nf = 0; nf < 4; ++nf)
                for (int j = 0; j < 4; ++j)
                    zo[m][nf][j] = pre[(size_t)(g0 + r0 + m*16 + l4*4 + j) * 256 + c0 + nf*16 + l15];
    }

    // epilogue 1: u = tanh(f)*sigmoid(g) -> cA0 as bf16
    for (int m = 0; m < 2; ++m)
        for (int nf = 0; nf < 4; ++nf) {
            int col = c0 + nf*16 + l15;
            float bfv = bfp[col], bgv = bgp[col];
            for (int j = 0; j < 4; ++j) {
                int row = r0 + m*16 + l4*4 + j;
                float fv = accf[m][nf][j] + bfv;
                fv = fminf(fmaxf(fv, -20.f), 20.f);
                float gv = accg[m][nf][j] + bgv;
                float e2 = __expf(-2.f * fv);
                float th = (1.f - e2) / (1.f + e2);
                float sg = 1.f / (1.f + __expf(-gv));
                *(bf16*)(cA0 + swz512(row, col*2)) = (bf16)(th * sg);
            }
        }
    __syncthreads();                               // S3

    v4f accr[2][4] = {}, accs[2][4] = {};
    if (mode != 2) {
        for (int ks = 0; ks < 8; ++ks) {
            v8bf a[2];
            for (int m = 0; m < 2; ++m)
                a[m] = *(const v8bf*)(cA0 + swz512(r0 + m*16 + l15, ks*64 + l4*16));
            for (int nf = 0; nf < 4; ++nf) {
                size_t bo = (size_t)(c0 + nf*16 + l15) * 256 + ks*32 + l4*8;
                v8bf br_ = *(const v8bf*)(wr + bo);
                v8bf bs_ = *(const v8bf*)(wsm + bo);
                for (int m = 0; m < 2; ++m) {
                    accr[m][nf] = MFMA(a[m], br_, accr[m][nf]);
                    accs[m][nf] = MFMA(a[m], bs_, accs[m][nf]);
                }
            }
        }
    } else {
        for (int ks = 0; ks < 8; ++ks) {
            v8bf a[2];
            for (int m = 0; m < 2; ++m)
                a[m] = *(const v8bf*)(cA0 + swz512(r0 + m*16 + l15, ks*64 + l4*16));
            for (int nf = 0; nf < 4; ++nf) {
                size_t bo = (size_t)(c0 + nf*16 + l15) * 256 + ks*32 + l4*8;
                v8bf bs_ = *(const v8bf*)(wsm + bo);
                for (int m = 0; m < 2; ++m)
                    accs[m][nf] = MFMA(a[m], bs_, accs[m][nf]);
            }
        }
    }
    __syncthreads();                               // S4: U reads done, cZ free

    if (mode != 2) {
        // z_new = z_old + conv_r + b_r; rsq partials; stage f32
        float zvv[2][4][4];
        for (int m = 0; m < 2; ++m)
            for (int nf = 0; nf < 4; ++nf) {
                int col = c0 + nf*16 + l15;
                float brv = brp[col];
                for (int j = 0; j < 4; ++j)
                    zvv[m][nf][j] = zo[m][nf][j] + accr[m][nf][j] + brv;
            }
        for (int m = 0; m < 2; ++m)
            for (int j = 0; j < 4; ++j) {
                int row = r0 + m*16 + l4*4 + j;
                float p = 0.f;
                for (int nf = 0; nf < 4; ++nf) { float v = zvv[m][nf][j]; p += v*v; }
                p += __shfl_xor(p,1); p += __shfl_xor(p,2); p += __shfl_xor(p,4); p += __shfl_xor(p,8);
                if (l15 == 0) rsq[row*5 + wn] = p;
            }
        for (int m = 0; m < 2; ++m)
            for (int nf = 0; nf < 4; ++nf) {
                int col = c0 + nf*16 + l15;
                for (int j = 0; j < 4; ++j)
                    *(float*)(cZ + swz1024(r0 + m*16 + l4*4 + j, col*4)) = zvv[m][nf][j];
            }
        // sum_old loads hidden under the copyout below
        float so[2][4][4];
        if (mode == 1) {
            for (int m = 0; m < 2; ++m)
                for (int nf = 0; nf < 4; ++nf)
                    for (int j = 0; j < 4; ++j)
                        so[m][nf][j] = sum[(size_t)(g0 + r0 + m*16 + l4*4 + j) * 256 + c0 + nf*16 + l15];
        }
        __syncthreads();                           // S5
        for (int k = 0; k < 8; ++k) {
            int idx = tid + k * 512;
            int row = idx >> 6, c16 = idx & 63;
            uint4 v = *(uint4*)(cZ + swz1024(row, c16*16));
            ((uint4*)z)[(size_t)(g0+row)*64 + c16] = v;
            float iv = rsqrtf((rsq[row*5]+rsq[row*5+1]+rsq[row*5+2]+rsq[row*5+3])*(1.f/256.f) + 1e-6f);
            float4 nwv = ((const float4*)nw)[c16];
            float4 f = *(float4*)&v;
            bf16 o4[4] = {(bf16)(f.x*iv*nwv.x), (bf16)(f.y*iv*nwv.y),
                          (bf16)(f.z*iv*nwv.z), (bf16)(f.w*iv*nwv.w)};
            ((uint2*)znout)[(size_t)(g0+row)*64 + c16] = *(uint2*)o4;
        }
        __syncthreads();                           // S6: cZ reads done
        for (int m = 0; m < 2; ++m)
            for (int nf = 0; nf < 4; ++nf) {
                int col = c0 + nf*16 + l15;
                float bsv = bsp[col];
                for (int j = 0; j < 4; ++j) {
                    float sv = accs[m][nf][j] + bsv + ((mode == 1) ? so[m][nf][j] : 0.f);
                    *(float*)(cZ + swz1024(r0 + m*16 + l4*4 + j, col*4)) = sv;
                }
            }
        __syncthreads();                           // S7
        for (int k = 0; k < 8; ++k) {
            int idx = tid + k * 512;
            int row = idx >> 6, c16 = idx & 63;
            ((uint4*)sum)[(size_t)(g0+row)*64 + c16] = *(uint4*)(cZ + swz1024(row, c16*16));
        }
    } else {
        // last layer: o = relu(sum_old + conv_s + b_s); head-norm -> on
        float ovv[2][4][4];
        for (int m = 0; m < 2; ++m)
            for (int nf = 0; nf < 4; ++nf) {
                int col = c0 + nf*16 + l15;
                float bsv = bsp[col];
                for (int j = 0; j < 4; ++j)
                    ovv[m][nf][j] = fmaxf(zo[m][nf][j] + accs[m][nf][j] + bsv, 0.f);
            }
        for (int m = 0; m < 2; ++m)
            for (int j = 0; j < 4; ++j) {
                int row = r0 + m*16 + l4*4 + j;
                float p = 0.f;
                for (int nf = 0; nf < 4; ++nf) { float v = ovv[m][nf][j]; p += v*v; }
                p += __shfl_xor(p,1); p += __shfl_xor(p,2); p += __shfl_xor(p,4); p += __shfl_xor(p,8);
                if (l15 == 0) rsq[row*5 + wn] = p;
            }
        for (int m = 0; m < 2; ++m)
            for (int nf = 0; nf < 4; ++nf) {
                int col = c0 + nf*16 + l15;
                for (int j = 0; j < 4; ++j)
                    *(float*)(cZ + swz1024(r0 + m*16 + l4*4 + j, col*4)) = ovv[m][nf][j];
            }
        __syncthreads();                           // S5
        for (int k = 0; k < 8; ++k) {
            int idx = tid + k * 512;
            int row = idx >> 6, c16 = idx & 63;
            uint4 v = *(uint4*)(cZ + swz1024(row, c16*16));
            float iv = rsqrtf((rsq[row*5]+rsq[row*5+1]+rsq[row*5+2]+rsq[row*5+3])*(1.f/256.f) + 1e-6f);
            float4 nwv = ((const float4*)nw)[c16];
            float4 f = *(float4*)&v;
            bf16 o4[4] = {(bf16)(f.x*iv*nwv.x), (bf16)(f.y*iv*nwv.y),
                          (bf16)(f.z*iv*nwv.z), (bf16)(f.w*iv*nwv.w)};
            ((uint2*)znout)[(size_t)(g0+row)*64 + c16] = *(uint2*)o4;
        }
    }
}

// ---------------- fused head: on @ W1 -> relu -> @ W2 ----------------
__global__ __launch_bounds__(256, 2) void head_kernel(
    const bf16* __restrict__ on, const bf16* __restrict__ w1b, const float* __restrict__ b1,
    const bf16* __restrict__ w2b, const float* __restrict__ b2, float* __restrict__ out) {
    __shared__ uint4 sOn[2048];
    __shared__ uint4 sH[2048];
    char* cOn = (char*)sOn; char* cH = (char*)sH;
    const int tid = threadIdx.x;
    const int g0 = blockIdx.x * 64;
    for (int i = 0; i < 8; ++i) {
        int ch = tid + i * 256;
        int r = ch >> 5, c16 = ch & 31;
        *(uint4*)(cOn + swz512(r, c16 * 16)) = ((const uint4*)(on + (size_t)(g0 + r) * 256))[c16];
    }
    __syncthreads();
    const int lane = tid & 63, w = tid >> 6;
    const int wm = w >> 1, wn = w & 1;
    const int l15 = lane & 15, l4 = lane >> 4;
    v4f acc2[2][4] = {};
    for (int hc = 0; hc < 4; ++hc) {
        v4f acch[2][8] = {};
        for (int ks = 0; ks < 8; ++ks) {
            v8bf a[2];
            for (int m = 0; m < 2; ++m)
                a[m] = *(const v8bf*)(cOn + swz512(wm*32 + m*16 + l15, ks*64 + l4*16));
            for (int nf = 0; nf < 8; ++nf) {
                int h = hc * 256 + wn * 128 + nf * 16 + l15;
                v8bf b = *(const v8bf*)(w1b + (size_t)h * 256 + ks * 32 + l4 * 8);
                for (int m = 0; m < 2; ++m) acch[m][nf] = MFMA(a[m], b, acch[m][nf]);
            }
        }
        __syncthreads();
        for (int m = 0; m < 2; ++m)
            for (int nf = 0; nf < 8; ++nf) {
                int coll = wn * 128 + nf * 16 + l15;
                float b1v = b1[hc * 256 + coll];
                for (int j = 0; j < 4; ++j) {
                    int row = wm * 32 + m * 16 + l4 * 4 + j;
                    float hv = fmaxf(acch[m][nf][j] + b1v, 0.f);
                    *(bf16*)(cH + swz512(row, coll * 2)) = (bf16)hv;
                }
            }
        __syncthreads();
        for (int ks = 0; ks < 8; ++ks) {
            v8bf a[2];
            for (int m = 0; m < 2; ++m)
                a[m] = *(const v8bf*)(cH + swz512(wm*32 + m*16 + l15, ks*64 + l4*16));
            for (int nf = 0; nf < 4; ++nf) {
                int o = wn * 64 + nf * 16 + l15;
                v8bf b = *(const v8bf*)(w2b + (size_t)o * 1024 + hc * 256 + ks * 32 + l4 * 8);
                for (int m = 0; m < 2; ++m) acc2[m][nf] = MFMA(a[m], b, acc2[m][nf]);
            }
        }
    }
    for (int m = 0; m < 2; ++m)
        for (int nf = 0; nf < 4; ++nf) {
            int o = wn * 64 + nf * 16 + l15;
            float b2v = b2[o];
            for (int j = 0; j < 4; ++j) {
                int row = wm * 32 + m * 16 + l4 * 4 + j;
                out[(size_t)(g0 + row) * 128 + o] = acc2[m][nf][j] + b2v;
            }
        }
}

extern "C" void kernel_launch(void* const* d_in, const int* in_sizes, int n_in,
                              void* d_out, int out_size, void* d_ws, size_t ws_size,
                              hipStream_t stream) {
    const float* x      = (const float*)d_in[0];
    const float* W_in   = (const float*)d_in[1];
    const float* b_in   = (const float*)d_in[2];
    const float* W_f    = (const float*)d_in[3];
    const float* b_f    = (const float*)d_in[4];
    const float* W_g    = (const float*)d_in[5];
    const float* b_g    = (const float*)d_in[6];
    const float* W_r    = (const float*)d_in[7];
    const float* b_r    = (const float*)d_in[8];
    const float* W_s    = (const float*)d_in[9];
    const float* b_s    = (const float*)d_in[10];
    const float* norm_w = (const float*)d_in[11];
    const float* hnw    = (const float*)d_in[12];
    const float* W1     = (const float*)d_in[13];
    const float* b1     = (const float*)d_in[14];
    const float* W2     = (const float*)d_in[15];
    const float* b2     = (const float*)d_in[16];

    char* p = (char*)d_ws;
    float* z    = (float*)p;           p += (size_t)BT * 256 * 4;
    float* sum  = (float*)p;           p += (size_t)BT * 256 * 4;
    bf16* zn_a  = (bf16*)p;            p += (size_t)BT * 256 * 2;
    bf16* zn_b  = (bf16*)p;            p += (size_t)BT * 256 * 2;
    bf16* wf0   = (bf16*)p;            p += (size_t)NL * 65536 * 2;
    bf16* wf1   = (bf16*)p;            p += (size_t)NL * 65536 * 2;
    bf16* wg0   = (bf16*)p;            p += (size_t)NL * 65536 * 2;
    bf16* wg1   = (bf16*)p;            p += (size_t)NL * 65536 * 2;
    bf16* wr    = (bf16*)p;            p += (size_t)NL * 65536 * 2;
    bf16* ws    = (bf16*)p;            p += (size_t)NL * 65536 * 2;
    bf16* winb  = (bf16*)p;            p += 65536 * 2;
    bf16* w1b   = (bf16*)p;            p += 262144 * 2;
    bf16* w2b   = (bf16*)p;            p += 131072 * 2;

    prep_w2<<<NL * 256, 256, 0, stream>>>(W_f, W_g, wf0, wf1, wg0, wg1);
    prep_w1<<<NL * 256, 256, 0, stream>>>(W_r, W_s, wr, ws);
    prep_misc<<<1792, 256, 0, stream>>>(W_in, W1, W2, winb, w1b, w2b);
    in_conv_kernel<<<BT / 64, 512, 0, stream>>>(x, winb, b_in, norm_w, z, zn_a);

    static const int dil[NL] = {1,2,4,8,16,32,64,128,256,512,
                                1,2,4,8,16,32,64,128,256,512};
    for (int i = 0; i < NL; ++i) {
        const bf16* zi = (i & 1) ? zn_b : zn_a;
        bf16* zo_      = (i & 1) ? zn_a : zn_b;
        int mode = (i == 0) ? 0 : ((i == NL - 1) ? 2 : 1);
        const float* nw = (i == NL - 1) ? hnw : (norm_w + (size_t)(i + 1) * 256);
        layer_kernel<<<BT / 64, 512, 0, stream>>>(zi, zo_, z, sum,
            wf0 + (size_t)i * 65536, wf1 + (size_t)i * 65536,
            wg0 + (size_t)i * 65536, wg1 + (size_t)i * 65536,
            wr + (size_t)i * 65536, ws + (size_t)i * 65536,
            b_f + i * 256, b_g + i * 256, b_r + i * 256, b_s + i * 256,
            nw, dil[i], mode);
    }
    // NL=20 even: last layer wrote zn_a
    head_kernel<<<BT / 64, 256, 0, stream>>>(zn_a, w1b, b1, w2b, b2, (float*)d_out);
}

// Round 3
// 5835.666 us; speedup vs baseline: 1.2396x; 1.0391x over previous
//
#include <hip/hip_runtime.h>
#include <hip/hip_bf16.h>

#define T 4096
#define BT (16*4096)
#define NL 20
#define TPB 4608   // 512 pad + 4096 tokens per batch
#define PAD 512

typedef __bf16 bf16;
typedef __bf16 v8bf __attribute__((ext_vector_type(8)));
typedef float v4f __attribute__((ext_vector_type(4)));

#define MFMA(a,b,c) __builtin_amdgcn_mfma_f32_16x16x32_bf16((a),(b),(c),0,0,0)

__device__ __forceinline__ int swz512(int row, int bc)  { return row*512  + (bc ^ ((row&7)<<4)); }
__device__ __forceinline__ int swz1024(int row, int bc) { return row*1024 + (bc ^ ((row&7)<<4)); }

__device__ __forceinline__ void gload16(const void* g, void* l) {
    __builtin_amdgcn_global_load_lds(
        (const __attribute__((address_space(1))) void*)g,
        (__attribute__((address_space(3))) void*)l, 16, 0, 0);
}

// ---------------- zero the per-batch pad stripes of both zn buffers ----------------
__global__ void zero_pads(bf16* __restrict__ zn_a, bf16* __restrict__ zn_b) {
    int idx = blockIdx.x * 256 + threadIdx.x;      // 2*16*16384 uint4
    int buf = idx >> 18;
    int r = idx & 262143;
    int b = r >> 14, off = r & 16383;              // pad = 512 rows * 32 uint4
    bf16* base = buf ? zn_b : zn_a;
    ((uint4*)(base + (size_t)b * TPB * 256))[off] = make_uint4(0, 0, 0, 0);
}

// ---------------- prep kernels: cast/reorder weights to bf16 ----------------
__global__ void prep_w2(const float* __restrict__ Wf, const float* __restrict__ Wg,
                        bf16* __restrict__ wf0, bf16* __restrict__ wf1,
                        bf16* __restrict__ wg0, bf16* __restrict__ wg1) {
    int idx = blockIdx.x * 256 + threadIdx.x;       // NL*256*256
    const float* pf = Wf + (size_t)idx * 2;
    wf0[idx] = (bf16)pf[0]; wf1[idx] = (bf16)pf[1];
    const float* pg = Wg + (size_t)idx * 2;
    wg0[idx] = (bf16)pg[0]; wg1[idx] = (bf16)pg[1];
}

__global__ void prep_w1(const float* __restrict__ Wr, const float* __restrict__ Ws,
                        bf16* __restrict__ wr, bf16* __restrict__ ws) {
    int idx = blockIdx.x * 256 + threadIdx.x;       // NL*256*256
    wr[idx] = (bf16)Wr[idx]; ws[idx] = (bf16)Ws[idx];
}

__global__ void prep_misc(const float* __restrict__ W_in, const float* __restrict__ W1,
                          const float* __restrict__ W2,
                          bf16* __restrict__ winb, bf16* __restrict__ w1b, bf16* __restrict__ w2b) {
    int idx = blockIdx.x * 256 + threadIdx.x;       // 458752 total
    if (idx < 65536) {
        int c = idx >> 8, jj = idx & 255, k = jj >> 3, ci = jj & 7;
        winb[idx] = (bf16)W_in[c * 256 + ci * 32 + k];   // winb[c][k*8+ci]
    } else if (idx < 327680) {
        int j = idx - 65536; w1b[j] = (bf16)W1[j];
    } else {
        int j = idx - 327680; w2b[j] = (bf16)W2[j];
    }
}

// ---------------- fused input conv + RMSNorm(norm_w[0]) ----------------
__global__ __launch_bounds__(512, 4) void in_conv_kernel(
    const float* __restrict__ x, const bf16* __restrict__ winb,
    const float* __restrict__ b_in, const float* __restrict__ nw0,
    float* __restrict__ z, bf16* __restrict__ znout) {
    __shared__ __align__(16) char smem[66816];
    char* cA = smem + 32768;
    char* cZ = smem;
    float* rsq = (float*)(smem + 65536);
    const int tid = threadIdx.x;
    const int g0 = blockIdx.x * 64;
    const int tl0 = g0 & (T - 1);
    const size_t pr0 = (size_t)(g0 >> 12) * TPB + PAD + tl0;
    for (int i = 0; i < 4; ++i) {
        int ch = tid + i * 512;
        int r = ch >> 5, c16 = ch & 31;
        int tok = tl0 + r - 31 + c16;
        bf16 t8[8] = {};
        if (tok >= 0) {
            const float* xr = x + (size_t)(g0 + r - 31 + c16) * 8;
            float4 xa = ((const float4*)xr)[0];
            float4 xb4 = ((const float4*)xr)[1];
            t8[0]=(bf16)xa.x; t8[1]=(bf16)xa.y; t8[2]=(bf16)xa.z; t8[3]=(bf16)xa.w;
            t8[4]=(bf16)xb4.x; t8[5]=(bf16)xb4.y; t8[6]=(bf16)xb4.z; t8[7]=(bf16)xb4.w;
        }
        *(uint4*)(cA + swz512(r, c16 * 16)) = *(uint4*)t8;
    }
    __syncthreads();
    const int lane = tid & 63, w = tid >> 6;
    const int wm = w >> 2, wn = w & 3;
    const int l15 = lane & 15, l4 = lane >> 4;
    const int r0 = wm * 32, c0 = wn * 64;
    v4f acc[2][4] = {};
    for (int ks = 0; ks < 8; ++ks) {
        v8bf a[2];
        for (int m = 0; m < 2; ++m)
            a[m] = *(const v8bf*)(cA + swz512(r0 + m*16 + l15, ks*64 + l4*16));
        for (int nf = 0; nf < 4; ++nf) {
            v8bf b = *(const v8bf*)(winb + (size_t)(c0 + nf*16 + l15)*256 + ks*32 + l4*8);
            for (int m = 0; m < 2; ++m) acc[m][nf] = MFMA(a[m], b, acc[m][nf]);
        }
    }
    __syncthreads();
    float zvv[2][4][4];
    for (int m = 0; m < 2; ++m)
        for (int nf = 0; nf < 4; ++nf) {
            int col = c0 + nf*16 + l15;
            float bv = b_in[col];
            for (int j = 0; j < 4; ++j) zvv[m][nf][j] = acc[m][nf][j] + bv;
        }
    for (int m = 0; m < 2; ++m)
        for (int j = 0; j < 4; ++j) {
            int row = r0 + m*16 + l4*4 + j;
            float p = 0.f;
            for (int nf = 0; nf < 4; ++nf) { float v = zvv[m][nf][j]; p += v*v; }
            p += __shfl_xor(p,1); p += __shfl_xor(p,2); p += __shfl_xor(p,4); p += __shfl_xor(p,8);
            if (l15 == 0) rsq[row*5 + wn] = p;
        }
    for (int m = 0; m < 2; ++m)
        for (int nf = 0; nf < 4; ++nf) {
            int col = c0 + nf*16 + l15;
            for (int j = 0; j < 4; ++j) {
                int row = r0 + m*16 + l4*4 + j;
                *(float*)(cZ + swz1024(row, col*4)) = zvv[m][nf][j];
            }
        }
    __syncthreads();
    for (int k = 0; k < 8; ++k) {
        int idx = tid + k * 512;
        int row = idx >> 6, c16 = idx & 63;
        uint4 v = *(uint4*)(cZ + swz1024(row, c16*16));
        ((uint4*)z)[(size_t)(g0+row)*64 + c16] = v;
        float iv = rsqrtf((rsq[row*5]+rsq[row*5+1]+rsq[row*5+2]+rsq[row*5+3])*(1.f/256.f) + 1e-6f);
        float4 nwv = ((const float4*)nw0)[c16];
        float4 f = *(float4*)&v;
        bf16 o4[4] = {(bf16)(f.x*iv*nwv.x), (bf16)(f.y*iv*nwv.y),
                      (bf16)(f.z*iv*nwv.z), (bf16)(f.w*iv*nwv.w)};
        *((uint2*)(znout + (pr0 + row) * 256) + c16) = *(uint2*)o4;
    }
}

// ---------------- fused gated-residual layer + next-layer RMSNorm ----------------
// mode: 0 = first (no sum read), 1 = mid, 2 = last (no z; relu+head-norm -> on)
__global__ __launch_bounds__(512, 4) void layer_kernel(
    const bf16* __restrict__ znin, bf16* __restrict__ znout,
    float* __restrict__ z, float* __restrict__ sum,
    const bf16* __restrict__ wf0, const bf16* __restrict__ wf1,
    const bf16* __restrict__ wg0, const bf16* __restrict__ wg1,
    const bf16* __restrict__ wr, const bf16* __restrict__ wsm,
    const float* __restrict__ bfp, const float* __restrict__ bgp,
    const float* __restrict__ brp, const float* __restrict__ bsp,
    const float* __restrict__ nw, int dil, int mode) {
    __shared__ __align__(16) char smem[66816];
    char* cA0 = smem;                  // zn[t-d] tile, then U tile, then zn-out staging
    char* cA1 = smem + 32768;          // zn[t] tile
    float* rsq = (float*)(smem + 65536);
    const int tid = threadIdx.x;
    const int lane = tid & 63, w = tid >> 6;
    const int g0 = blockIdx.x * 64;
    const size_t pr0 = (size_t)(g0 >> 12) * TPB + PAD + (g0 & (T - 1));

    // async stage zn[t]->cA1, zn[t-dil]->cA0 with pre-swizzled global source
    {
        int rl = w * 8 + (lane >> 5);
        int d = lane & 31;
        #pragma unroll
        for (int j = 0; j < 4; ++j) {
            int r = rl + j * 2;
            int s = d ^ (r & 7);
            gload16(znin + (pr0 + r) * 256 + s * 8,       cA1 + (w*8 + j*2) * 512);
            gload16(znin + (pr0 + r - dil) * 256 + s * 8, cA0 + (w*8 + j*2) * 512);
        }
    }
    __syncthreads();                               // S1

    const int wm = w >> 2, wn = w & 3;
    const int l15 = lane & 15, l4 = lane >> 4;
    const int r0 = wm * 32, c0 = wn * 64;

    v4f accf[2][4] = {}, accg[2][4] = {};
    #pragma unroll
    for (int ks = 0; ks < 8; ++ks) {
        v8bf a0[2], a1[2];
        for (int m = 0; m < 2; ++m) {
            int off = swz512(r0 + m*16 + l15, ks*64 + l4*16);
            a0[m] = *(const v8bf*)(cA0 + off);
            a1[m] = *(const v8bf*)(cA1 + off);
        }
        for (int nf = 0; nf < 4; ++nf) {
            size_t bo = (size_t)(c0 + nf*16 + l15) * 256 + ks*32 + l4*8;
            v8bf b0 = *(const v8bf*)(wf0 + bo);
            v8bf b1 = *(const v8bf*)(wf1 + bo);
            v8bf b2 = *(const v8bf*)(wg0 + bo);
            v8bf b3 = *(const v8bf*)(wg1 + bo);
            for (int m = 0; m < 2; ++m) {
                accf[m][nf] = MFMA(a0[m], b0, accf[m][nf]);
                accf[m][nf] = MFMA(a1[m], b1, accf[m][nf]);
                accg[m][nf] = MFMA(a0[m], b2, accg[m][nf]);
                accg[m][nf] = MFMA(a1[m], b3, accg[m][nf]);
            }
        }
    }
    __syncthreads();                               // S2: tile reads done

    // epilogue 1: u = tanh(f)*sigmoid(g) -> cA0 as bf16
    for (int m = 0; m < 2; ++m)
        for (int nf = 0; nf < 4; ++nf) {
            int col = c0 + nf*16 + l15;
            float bfv = bfp[col], bgv = bgp[col];
            for (int j = 0; j < 4; ++j) {
                int row = r0 + m*16 + l4*4 + j;
                float fv = accf[m][nf][j] + bfv;
                fv = fminf(fmaxf(fv, -20.f), 20.f);
                float gv = accg[m][nf][j] + bgv;
                float e2 = __expf(-2.f * fv);
                float th = (1.f - e2) / (1.f + e2);
                float sg = 1.f / (1.f + __expf(-gv));
                *(bf16*)(cA0 + swz512(row, col*2)) = (bf16)(th * sg);
            }
        }
    __syncthreads();                               // S3

    // sum_old loads overlap GEMM2
    float so[2][4][4];
    if (mode != 0) {
        for (int m = 0; m < 2; ++m)
            for (int nf = 0; nf < 4; ++nf)
                for (int j = 0; j < 4; ++j)
                    so[m][nf][j] = sum[(size_t)(g0 + r0 + m*16 + l4*4 + j) * 256 + c0 + nf*16 + l15];
    } else {
        for (int m = 0; m < 2; ++m)
            for (int nf = 0; nf < 4; ++nf)
                for (int j = 0; j < 4; ++j) so[m][nf][j] = 0.f;
    }

    v4f accr[2][4] = {}, accs[2][4] = {};
    if (mode != 2) {
        #pragma unroll
        for (int ks = 0; ks < 8; ++ks) {
            v8bf a[2];
            for (int m = 0; m < 2; ++m)
                a[m] = *(const v8bf*)(cA0 + swz512(r0 + m*16 + l15, ks*64 + l4*16));
            for (int nf = 0; nf < 4; ++nf) {
                size_t bo = (size_t)(c0 + nf*16 + l15) * 256 + ks*32 + l4*8;
                v8bf br_ = *(const v8bf*)(wr + bo);
                v8bf bs_ = *(const v8bf*)(wsm + bo);
                for (int m = 0; m < 2; ++m) {
                    accr[m][nf] = MFMA(a[m], br_, accr[m][nf]);
                    accs[m][nf] = MFMA(a[m], bs_, accs[m][nf]);
                }
            }
        }
    } else {
        #pragma unroll
        for (int ks = 0; ks < 8; ++ks) {
            v8bf a[2];
            for (int m = 0; m < 2; ++m)
                a[m] = *(const v8bf*)(cA0 + swz512(r0 + m*16 + l15, ks*64 + l4*16));
            for (int nf = 0; nf < 4; ++nf) {
                size_t bo = (size_t)(c0 + nf*16 + l15) * 256 + ks*32 + l4*8;
                v8bf bs_ = *(const v8bf*)(wsm + bo);
                for (int m = 0; m < 2; ++m)
                    accs[m][nf] = MFMA(a[m], bs_, accs[m][nf]);
            }
        }
    }

    float zva[2][4][4];
    if (mode != 2) {
        // sum stores (direct, 64B-line aligned)
        for (int m = 0; m < 2; ++m)
            for (int nf = 0; nf < 4; ++nf) {
                int col = c0 + nf*16 + l15;
                float bsv = bsp[col];
                for (int j = 0; j < 4; ++j)
                    sum[(size_t)(g0 + r0 + m*16 + l4*4 + j) * 256 + col] = so[m][nf][j] + accs[m][nf][j] + bsv;
            }
        // z_old load (deferred), z_new compute + store
        for (int m = 0; m < 2; ++m)
            for (int nf = 0; nf < 4; ++nf) {
                int col = c0 + nf*16 + l15;
                float brv = brp[col];
                for (int j = 0; j < 4; ++j) {
                    size_t idx = (size_t)(g0 + r0 + m*16 + l4*4 + j) * 256 + col;
                    float zv = z[idx] + accr[m][nf][j] + brv;
                    z[idx] = zv;
                    zva[m][nf][j] = zv;
                }
            }
    } else {
        for (int m = 0; m < 2; ++m)
            for (int nf = 0; nf < 4; ++nf) {
                int col = c0 + nf*16 + l15;
                float bsv = bsp[col];
                for (int j = 0; j < 4; ++j)
                    zva[m][nf][j] = fmaxf(so[m][nf][j] + accs[m][nf][j] + bsv, 0.f);
            }
    }
    // rsq partials
    for (int m = 0; m < 2; ++m)
        for (int j = 0; j < 4; ++j) {
            int row = r0 + m*16 + l4*4 + j;
            float p = 0.f;
            for (int nf = 0; nf < 4; ++nf) { float v = zva[m][nf][j]; p += v*v; }
            p += __shfl_xor(p,1); p += __shfl_xor(p,2); p += __shfl_xor(p,4); p += __shfl_xor(p,8);
            if (l15 == 0) rsq[row*5 + wn] = p;
        }
    __syncthreads();                               // S4: GEMM2 reads + rsq done

    // zn staging (bf16, swizzled) into cA0
    for (int m = 0; m < 2; ++m)
        for (int j = 0; j < 4; ++j) {
            int row = r0 + m*16 + l4*4 + j;
            float iv = rsqrtf((rsq[row*5]+rsq[row*5+1]+rsq[row*5+2]+rsq[row*5+3])*(1.f/256.f) + 1e-6f);
            for (int nf = 0; nf < 4; ++nf) {
                int col = c0 + nf*16 + l15;
                *(bf16*)(cA0 + swz512(row, col*2)) = (bf16)(zva[m][nf][j] * iv * nw[col]);
            }
        }
    __syncthreads();                               // S5

    // coalesced zn copyout (padded layout)
    for (int k = 0; k < 4; ++k) {
        int idx = tid + k * 512;
        int row = idx >> 5, d = idx & 31;
        uint4 v = *(uint4*)(cA0 + swz512(row, d*16));
        *((uint4*)(znout + (pr0 + row) * 256) + d) = v;
    }
}

// ---------------- fused head: on @ W1 -> relu -> @ W2 ----------------
__global__ __launch_bounds__(256, 2) void head_kernel(
    const bf16* __restrict__ on, const bf16* __restrict__ w1b, const float* __restrict__ b1,
    const bf16* __restrict__ w2b, const float* __restrict__ b2, float* __restrict__ out) {
    __shared__ uint4 sOn[2048];
    __shared__ uint4 sH[2048];
    char* cOn = (char*)sOn; char* cH = (char*)sH;
    const int tid = threadIdx.x;
    const int g0 = blockIdx.x * 64;
    const size_t pr0 = (size_t)(g0 >> 12) * TPB + PAD + (g0 & (T - 1));
    for (int i = 0; i < 8; ++i) {
        int ch = tid + i * 256;
        int r = ch >> 5, c16 = ch & 31;
        *(uint4*)(cOn + swz512(r, c16 * 16)) = *((const uint4*)(on + (pr0 + r) * 256) + c16);
    }
    __syncthreads();
    const int lane = tid & 63, w = tid >> 6;
    const int wm = w >> 1, wn = w & 1;
    const int l15 = lane & 15, l4 = lane >> 4;
    v4f acc2[2][4] = {};
    for (int hc = 0; hc < 4; ++hc) {
        v4f acch[2][8] = {};
        for (int ks = 0; ks < 8; ++ks) {
            v8bf a[2];
            for (int m = 0; m < 2; ++m)
                a[m] = *(const v8bf*)(cOn + swz512(wm*32 + m*16 + l15, ks*64 + l4*16));
            for (int nf = 0; nf < 8; ++nf) {
                int h = hc * 256 + wn * 128 + nf * 16 + l15;
                v8bf b = *(const v8bf*)(w1b + (size_t)h * 256 + ks * 32 + l4 * 8);
                for (int m = 0; m < 2; ++m) acch[m][nf] = MFMA(a[m], b, acch[m][nf]);
            }
        }
        __syncthreads();
        for (int m = 0; m < 2; ++m)
            for (int nf = 0; nf < 8; ++nf) {
                int coll = wn * 128 + nf * 16 + l15;
                float b1v = b1[hc * 256 + coll];
                for (int j = 0; j < 4; ++j) {
                    int row = wm * 32 + m * 16 + l4 * 4 + j;
                    float hv = fmaxf(acch[m][nf][j] + b1v, 0.f);
                    *(bf16*)(cH + swz512(row, coll * 2)) = (bf16)hv;
                }
            }
        __syncthreads();
        for (int ks = 0; ks < 8; ++ks) {
            v8bf a[2];
            for (int m = 0; m < 2; ++m)
                a[m] = *(const v8bf*)(cH + swz512(wm*32 + m*16 + l15, ks*64 + l4*16));
            for (int nf = 0; nf < 4; ++nf) {
                int o = wn * 64 + nf * 16 + l15;
                v8bf b = *(const v8bf*)(w2b + (size_t)o * 1024 + hc * 256 + ks * 32 + l4 * 8);
                for (int m = 0; m < 2; ++m) acc2[m][nf] = MFMA(a[m], b, acc2[m][nf]);
            }
        }
    }
    for (int m = 0; m < 2; ++m)
        for (int nf = 0; nf < 4; ++nf) {
            int o = wn * 64 + nf * 16 + l15;
            float b2v = b2[o];
            for (int j = 0; j < 4; ++j) {
                int row = wm * 32 + m * 16 + l4 * 4 + j;
                out[(size_t)(g0 + row) * 128 + o] = acc2[m][nf][j] + b2v;
            }
        }
}

extern "C" void kernel_launch(void* const* d_in, const int* in_sizes, int n_in,
                              void* d_out, int out_size, void* d_ws, size_t ws_size,
                              hipStream_t stream) {
    const float* x      = (const float*)d_in[0];
    const float* W_in   = (const float*)d_in[1];
    const float* b_in   = (const float*)d_in[2];
    const float* W_f    = (const float*)d_in[3];
    const float* b_f    = (const float*)d_in[4];
    const float* W_g    = (const float*)d_in[5];
    const float* b_g    = (const float*)d_in[6];
    const float* W_r    = (const float*)d_in[7];
    const float* b_r    = (const float*)d_in[8];
    const float* W_s    = (const float*)d_in[9];
    const float* b_s    = (const float*)d_in[10];
    const float* norm_w = (const float*)d_in[11];
    const float* hnw    = (const float*)d_in[12];
    const float* W1     = (const float*)d_in[13];
    const float* b1     = (const float*)d_in[14];
    const float* W2     = (const float*)d_in[15];
    const float* b2     = (const float*)d_in[16];

    char* p = (char*)d_ws;
    float* z    = (float*)p;           p += (size_t)BT * 256 * 4;
    float* sum  = (float*)p;           p += (size_t)BT * 256 * 4;
    bf16* zn_a  = (bf16*)p;            p += (size_t)16 * TPB * 256 * 2;
    bf16* zn_b  = (bf16*)p;            p += (size_t)16 * TPB * 256 * 2;
    bf16* wf0   = (bf16*)p;            p += (size_t)NL * 65536 * 2;
    bf16* wf1   = (bf16*)p;            p += (size_t)NL * 65536 * 2;
    bf16* wg0   = (bf16*)p;            p += (size_t)NL * 65536 * 2;
    bf16* wg1   = (bf16*)p;            p += (size_t)NL * 65536 * 2;
    bf16* wr    = (bf16*)p;            p += (size_t)NL * 65536 * 2;
    bf16* ws    = (bf16*)p;            p += (size_t)NL * 65536 * 2;
    bf16* winb  = (bf16*)p;            p += 65536 * 2;
    bf16* w1b   = (bf16*)p;            p += 262144 * 2;
    bf16* w2b   = (bf16*)p;            p += 131072 * 2;

    zero_pads<<<2048, 256, 0, stream>>>(zn_a, zn_b);
    prep_w2<<<NL * 256, 256, 0, stream>>>(W_f, W_g, wf0, wf1, wg0, wg1);
    prep_w1<<<NL * 256, 256, 0, stream>>>(W_r, W_s, wr, ws);
    prep_misc<<<1792, 256, 0, stream>>>(W_in, W1, W2, winb, w1b, w2b);
    in_conv_kernel<<<BT / 64, 512, 0, stream>>>(x, winb, b_in, norm_w, z, zn_a);

    static const int dil[NL] = {1,2,4,8,16,32,64,128,256,512,
                                1,2,4,8,16,32,64,128,256,512};
    for (int i = 0; i < NL; ++i) {
        const bf16* zi = (i & 1) ? zn_b : zn_a;
        bf16* zo_      = (i & 1) ? zn_a : zn_b;
        int mode = (i == 0) ? 0 : ((i == NL - 1) ? 2 : 1);
        const float* nw = (i == NL - 1) ? hnw : (norm_w + (size_t)(i + 1) * 256);
        layer_kernel<<<BT / 64, 512, 0, stream>>>(zi, zo_, z, sum,
            wf0 + (size_t)i * 65536, wf1 + (size_t)i * 65536,
            wg0 + (size_t)i * 65536, wg1 + (size_t)i * 65536,
            wr + (size_t)i * 65536, ws + (size_t)i * 65536,
            b_f + i * 256, b_g + i * 256, b_r + i * 256, b_s + i * 256,
            nw, dil[i], mode);
    }
    // NL=20 even: last layer wrote zn_a
    head_kernel<<<BT / 64, 256, 0, stream>>>(zn_a, w1b, b1, w2b, b2, (float*)d_out);
}

// Round 4
// 5147.780 us; speedup vs baseline: 1.4052x; 1.1336x over previous
//
#include <hip/hip_runtime.h>
#include <hip/hip_bf16.h>

#define T 4096
#define BT (16*4096)
#define NL 20
#define TPB 4608   // 512 pad + 4096 tokens per batch
#define PAD 512

typedef __bf16 bf16;
typedef __bf16 v8bf __attribute__((ext_vector_type(8)));
typedef float v4f __attribute__((ext_vector_type(4)));

#define MFMA(a,b,c) __builtin_amdgcn_mfma_f32_16x16x32_bf16((a),(b),(c),0,0,0)

__device__ __forceinline__ int swz512(int row, int bc)  { return row*512  + (bc ^ ((row&7)<<4)); }
__device__ __forceinline__ int swz1024(int row, int bc) { return row*1024 + (bc ^ ((row&7)<<4)); }

__device__ __forceinline__ void gload16(const void* g, void* l) {
    __builtin_amdgcn_global_load_lds(
        (const __attribute__((address_space(1))) void*)g,
        (__attribute__((address_space(3))) void*)l, 16, 0, 0);
}

// ---------------- zero the per-batch pad stripes of both zn buffers ----------------
__global__ void zero_pads(bf16* __restrict__ zn_a, bf16* __restrict__ zn_b) {
    int idx = blockIdx.x * 256 + threadIdx.x;      // 2*16*16384 uint4
    int buf = idx >> 18;
    int r = idx & 262143;
    int b = r >> 14, off = r & 16383;              // pad = 512 rows * 32 uint4
    bf16* base = buf ? zn_b : zn_a;
    ((uint4*)(base + (size_t)b * TPB * 256))[off] = make_uint4(0, 0, 0, 0);
}

// ---------------- prep kernels: cast/reorder weights to bf16 ----------------
__global__ void prep_w2(const float* __restrict__ Wf, const float* __restrict__ Wg,
                        bf16* __restrict__ wf0, bf16* __restrict__ wf1,
                        bf16* __restrict__ wg0, bf16* __restrict__ wg1) {
    int idx = blockIdx.x * 256 + threadIdx.x;       // NL*256*256
    const float* pf = Wf + (size_t)idx * 2;
    wf0[idx] = (bf16)pf[0]; wf1[idx] = (bf16)pf[1];
    const float* pg = Wg + (size_t)idx * 2;
    wg0[idx] = (bf16)pg[0]; wg1[idx] = (bf16)pg[1];
}

__global__ void prep_w1(const float* __restrict__ Wr, const float* __restrict__ Ws,
                        bf16* __restrict__ wr, bf16* __restrict__ ws) {
    int idx = blockIdx.x * 256 + threadIdx.x;       // NL*256*256
    wr[idx] = (bf16)Wr[idx]; ws[idx] = (bf16)Ws[idx];
}

__global__ void prep_misc(const float* __restrict__ W_in, const float* __restrict__ W1,
                          const float* __restrict__ W2,
                          bf16* __restrict__ winb, bf16* __restrict__ w1b, bf16* __restrict__ w2b) {
    int idx = blockIdx.x * 256 + threadIdx.x;       // 458752 total
    if (idx < 65536) {
        int c = idx >> 8, jj = idx & 255, k = jj >> 3, ci = jj & 7;
        winb[idx] = (bf16)W_in[c * 256 + ci * 32 + k];   // winb[c][k*8+ci]
    } else if (idx < 327680) {
        int j = idx - 65536; w1b[j] = (bf16)W1[j];
    } else {
        int j = idx - 327680; w2b[j] = (bf16)W2[j];
    }
}

// ---------------- fused input conv + RMSNorm(norm_w[0]) ----------------
__global__ __launch_bounds__(512, 3) void in_conv_kernel(
    const float* __restrict__ x, const bf16* __restrict__ winb,
    const float* __restrict__ b_in, const float* __restrict__ nw0,
    float* __restrict__ z, bf16* __restrict__ znout) {
    __shared__ __align__(16) char smem[66816];
    char* cA = smem + 32768;
    char* cZ = smem;
    float* rsq = (float*)(smem + 65536);
    const int tid = threadIdx.x;
    const int g0 = blockIdx.x * 64;
    const int tl0 = g0 & (T - 1);
    const size_t pr0 = (size_t)(g0 >> 12) * TPB + PAD + tl0;
    for (int i = 0; i < 4; ++i) {
        int ch = tid + i * 512;
        int r = ch >> 5, c16 = ch & 31;
        int tok = tl0 + r - 31 + c16;
        bf16 t8[8] = {};
        if (tok >= 0) {
            const float* xr = x + (size_t)(g0 + r - 31 + c16) * 8;
            float4 xa = ((const float4*)xr)[0];
            float4 xb4 = ((const float4*)xr)[1];
            t8[0]=(bf16)xa.x; t8[1]=(bf16)xa.y; t8[2]=(bf16)xa.z; t8[3]=(bf16)xa.w;
            t8[4]=(bf16)xb4.x; t8[5]=(bf16)xb4.y; t8[6]=(bf16)xb4.z; t8[7]=(bf16)xb4.w;
        }
        *(uint4*)(cA + swz512(r, c16 * 16)) = *(uint4*)t8;
    }
    __syncthreads();
    const int lane = tid & 63, w = tid >> 6;
    const int wm = w >> 2, wn = w & 3;
    const int l15 = lane & 15, l4 = lane >> 4;
    const int r0 = wm * 32, c0 = wn * 64;
    v4f acc[2][4] = {};
    for (int ks = 0; ks < 8; ++ks) {
        v8bf a[2];
        for (int m = 0; m < 2; ++m)
            a[m] = *(const v8bf*)(cA + swz512(r0 + m*16 + l15, ks*64 + l4*16));
        for (int nf = 0; nf < 4; ++nf) {
            v8bf b = *(const v8bf*)(winb + (size_t)(c0 + nf*16 + l15)*256 + ks*32 + l4*8);
            for (int m = 0; m < 2; ++m) acc[m][nf] = MFMA(a[m], b, acc[m][nf]);
        }
    }
    __syncthreads();
    float zvv[2][4][4];
    for (int m = 0; m < 2; ++m)
        for (int nf = 0; nf < 4; ++nf) {
            int col = c0 + nf*16 + l15;
            float bv = b_in[col];
            for (int j = 0; j < 4; ++j) zvv[m][nf][j] = acc[m][nf][j] + bv;
        }
    for (int m = 0; m < 2; ++m)
        for (int j = 0; j < 4; ++j) {
            int row = r0 + m*16 + l4*4 + j;
            float p = 0.f;
            for (int nf = 0; nf < 4; ++nf) { float v = zvv[m][nf][j]; p += v*v; }
            p += __shfl_xor(p,1); p += __shfl_xor(p,2); p += __shfl_xor(p,4); p += __shfl_xor(p,8);
            if (l15 == 0) rsq[row*5 + wn] = p;
        }
    for (int m = 0; m < 2; ++m)
        for (int nf = 0; nf < 4; ++nf) {
            int col = c0 + nf*16 + l15;
            for (int j = 0; j < 4; ++j) {
                int row = r0 + m*16 + l4*4 + j;
                *(float*)(cZ + swz1024(row, col*4)) = zvv[m][nf][j];
            }
        }
    __syncthreads();
    for (int k = 0; k < 8; ++k) {
        int idx = tid + k * 512;
        int row = idx >> 6, c16 = idx & 63;
        uint4 v = *(uint4*)(cZ + swz1024(row, c16*16));
        ((uint4*)z)[(size_t)(g0+row)*64 + c16] = v;
        float iv = rsqrtf((rsq[row*5]+rsq[row*5+1]+rsq[row*5+2]+rsq[row*5+3])*(1.f/256.f) + 1e-6f);
        float4 nwv = ((const float4*)nw0)[c16];
        float4 f = *(float4*)&v;
        bf16 o4[4] = {(bf16)(f.x*iv*nwv.x), (bf16)(f.y*iv*nwv.y),
                      (bf16)(f.z*iv*nwv.z), (bf16)(f.w*iv*nwv.w)};
        *((uint2*)(znout + (pr0 + row) * 256) + c16) = *(uint2*)o4;
    }
}

// ---------------- fused gated-residual layer + next-layer RMSNorm ----------------
// mode: 0 = first (no sum read), 1 = mid, 2 = last (no z; relu+head-norm -> on)
__global__ __launch_bounds__(512, 2) void layer_kernel(
    const bf16* __restrict__ znin, bf16* __restrict__ znout,
    float* __restrict__ z, float* __restrict__ sum,
    const bf16* __restrict__ wf0, const bf16* __restrict__ wf1,
    const bf16* __restrict__ wg0, const bf16* __restrict__ wg1,
    const bf16* __restrict__ wr, const bf16* __restrict__ wsm,
    const float* __restrict__ bfp, const float* __restrict__ bgp,
    const float* __restrict__ brp, const float* __restrict__ bsp,
    const float* __restrict__ nw, int dil, int mode) {
    __shared__ __align__(16) char smem[66816];
    char* cA0 = smem;                  // zn[t-d] tile, then U tile, then zn-out staging
    char* cA1 = smem + 32768;          // zn[t] tile
    float* rsq = (float*)(smem + 65536);
    const int tid = threadIdx.x;
    const int lane = tid & 63, w = tid >> 6;
    const int g0 = blockIdx.x * 64;
    const size_t pr0 = (size_t)(g0 >> 12) * TPB + PAD + (g0 & (T - 1));

    // async stage zn[t]->cA1, zn[t-dil]->cA0 with pre-swizzled global source
    {
        int rl = w * 8 + (lane >> 5);
        int d = lane & 31;
        #pragma unroll
        for (int j = 0; j < 4; ++j) {
            int r = rl + j * 2;
            int s = d ^ (r & 7);
            gload16(znin + (pr0 + r) * 256 + s * 8,       cA1 + (w*8 + j*2) * 512);
            gload16(znin + (pr0 + r - dil) * 256 + s * 8, cA0 + (w*8 + j*2) * 512);
        }
    }

    const int wm = w >> 2, wn = w & 3;
    const int l15 = lane & 15, l4 = lane >> 4;
    const int r0 = wm * 32, c0 = wn * 64;
    const size_t gbase = (size_t)(g0 + r0 + l4*4) * 256 + c0 + l15;

    __syncthreads();                               // S1

    // prefetch old accumulators early; latency hides under GEMM1
    float so[2][4][4], zo[2][4][4];
    if (mode != 0) {
        #pragma unroll
        for (int m = 0; m < 2; ++m)
            #pragma unroll
            for (int nf = 0; nf < 4; ++nf)
                #pragma unroll
                for (int j = 0; j < 4; ++j)
                    so[m][nf][j] = sum[gbase + (size_t)(m*16 + j)*256 + nf*16];
    } else {
        #pragma unroll
        for (int m = 0; m < 2; ++m)
            #pragma unroll
            for (int nf = 0; nf < 4; ++nf)
                #pragma unroll
                for (int j = 0; j < 4; ++j) so[m][nf][j] = 0.f;
    }
    if (mode != 2) {
        #pragma unroll
        for (int m = 0; m < 2; ++m)
            #pragma unroll
            for (int nf = 0; nf < 4; ++nf)
                #pragma unroll
                for (int j = 0; j < 4; ++j)
                    zo[m][nf][j] = z[gbase + (size_t)(m*16 + j)*256 + nf*16];
    }

    v4f accf[2][4] = {}, accg[2][4] = {};
    #pragma unroll
    for (int ks = 0; ks < 8; ++ks) {
        v8bf a0[2], a1[2];
        #pragma unroll
        for (int m = 0; m < 2; ++m) {
            int off = swz512(r0 + m*16 + l15, ks*64 + l4*16);
            a0[m] = *(const v8bf*)(cA0 + off);
            a1[m] = *(const v8bf*)(cA1 + off);
        }
        #pragma unroll
        for (int nf = 0; nf < 4; ++nf) {
            size_t bo = (size_t)(c0 + nf*16 + l15) * 256 + ks*32 + l4*8;
            v8bf b0 = *(const v8bf*)(wf0 + bo);
            v8bf b1 = *(const v8bf*)(wf1 + bo);
            v8bf b2 = *(const v8bf*)(wg0 + bo);
            v8bf b3 = *(const v8bf*)(wg1 + bo);
            #pragma unroll
            for (int m = 0; m < 2; ++m) {
                accf[m][nf] = MFMA(a0[m], b0, accf[m][nf]);
                accf[m][nf] = MFMA(a1[m], b1, accf[m][nf]);
                accg[m][nf] = MFMA(a0[m], b2, accg[m][nf]);
                accg[m][nf] = MFMA(a1[m], b3, accg[m][nf]);
            }
        }
    }
    __syncthreads();                               // S2: tile reads done

    // epilogue 1: u = tanh(f)*sigmoid(g) -> cA0 as bf16
    #pragma unroll
    for (int m = 0; m < 2; ++m)
        #pragma unroll
        for (int nf = 0; nf < 4; ++nf) {
            int col = c0 + nf*16 + l15;
            float bfv = bfp[col], bgv = bgp[col];
            #pragma unroll
            for (int j = 0; j < 4; ++j) {
                int row = r0 + m*16 + l4*4 + j;
                float fv = accf[m][nf][j] + bfv;
                fv = fminf(fmaxf(fv, -20.f), 20.f);
                float gv = accg[m][nf][j] + bgv;
                float e2 = __expf(-2.f * fv);
                float th = (1.f - e2) / (1.f + e2);
                float sg = 1.f / (1.f + __expf(-gv));
                *(bf16*)(cA0 + swz512(row, col*2)) = (bf16)(th * sg);
            }
        }
    __syncthreads();                               // S3

    v4f accr[2][4] = {}, accs[2][4] = {};
    if (mode != 2) {
        #pragma unroll
        for (int ks = 0; ks < 8; ++ks) {
            v8bf a[2];
            #pragma unroll
            for (int m = 0; m < 2; ++m)
                a[m] = *(const v8bf*)(cA0 + swz512(r0 + m*16 + l15, ks*64 + l4*16));
            #pragma unroll
            for (int nf = 0; nf < 4; ++nf) {
                size_t bo = (size_t)(c0 + nf*16 + l15) * 256 + ks*32 + l4*8;
                v8bf br_ = *(const v8bf*)(wr + bo);
                v8bf bs_ = *(const v8bf*)(wsm + bo);
                #pragma unroll
                for (int m = 0; m < 2; ++m) {
                    accr[m][nf] = MFMA(a[m], br_, accr[m][nf]);
                    accs[m][nf] = MFMA(a[m], bs_, accs[m][nf]);
                }
            }
        }
    } else {
        #pragma unroll
        for (int ks = 0; ks < 8; ++ks) {
            v8bf a[2];
            #pragma unroll
            for (int m = 0; m < 2; ++m)
                a[m] = *(const v8bf*)(cA0 + swz512(r0 + m*16 + l15, ks*64 + l4*16));
            #pragma unroll
            for (int nf = 0; nf < 4; ++nf) {
                size_t bo = (size_t)(c0 + nf*16 + l15) * 256 + ks*32 + l4*8;
                v8bf bs_ = *(const v8bf*)(wsm + bo);
                #pragma unroll
                for (int m = 0; m < 2; ++m)
                    accs[m][nf] = MFMA(a[m], bs_, accs[m][nf]);
            }
        }
    }

    float zva[2][4][4];
    if (mode != 2) {
        // sum_new stores + z RMW (old values already in regs)
        #pragma unroll
        for (int m = 0; m < 2; ++m)
            #pragma unroll
            for (int nf = 0; nf < 4; ++nf) {
                int col = c0 + nf*16 + l15;
                float bsv = bsp[col], brv = brp[col];
                #pragma unroll
                for (int j = 0; j < 4; ++j) {
                    size_t idx = gbase + (size_t)(m*16 + j)*256 + nf*16;
                    sum[idx] = so[m][nf][j] + accs[m][nf][j] + bsv;
                    float zv = zo[m][nf][j] + accr[m][nf][j] + brv;
                    z[idx] = zv;
                    zva[m][nf][j] = zv;
                }
            }
    } else {
        #pragma unroll
        for (int m = 0; m < 2; ++m)
            #pragma unroll
            for (int nf = 0; nf < 4; ++nf) {
                int col = c0 + nf*16 + l15;
                float bsv = bsp[col];
                #pragma unroll
                for (int j = 0; j < 4; ++j)
                    zva[m][nf][j] = fmaxf(so[m][nf][j] + accs[m][nf][j] + bsv, 0.f);
            }
    }
    // rsq partials
    #pragma unroll
    for (int m = 0; m < 2; ++m)
        #pragma unroll
        for (int j = 0; j < 4; ++j) {
            int row = r0 + m*16 + l4*4 + j;
            float p = 0.f;
            #pragma unroll
            for (int nf = 0; nf < 4; ++nf) { float v = zva[m][nf][j]; p += v*v; }
            p += __shfl_xor(p,1); p += __shfl_xor(p,2); p += __shfl_xor(p,4); p += __shfl_xor(p,8);
            if (l15 == 0) rsq[row*5 + wn] = p;
        }
    __syncthreads();                               // S4: GEMM2 reads + rsq done

    // zn staging (bf16, swizzled) into cA0
    #pragma unroll
    for (int m = 0; m < 2; ++m)
        #pragma unroll
        for (int j = 0; j < 4; ++j) {
            int row = r0 + m*16 + l4*4 + j;
            float iv = rsqrtf((rsq[row*5]+rsq[row*5+1]+rsq[row*5+2]+rsq[row*5+3])*(1.f/256.f) + 1e-6f);
            #pragma unroll
            for (int nf = 0; nf < 4; ++nf) {
                int col = c0 + nf*16 + l15;
                *(bf16*)(cA0 + swz512(row, col*2)) = (bf16)(zva[m][nf][j] * iv * nw[col]);
            }
        }
    __syncthreads();                               // S5

    // coalesced zn copyout (padded layout)
    #pragma unroll
    for (int k = 0; k < 4; ++k) {
        int idx = tid + k * 512;
        int row = idx >> 5, d = idx & 31;
        uint4 v = *(uint4*)(cA0 + swz512(row, d*16));
        *((uint4*)(znout + (pr0 + row) * 256) + d) = v;
    }
}

// ---------------- fused head: on @ W1 -> relu -> @ W2 ----------------
__global__ __launch_bounds__(256, 2) void head_kernel(
    const bf16* __restrict__ on, const bf16* __restrict__ w1b, const float* __restrict__ b1,
    const bf16* __restrict__ w2b, const float* __restrict__ b2, float* __restrict__ out) {
    __shared__ uint4 sOn[2048];
    __shared__ uint4 sH[2048];
    char* cOn = (char*)sOn; char* cH = (char*)sH;
    const int tid = threadIdx.x;
    const int g0 = blockIdx.x * 64;
    const size_t pr0 = (size_t)(g0 >> 12) * TPB + PAD + (g0 & (T - 1));
    for (int i = 0; i < 8; ++i) {
        int ch = tid + i * 256;
        int r = ch >> 5, c16 = ch & 31;
        *(uint4*)(cOn + swz512(r, c16 * 16)) = *((const uint4*)(on + (pr0 + r) * 256) + c16);
    }
    __syncthreads();
    const int lane = tid & 63, w = tid >> 6;
    const int wm = w >> 1, wn = w & 1;
    const int l15 = lane & 15, l4 = lane >> 4;
    v4f acc2[2][4] = {};
    for (int hc = 0; hc < 4; ++hc) {
        v4f acch[2][8] = {};
        for (int ks = 0; ks < 8; ++ks) {
            v8bf a[2];
            for (int m = 0; m < 2; ++m)
                a[m] = *(const v8bf*)(cOn + swz512(wm*32 + m*16 + l15, ks*64 + l4*16));
            for (int nf = 0; nf < 8; ++nf) {
                int h = hc * 256 + wn * 128 + nf * 16 + l15;
                v8bf b = *(const v8bf*)(w1b + (size_t)h * 256 + ks * 32 + l4 * 8);
                for (int m = 0; m < 2; ++m) acch[m][nf] = MFMA(a[m], b, acch[m][nf]);
            }
        }
        __syncthreads();
        for (int m = 0; m < 2; ++m)
            for (int nf = 0; nf < 8; ++nf) {
                int coll = wn * 128 + nf * 16 + l15;
                float b1v = b1[hc * 256 + coll];
                for (int j = 0; j < 4; ++j) {
                    int row = wm * 32 + m * 16 + l4 * 4 + j;
                    float hv = fmaxf(acch[m][nf][j] + b1v, 0.f);
                    *(bf16*)(cH + swz512(row, coll * 2)) = (bf16)hv;
                }
            }
        __syncthreads();
        for (int ks = 0; ks < 8; ++ks) {
            v8bf a[2];
            for (int m = 0; m < 2; ++m)
                a[m] = *(const v8bf*)(cH + swz512(wm*32 + m*16 + l15, ks*64 + l4*16));
            for (int nf = 0; nf < 4; ++nf) {
                int o = wn * 64 + nf * 16 + l15;
                v8bf b = *(const v8bf*)(w2b + (size_t)o * 1024 + hc * 256 + ks * 32 + l4 * 8);
                for (int m = 0; m < 2; ++m) acc2[m][nf] = MFMA(a[m], b, acc2[m][nf]);
            }
        }
    }
    for (int m = 0; m < 2; ++m)
        for (int nf = 0; nf < 4; ++nf) {
            int o = wn * 64 + nf * 16 + l15;
            float b2v = b2[o];
            for (int j = 0; j < 4; ++j) {
                int row = wm * 32 + m * 16 + l4 * 4 + j;
                out[(size_t)(g0 + row) * 128 + o] = acc2[m][nf][j] + b2v;
            }
        }
}

extern "C" void kernel_launch(void* const* d_in, const int* in_sizes, int n_in,
                              void* d_out, int out_size, void* d_ws, size_t ws_size,
                              hipStream_t stream) {
    const float* x      = (const float*)d_in[0];
    const float* W_in   = (const float*)d_in[1];
    const float* b_in   = (const float*)d_in[2];
    const float* W_f    = (const float*)d_in[3];
    const float* b_f    = (const float*)d_in[4];
    const float* W_g    = (const float*)d_in[5];
    const float* b_g    = (const float*)d_in[6];
    const float* W_r    = (const float*)d_in[7];
    const float* b_r    = (const float*)d_in[8];
    const float* W_s    = (const float*)d_in[9];
    const float* b_s    = (const float*)d_in[10];
    const float* norm_w = (const float*)d_in[11];
    const float* hnw    = (const float*)d_in[12];
    const float* W1     = (const float*)d_in[13];
    const float* b1     = (const float*)d_in[14];
    const float* W2     = (const float*)d_in[15];
    const float* b2     = (const float*)d_in[16];

    char* p = (char*)d_ws;
    float* z    = (float*)p;           p += (size_t)BT * 256 * 4;
    float* sum  = (float*)p;           p += (size_t)BT * 256 * 4;
    bf16* zn_a  = (bf16*)p;            p += (size_t)16 * TPB * 256 * 2;
    bf16* zn_b  = (bf16*)p;            p += (size_t)16 * TPB * 256 * 2;
    bf16* wf0   = (bf16*)p;            p += (size_t)NL * 65536 * 2;
    bf16* wf1   = (bf16*)p;            p += (size_t)NL * 65536 * 2;
    bf16* wg0   = (bf16*)p;            p += (size_t)NL * 65536 * 2;
    bf16* wg1   = (bf16*)p;            p += (size_t)NL * 65536 * 2;
    bf16* wr    = (bf16*)p;            p += (size_t)NL * 65536 * 2;
    bf16* ws    = (bf16*)p;            p += (size_t)NL * 65536 * 2;
    bf16* winb  = (bf16*)p;            p += 65536 * 2;
    bf16* w1b   = (bf16*)p;            p += 262144 * 2;
    bf16* w2b   = (bf16*)p;            p += 131072 * 2;

    zero_pads<<<2048, 256, 0, stream>>>(zn_a, zn_b);
    prep_w2<<<NL * 256, 256, 0, stream>>>(W_f, W_g, wf0, wf1, wg0, wg1);
    prep_w1<<<NL * 256, 256, 0, stream>>>(W_r, W_s, wr, ws);
    prep_misc<<<1792, 256, 0, stream>>>(W_in, W1, W2, winb, w1b, w2b);
    in_conv_kernel<<<BT / 64, 512, 0, stream>>>(x, winb, b_in, norm_w, z, zn_a);

    static const int dil[NL] = {1,2,4,8,16,32,64,128,256,512,
                                1,2,4,8,16,32,64,128,256,512};
    for (int i = 0; i < NL; ++i) {
        const bf16* zi = (i & 1) ? zn_b : zn_a;
        bf16* zo_      = (i & 1) ? zn_a : zn_b;
        int mode = (i == 0) ? 0 : ((i == NL - 1) ? 2 : 1);
        const float* nw = (i == NL - 1) ? hnw : (norm_w + (size_t)(i + 1) * 256);
        layer_kernel<<<BT / 64, 512, 0, stream>>>(zi, zo_, z, sum,
            wf0 + (size_t)i * 65536, wf1 + (size_t)i * 65536,
            wg0 + (size_t)i * 65536, wg1 + (size_t)i * 65536,
            wr + (size_t)i * 65536, ws + (size_t)i * 65536,
            b_f + i * 256, b_g + i * 256, b_r + i * 256, b_s + i * 256,
            nw, dil[i], mode);
    }
    // NL=20 even: last layer wrote zn_a
    head_kernel<<<BT / 64, 256, 0, stream>>>(zn_a, w1b, b1, w2b, b2, (float*)d_out);
}

// Round 5
// 4412.395 us; speedup vs baseline: 1.6394x; 1.1667x over previous
//
#include <hip/hip_runtime.h>
#include <hip/hip_bf16.h>

#define T 4096
#define BT (16*4096)
#define NL 20
#define TPB 4608   // 512 pad + 4096 tokens per batch
#define PAD 512

typedef __bf16 bf16;
typedef __bf16 v8bf __attribute__((ext_vector_type(8)));
typedef float v4f __attribute__((ext_vector_type(4)));
typedef unsigned int uint32;
typedef unsigned short ushort16;

#define MFMA(a,b,c) __builtin_amdgcn_mfma_f32_16x16x32_bf16((a),(b),(c),0,0,0)

__device__ __forceinline__ int swz512(int row, int bc)  { return row*512  + (bc ^ ((row&7)<<4)); }

__device__ __forceinline__ void gload16(const void* g, void* l) {
    __builtin_amdgcn_global_load_lds(
        (const __attribute__((address_space(1))) void*)g,
        (__attribute__((address_space(3))) void*)l, 16, 0, 0);
}

__device__ __forceinline__ ushort16 bfbits(float v) {
    bf16 h = (bf16)v; return *(ushort16*)&h;
}
__device__ __forceinline__ uint32 pack2(float zf, float sf) {
    return (uint32)bfbits(zf) | ((uint32)bfbits(sf) << 16);
}
__device__ __forceinline__ float lo_f(uint32 v) { uint32 t = v << 16;          return *(float*)&t; }
__device__ __forceinline__ float hi_f(uint32 v) { uint32 t = v & 0xffff0000u;  return *(float*)&t; }

// ---------------- zero the per-batch pad stripes of both zn buffers ----------------
__global__ void zero_pads(bf16* __restrict__ zn_a, bf16* __restrict__ zn_b) {
    int idx = blockIdx.x * 256 + threadIdx.x;      // 2*16*16384 uint4
    int buf = idx >> 18;
    int r = idx & 262143;
    int b = r >> 14, off = r & 16383;              // pad = 512 rows * 32 uint4
    bf16* base = buf ? zn_b : zn_a;
    ((uint4*)(base + (size_t)b * TPB * 256))[off] = make_uint4(0, 0, 0, 0);
}

// ---------------- prep kernels: cast/reorder weights to bf16 ----------------
__global__ void prep_w2(const float* __restrict__ Wf, const float* __restrict__ Wg,
                        bf16* __restrict__ wf0, bf16* __restrict__ wf1,
                        bf16* __restrict__ wg0, bf16* __restrict__ wg1) {
    int idx = blockIdx.x * 256 + threadIdx.x;       // NL*256*256
    const float* pf = Wf + (size_t)idx * 2;
    wf0[idx] = (bf16)pf[0]; wf1[idx] = (bf16)pf[1];
    const float* pg = Wg + (size_t)idx * 2;
    wg0[idx] = (bf16)pg[0]; wg1[idx] = (bf16)pg[1];
}

__global__ void prep_w1(const float* __restrict__ Wr, const float* __restrict__ Ws,
                        bf16* __restrict__ wr, bf16* __restrict__ ws) {
    int idx = blockIdx.x * 256 + threadIdx.x;       // NL*256*256
    wr[idx] = (bf16)Wr[idx]; ws[idx] = (bf16)Ws[idx];
}

__global__ void prep_misc(const float* __restrict__ W_in, const float* __restrict__ W1,
                          const float* __restrict__ W2,
                          bf16* __restrict__ winb, bf16* __restrict__ w1b, bf16* __restrict__ w2b) {
    int idx = blockIdx.x * 256 + threadIdx.x;       // 458752 total
    if (idx < 65536) {
        int c = idx >> 8, jj = idx & 255, k = jj >> 3, ci = jj & 7;
        winb[idx] = (bf16)W_in[c * 256 + ci * 32 + k];   // winb[c][k*8+ci]
    } else if (idx < 327680) {
        int j = idx - 65536; w1b[j] = (bf16)W1[j];
    } else {
        int j = idx - 327680; w2b[j] = (bf16)W2[j];
    }
}

// ---------------- fused input conv + RMSNorm(norm_w[0]) ----------------
__global__ __launch_bounds__(512, 4) void in_conv_kernel(
    const float* __restrict__ x, const bf16* __restrict__ winb,
    const float* __restrict__ b_in, const float* __restrict__ nw0,
    uint32* __restrict__ zs, bf16* __restrict__ znout) {
    __shared__ __align__(16) char smem[65536];
    char* cW  = smem + 32768;                 // window tile
    char* cZn = smem;                         // zn staging
    float* rsq = (float*)(smem + 32768);      // alias cW after GEMM reads
    const int tid = threadIdx.x;
    const int g0 = blockIdx.x * 64;
    const int tl0 = g0 & (T - 1);
    const size_t pr0 = (size_t)(g0 >> 12) * TPB + PAD + tl0;
    for (int i = 0; i < 4; ++i) {
        int ch = tid + i * 512;
        int r = ch >> 5, c16 = ch & 31;
        int tok = tl0 + r - 31 + c16;
        bf16 t8[8] = {};
        if (tok >= 0) {
            const float* xr = x + (size_t)(g0 + r - 31 + c16) * 8;
            float4 xa = ((const float4*)xr)[0];
            float4 xb4 = ((const float4*)xr)[1];
            t8[0]=(bf16)xa.x; t8[1]=(bf16)xa.y; t8[2]=(bf16)xa.z; t8[3]=(bf16)xa.w;
            t8[4]=(bf16)xb4.x; t8[5]=(bf16)xb4.y; t8[6]=(bf16)xb4.z; t8[7]=(bf16)xb4.w;
        }
        *(uint4*)(cW + swz512(r, c16 * 16)) = *(uint4*)t8;
    }
    __syncthreads();
    const int lane = tid & 63, w = tid >> 6;
    const int wm = w >> 2, wn = w & 3;
    const int l15 = lane & 15, l4 = lane >> 4;
    const int r0 = wm * 32, c0 = wn * 64;
    const size_t gbase = (size_t)(g0 + r0 + l4*4) * 256 + c0 + l15;
    v4f acc[2][4] = {};
    #pragma unroll
    for (int ks = 0; ks < 8; ++ks) {
        v8bf a[2];
        #pragma unroll
        for (int m = 0; m < 2; ++m)
            a[m] = *(const v8bf*)(cW + swz512(r0 + m*16 + l15, ks*64 + l4*16));
        #pragma unroll
        for (int nf = 0; nf < 4; ++nf) {
            v8bf b = *(const v8bf*)(winb + (size_t)(c0 + nf*16 + l15)*256 + ks*32 + l4*8);
            #pragma unroll
            for (int m = 0; m < 2; ++m) acc[m][nf] = MFMA(a[m], b, acc[m][nf]);
        }
    }
    __syncthreads();                                  // S2: window reads done
    float p8[2][4] = {};
    uint32 zpk[2][4][2] = {};
    #pragma unroll
    for (int m = 0; m < 2; ++m)
        #pragma unroll
        for (int nf = 0; nf < 4; ++nf) {
            int col = c0 + nf*16 + l15;
            float bv = b_in[col];
            #pragma unroll
            for (int j = 0; j < 4; ++j) {
                float zf = acc[m][nf][j] + bv;
                zs[gbase + (size_t)(m*16 + j)*256 + nf*16] = pack2(zf, 0.f);
                p8[m][j] += zf * zf;
                zpk[m][nf][j>>1] |= (uint32)bfbits(zf) << ((j&1)*16);
            }
        }
    #pragma unroll
    for (int m = 0; m < 2; ++m)
        #pragma unroll
        for (int j = 0; j < 4; ++j) {
            float p = p8[m][j];
            p += __shfl_xor(p,1); p += __shfl_xor(p,2); p += __shfl_xor(p,4); p += __shfl_xor(p,8);
            if (l15 == 0) rsq[(r0 + m*16 + l4*4 + j)*5 + wn] = p;
        }
    __syncthreads();                                  // S3: rsq ready
    #pragma unroll
    for (int m = 0; m < 2; ++m)
        #pragma unroll
        for (int j = 0; j < 4; ++j) {
            int row = r0 + m*16 + l4*4 + j;
            float iv = rsqrtf((rsq[row*5]+rsq[row*5+1]+rsq[row*5+2]+rsq[row*5+3])*(1.f/256.f) + 1e-6f);
            #pragma unroll
            for (int nf = 0; nf < 4; ++nf) {
                int col = c0 + nf*16 + l15;
                uint32 t = (zpk[m][nf][j>>1] >> ((j&1)*16)) << 16;
                float zf = *(float*)&t;
                *(bf16*)(cZn + swz512(row, col*2)) = (bf16)(zf * iv * nw0[col]);
            }
        }
    __syncthreads();                                  // S4
    #pragma unroll
    for (int k = 0; k < 4; ++k) {
        int idx = tid + k * 512;
        int row = idx >> 5, d = idx & 31;
        uint4 v = *(uint4*)(cZn + swz512(row, d*16));
        *((uint4*)(znout + (pr0 + row) * 256) + d) = v;
    }
}

// ---------------- fused gated-residual layer + next-layer RMSNorm ----------------
// mode: 1 = normal, 2 = last (no z update; relu+head-norm -> on)
__global__ __launch_bounds__(512, 4) void layer_kernel(
    const bf16* __restrict__ znin, bf16* __restrict__ znout, uint32* __restrict__ zs,
    const bf16* __restrict__ wf0, const bf16* __restrict__ wf1,
    const bf16* __restrict__ wg0, const bf16* __restrict__ wg1,
    const bf16* __restrict__ wr, const bf16* __restrict__ wsm,
    const float* __restrict__ bfp, const float* __restrict__ bgp,
    const float* __restrict__ brp, const float* __restrict__ bsp,
    const float* __restrict__ nw, int dil, int mode) {
    __shared__ __align__(16) char smem[65536];
    char* cA0 = smem;                     // zn[t-d] tile -> U tile -> zn-out staging
    char* cA1 = smem + 32768;             // zn[t] tile
    float* rsq = (float*)(smem + 32768);  // alias cA1 (free after GEMM1)
    const int tid = threadIdx.x;
    const int lane = tid & 63, w = tid >> 6;
    const int g0 = blockIdx.x * 64;
    const size_t pr0 = (size_t)(g0 >> 12) * TPB + PAD + (g0 & (T - 1));

    // async stage zn[t]->cA1, zn[t-dil]->cA0 with pre-swizzled global source
    {
        int rl = w * 8 + (lane >> 5);
        int d = lane & 31;
        #pragma unroll
        for (int j = 0; j < 4; ++j) {
            int r = rl + j * 2;
            int s = d ^ (r & 7);
            gload16(znin + (pr0 + r) * 256 + s * 8,       cA1 + (w*8 + j*2) * 512);
            gload16(znin + (pr0 + r - dil) * 256 + s * 8, cA0 + (w*8 + j*2) * 512);
        }
    }

    const int wm = w >> 2, wn = w & 3;
    const int l15 = lane & 15, l4 = lane >> 4;
    const int r0 = wm * 32, c0 = wn * 64;
    const size_t gbase = (size_t)(g0 + r0 + l4*4) * 256 + c0 + l15;

    __syncthreads();                               // S1

    // ---- GEMM1 pass f ----
    uint32 pf[2][4][2];
    {
        v4f accf[2][4] = {};
        #pragma unroll
        for (int ks = 0; ks < 8; ++ks) {
            v8bf a0[2], a1[2];
            #pragma unroll
            for (int m = 0; m < 2; ++m) {
                int off = swz512(r0 + m*16 + l15, ks*64 + l4*16);
                a0[m] = *(const v8bf*)(cA0 + off);
                a1[m] = *(const v8bf*)(cA1 + off);
            }
            #pragma unroll
            for (int nf = 0; nf < 4; ++nf) {
                size_t bo = (size_t)(c0 + nf*16 + l15) * 256 + ks*32 + l4*8;
                v8bf b0 = *(const v8bf*)(wf0 + bo);
                v8bf b1 = *(const v8bf*)(wf1 + bo);
                #pragma unroll
                for (int m = 0; m < 2; ++m) {
                    accf[m][nf] = MFMA(a0[m], b0, accf[m][nf]);
                    accf[m][nf] = MFMA(a1[m], b1, accf[m][nf]);
                }
            }
        }
        // tanh(f) -> packed bf16 pairs
        #pragma unroll
        for (int m = 0; m < 2; ++m)
            #pragma unroll
            for (int nf = 0; nf < 4; ++nf) {
                float bfv = bfp[c0 + nf*16 + l15];
                uint32 lo, hi;
                {
                    float fv = fminf(fmaxf(accf[m][nf][0] + bfv, -20.f), 20.f);
                    float e2 = __expf(-2.f * fv); float th = (1.f - e2) / (1.f + e2);
                    lo = (uint32)bfbits(th);
                    fv = fminf(fmaxf(accf[m][nf][1] + bfv, -20.f), 20.f);
                    e2 = __expf(-2.f * fv); th = (1.f - e2) / (1.f + e2);
                    lo |= (uint32)bfbits(th) << 16;
                    fv = fminf(fmaxf(accf[m][nf][2] + bfv, -20.f), 20.f);
                    e2 = __expf(-2.f * fv); th = (1.f - e2) / (1.f + e2);
                    hi = (uint32)bfbits(th);
                    fv = fminf(fmaxf(accf[m][nf][3] + bfv, -20.f), 20.f);
                    e2 = __expf(-2.f * fv); th = (1.f - e2) / (1.f + e2);
                    hi |= (uint32)bfbits(th) << 16;
                }
                pf[m][nf][0] = lo; pf[m][nf][1] = hi;
            }
    }

    // ---- GEMM1 pass g ----
    v4f accg[2][4] = {};
    #pragma unroll
    for (int ks = 0; ks < 8; ++ks) {
        v8bf a0[2], a1[2];
        #pragma unroll
        for (int m = 0; m < 2; ++m) {
            int off = swz512(r0 + m*16 + l15, ks*64 + l4*16);
            a0[m] = *(const v8bf*)(cA0 + off);
            a1[m] = *(const v8bf*)(cA1 + off);
        }
        #pragma unroll
        for (int nf = 0; nf < 4; ++nf) {
            size_t bo = (size_t)(c0 + nf*16 + l15) * 256 + ks*32 + l4*8;
            v8bf b2 = *(const v8bf*)(wg0 + bo);
            v8bf b3 = *(const v8bf*)(wg1 + bo);
            #pragma unroll
            for (int m = 0; m < 2; ++m) {
                accg[m][nf] = MFMA(a0[m], b2, accg[m][nf]);
                accg[m][nf] = MFMA(a1[m], b3, accg[m][nf]);
            }
        }
    }
    __syncthreads();                               // S2: tile reads done

    // epilogue 1: u = tanh_f * sigmoid(g) -> cA0 as bf16
    #pragma unroll
    for (int m = 0; m < 2; ++m)
        #pragma unroll
        for (int nf = 0; nf < 4; ++nf) {
            int col = c0 + nf*16 + l15;
            float bgv = bgp[col];
            #pragma unroll
            for (int j = 0; j < 4; ++j) {
                float gv = accg[m][nf][j] + bgv;
                float sg = 1.f / (1.f + __expf(-gv));
                uint32 t = (pf[m][nf][j>>1] >> ((j&1)*16)) << 16;
                float th = *(float*)&t;
                int row = r0 + m*16 + l4*4 + j;
                *(bf16*)(cA0 + swz512(row, col*2)) = (bf16)(th * sg);
            }
        }
    __syncthreads();                               // S3

    // ---- GEMM2 ----
    v4f accr[2][4] = {}, accs[2][4] = {};
    if (mode != 2) {
        #pragma unroll
        for (int ks = 0; ks < 8; ++ks) {
            v8bf a[2];
            #pragma unroll
            for (int m = 0; m < 2; ++m)
                a[m] = *(const v8bf*)(cA0 + swz512(r0 + m*16 + l15, ks*64 + l4*16));
            #pragma unroll
            for (int nf = 0; nf < 4; ++nf) {
                size_t bo = (size_t)(c0 + nf*16 + l15) * 256 + ks*32 + l4*8;
                v8bf br_ = *(const v8bf*)(wr + bo);
                v8bf bs_ = *(const v8bf*)(wsm + bo);
                #pragma unroll
                for (int m = 0; m < 2; ++m) {
                    accr[m][nf] = MFMA(a[m], br_, accr[m][nf]);
                    accs[m][nf] = MFMA(a[m], bs_, accs[m][nf]);
                }
            }
        }
    } else {
        #pragma unroll
        for (int ks = 0; ks < 8; ++ks) {
            v8bf a[2];
            #pragma unroll
            for (int m = 0; m < 2; ++m)
                a[m] = *(const v8bf*)(cA0 + swz512(r0 + m*16 + l15, ks*64 + l4*16));
            #pragma unroll
            for (int nf = 0; nf < 4; ++nf) {
                size_t bo = (size_t)(c0 + nf*16 + l15) * 256 + ks*32 + l4*8;
                v8bf bs_ = *(const v8bf*)(wsm + bo);
                #pragma unroll
                for (int m = 0; m < 2; ++m)
                    accs[m][nf] = MFMA(a[m], bs_, accs[m][nf]);
            }
        }
    }

    // ---- residual/skip RMW + rsq partials ----
    float p8[2][4] = {};
    uint32 zpk[2][4][2] = {};
    if (mode != 2) {
        #pragma unroll
        for (int m = 0; m < 2; ++m)
            #pragma unroll
            for (int nf = 0; nf < 4; ++nf) {
                int col = c0 + nf*16 + l15;
                float brv = brp[col], bsv = bsp[col];
                #pragma unroll
                for (int j = 0; j < 4; ++j) {
                    size_t idx = gbase + (size_t)(m*16 + j)*256 + nf*16;
                    uint32 old = zs[idx];
                    float zf = lo_f(old) + accr[m][nf][j] + brv;
                    float sf = hi_f(old) + accs[m][nf][j] + bsv;
                    zs[idx] = pack2(zf, sf);
                    p8[m][j] += zf * zf;
                    zpk[m][nf][j>>1] |= (uint32)bfbits(zf) << ((j&1)*16);
                }
            }
    } else {
        #pragma unroll
        for (int m = 0; m < 2; ++m)
            #pragma unroll
            for (int nf = 0; nf < 4; ++nf) {
                int col = c0 + nf*16 + l15;
                float bsv = bsp[col];
                #pragma unroll
                for (int j = 0; j < 4; ++j) {
                    size_t idx = gbase + (size_t)(m*16 + j)*256 + nf*16;
                    uint32 old = zs[idx];
                    float of = fmaxf(hi_f(old) + accs[m][nf][j] + bsv, 0.f);
                    p8[m][j] += of * of;
                    zpk[m][nf][j>>1] |= (uint32)bfbits(of) << ((j&1)*16);
                }
            }
    }
    #pragma unroll
    for (int m = 0; m < 2; ++m)
        #pragma unroll
        for (int j = 0; j < 4; ++j) {
            float p = p8[m][j];
            p += __shfl_xor(p,1); p += __shfl_xor(p,2); p += __shfl_xor(p,4); p += __shfl_xor(p,8);
            if (l15 == 0) rsq[(r0 + m*16 + l4*4 + j)*5 + wn] = p;
        }
    __syncthreads();                               // S4: GEMM2 reads + rsq done

    // zn staging (bf16, swizzled) into cA0
    #pragma unroll
    for (int m = 0; m < 2; ++m)
        #pragma unroll
        for (int j = 0; j < 4; ++j) {
            int row = r0 + m*16 + l4*4 + j;
            float iv = rsqrtf((rsq[row*5]+rsq[row*5+1]+rsq[row*5+2]+rsq[row*5+3])*(1.f/256.f) + 1e-6f);
            #pragma unroll
            for (int nf = 0; nf < 4; ++nf) {
                int col = c0 + nf*16 + l15;
                uint32 t = (zpk[m][nf][j>>1] >> ((j&1)*16)) << 16;
                float zf = *(float*)&t;
                *(bf16*)(cA0 + swz512(row, col*2)) = (bf16)(zf * iv * nw[col]);
            }
        }
    __syncthreads();                               // S5

    // coalesced zn copyout (padded layout)
    #pragma unroll
    for (int k = 0; k < 4; ++k) {
        int idx = tid + k * 512;
        int row = idx >> 5, d = idx & 31;
        uint4 v = *(uint4*)(cA0 + swz512(row, d*16));
        *((uint4*)(znout + (pr0 + row) * 256) + d) = v;
    }
}

// ---------------- fused head: on @ W1 -> relu -> @ W2 ----------------
__global__ __launch_bounds__(256, 2) void head_kernel(
    const bf16* __restrict__ on, const bf16* __restrict__ w1b, const float* __restrict__ b1,
    const bf16* __restrict__ w2b, const float* __restrict__ b2, float* __restrict__ out) {
    __shared__ uint4 sOn[2048];
    __shared__ uint4 sH[2048];
    char* cOn = (char*)sOn; char* cH = (char*)sH;
    const int tid = threadIdx.x;
    const int g0 = blockIdx.x * 64;
    const size_t pr0 = (size_t)(g0 >> 12) * TPB + PAD + (g0 & (T - 1));
    for (int i = 0; i < 8; ++i) {
        int ch = tid + i * 256;
        int r = ch >> 5, c16 = ch & 31;
        *(uint4*)(cOn + swz512(r, c16 * 16)) = *((const uint4*)(on + (pr0 + r) * 256) + c16);
    }
    __syncthreads();
    const int lane = tid & 63, w = tid >> 6;
    const int wm = w >> 1, wn = w & 1;
    const int l15 = lane & 15, l4 = lane >> 4;
    v4f acc2[2][4] = {};
    for (int hc = 0; hc < 4; ++hc) {
        v4f acch[2][8] = {};
        for (int ks = 0; ks < 8; ++ks) {
            v8bf a[2];
            for (int m = 0; m < 2; ++m)
                a[m] = *(const v8bf*)(cOn + swz512(wm*32 + m*16 + l15, ks*64 + l4*16));
            for (int nf = 0; nf < 8; ++nf) {
                int h = hc * 256 + wn * 128 + nf * 16 + l15;
                v8bf b = *(const v8bf*)(w1b + (size_t)h * 256 + ks * 32 + l4 * 8);
                for (int m = 0; m < 2; ++m) acch[m][nf] = MFMA(a[m], b, acch[m][nf]);
            }
        }
        __syncthreads();
        for (int m = 0; m < 2; ++m)
            for (int nf = 0; nf < 8; ++nf) {
                int coll = wn * 128 + nf * 16 + l15;
                float b1v = b1[hc * 256 + coll];
                for (int j = 0; j < 4; ++j) {
                    int row = wm * 32 + m * 16 + l4 * 4 + j;
                    float hv = fmaxf(acch[m][nf][j] + b1v, 0.f);
                    *(bf16*)(cH + swz512(row, coll * 2)) = (bf16)hv;
                }
            }
        __syncthreads();
        for (int ks = 0; ks < 8; ++ks) {
            v8bf a[2];
            for (int m = 0; m < 2; ++m)
                a[m] = *(const v8bf*)(cH + swz512(wm*32 + m*16 + l15, ks*64 + l4*16));
            for (int nf = 0; nf < 4; ++nf) {
                int o = wn * 64 + nf * 16 + l15;
                v8bf b = *(const v8bf*)(w2b + (size_t)o * 1024 + hc * 256 + ks * 32 + l4 * 8);
                for (int m = 0; m < 2; ++m) acc2[m][nf] = MFMA(a[m], b, acc2[m][nf]);
            }
        }
    }
    for (int m = 0; m < 2; ++m)
        for (int nf = 0; nf < 4; ++nf) {
            int o = wn * 64 + nf * 16 + l15;
            float b2v = b2[o];
            for (int j = 0; j < 4; ++j) {
                int row = wm * 32 + m * 16 + l4 * 4 + j;
                out[(size_t)(g0 + row) * 128 + o] = acc2[m][nf][j] + b2v;
            }
        }
}

extern "C" void kernel_launch(void* const* d_in, const int* in_sizes, int n_in,
                              void* d_out, int out_size, void* d_ws, size_t ws_size,
                              hipStream_t stream) {
    const float* x      = (const float*)d_in[0];
    const float* W_in   = (const float*)d_in[1];
    const float* b_in   = (const float*)d_in[2];
    const float* W_f    = (const float*)d_in[3];
    const float* b_f    = (const float*)d_in[4];
    const float* W_g    = (const float*)d_in[5];
    const float* b_g    = (const float*)d_in[6];
    const float* W_r    = (const float*)d_in[7];
    const float* b_r    = (const float*)d_in[8];
    const float* W_s    = (const float*)d_in[9];
    const float* b_s    = (const float*)d_in[10];
    const float* norm_w = (const float*)d_in[11];
    const float* hnw    = (const float*)d_in[12];
    const float* W1     = (const float*)d_in[13];
    const float* b1     = (const float*)d_in[14];
    const float* W2     = (const float*)d_in[15];
    const float* b2     = (const float*)d_in[16];

    char* p = (char*)d_ws;
    uint32* zs  = (uint32*)p;          p += (size_t)BT * 256 * 4;
    bf16* zn_a  = (bf16*)p;            p += (size_t)16 * TPB * 256 * 2;
    bf16* zn_b  = (bf16*)p;            p += (size_t)16 * TPB * 256 * 2;
    bf16* wf0   = (bf16*)p;            p += (size_t)NL * 65536 * 2;
    bf16* wf1   = (bf16*)p;            p += (size_t)NL * 65536 * 2;
    bf16* wg0   = (bf16*)p;            p += (size_t)NL * 65536 * 2;
    bf16* wg1   = (bf16*)p;            p += (size_t)NL * 65536 * 2;
    bf16* wr    = (bf16*)p;            p += (size_t)NL * 65536 * 2;
    bf16* ws    = (bf16*)p;            p += (size_t)NL * 65536 * 2;
    bf16* winb  = (bf16*)p;            p += 65536 * 2;
    bf16* w1b   = (bf16*)p;            p += 262144 * 2;
    bf16* w2b   = (bf16*)p;            p += 131072 * 2;

    zero_pads<<<2048, 256, 0, stream>>>(zn_a, zn_b);
    prep_w2<<<NL * 256, 256, 0, stream>>>(W_f, W_g, wf0, wf1, wg0, wg1);
    prep_w1<<<NL * 256, 256, 0, stream>>>(W_r, W_s, wr, ws);
    prep_misc<<<1792, 256, 0, stream>>>(W_in, W1, W2, winb, w1b, w2b);
    in_conv_kernel<<<BT / 64, 512, 0, stream>>>(x, winb, b_in, norm_w, zs, zn_a);

    static const int dil[NL] = {1,2,4,8,16,32,64,128,256,512,
                                1,2,4,8,16,32,64,128,256,512};
    for (int i = 0; i < NL; ++i) {
        const bf16* zi = (i & 1) ? zn_b : zn_a;
        bf16* zo_      = (i & 1) ? zn_a : zn_b;
        int mode = (i == NL - 1) ? 2 : 1;
        const float* nw = (i == NL - 1) ? hnw : (norm_w + (size_t)(i + 1) * 256);
        layer_kernel<<<BT / 64, 512, 0, stream>>>(zi, zo_, zs,
            wf0 + (size_t)i * 65536, wf1 + (size_t)i * 65536,
            wg0 + (size_t)i * 65536, wg1 + (size_t)i * 65536,
            wr + (size_t)i * 65536, ws + (size_t)i * 65536,
            b_f + i * 256, b_g + i * 256, b_r + i * 256, b_s + i * 256,
            nw, dil[i], mode);
    }
    // NL=20 even: last layer wrote zn_a
    head_kernel<<<BT / 64, 256, 0, stream>>>(zn_a, w1b, b1, w2b, b2, (float*)d_out);
}

// Round 6
// 4313.854 us; speedup vs baseline: 1.6768x; 1.0228x over previous
//
#include <hip/hip_runtime.h>
#include <hip/hip_bf16.h>

#define T 4096
#define BT (16*4096)
#define NL 20
#define TPB 4608   // 512 pad + 4096 tokens per batch
#define PAD 512

typedef __bf16 bf16;
typedef __bf16 v8bf __attribute__((ext_vector_type(8)));
typedef float v4f __attribute__((ext_vector_type(4)));
typedef unsigned int uint32;
typedef unsigned short ushort16;

#define MFMA(a,b,c) __builtin_amdgcn_mfma_f32_16x16x32_bf16((a),(b),(c),0,0,0)

__device__ __forceinline__ int swz512(int row, int bc)  { return row*512  + (bc ^ ((row&7)<<4)); }

__device__ __forceinline__ void gload16(const void* g, void* l) {
    __builtin_amdgcn_global_load_lds(
        (const __attribute__((address_space(1))) void*)g,
        (__attribute__((address_space(3))) void*)l, 16, 0, 0);
}

__device__ __forceinline__ ushort16 bfbits(float v) {
    bf16 h = (bf16)v; return *(ushort16*)&h;
}
__device__ __forceinline__ uint32 pack2(float zf, float sf) {
    return (uint32)bfbits(zf) | ((uint32)bfbits(sf) << 16);
}
__device__ __forceinline__ float lo_f(uint32 v) { uint32 t = v << 16;          return *(float*)&t; }
__device__ __forceinline__ float hi_f(uint32 v) { uint32 t = v & 0xffff0000u;  return *(float*)&t; }
__device__ __forceinline__ float sel_f(uint32 pair, int j) {  // j&1: 0=lo,1=hi
    uint32 t = (j & 1) ? (pair & 0xffff0000u) : (pair << 16);
    return *(float*)&t;
}
__device__ __forceinline__ float tanh_clamped(float fv) {
    fv = fminf(fmaxf(fv, -20.f), 20.f);
    float e2 = __expf(-2.f * fv);
    return (1.f - e2) / (1.f + e2);
}

// ---------------- zero the per-batch pad stripes of both zn buffers ----------------
__global__ void zero_pads(bf16* __restrict__ zn_a, bf16* __restrict__ zn_b) {
    int idx = blockIdx.x * 256 + threadIdx.x;      // 2*16*16384 uint4
    int buf = idx >> 18;
    int r = idx & 262143;
    int b = r >> 14, off = r & 16383;              // pad = 512 rows * 32 uint4
    bf16* base = buf ? zn_b : zn_a;
    ((uint4*)(base + (size_t)b * TPB * 256))[off] = make_uint4(0, 0, 0, 0);
}

// ---------------- prep kernels: cast/reorder weights to bf16 ----------------
__global__ void prep_w2(const float* __restrict__ Wf, const float* __restrict__ Wg,
                        bf16* __restrict__ wf0, bf16* __restrict__ wf1,
                        bf16* __restrict__ wg0, bf16* __restrict__ wg1) {
    int idx = blockIdx.x * 256 + threadIdx.x;       // NL*256*256
    const float* pf = Wf + (size_t)idx * 2;
    wf0[idx] = (bf16)pf[0]; wf1[idx] = (bf16)pf[1];
    const float* pg = Wg + (size_t)idx * 2;
    wg0[idx] = (bf16)pg[0]; wg1[idx] = (bf16)pg[1];
}

__global__ void prep_w1(const float* __restrict__ Wr, const float* __restrict__ Ws,
                        bf16* __restrict__ wr, bf16* __restrict__ ws) {
    int idx = blockIdx.x * 256 + threadIdx.x;       // NL*256*256
    wr[idx] = (bf16)Wr[idx]; ws[idx] = (bf16)Ws[idx];
}

__global__ void prep_misc(const float* __restrict__ W_in, const float* __restrict__ W1,
                          const float* __restrict__ W2,
                          bf16* __restrict__ winb, bf16* __restrict__ w1b, bf16* __restrict__ w2b) {
    int idx = blockIdx.x * 256 + threadIdx.x;       // 458752 total
    if (idx < 65536) {
        int c = idx >> 8, jj = idx & 255, k = jj >> 3, ci = jj & 7;
        winb[idx] = (bf16)W_in[c * 256 + ci * 32 + k];   // winb[c][k*8+ci]
    } else if (idx < 327680) {
        int j = idx - 65536; w1b[j] = (bf16)W1[j];
    } else {
        int j = idx - 327680; w2b[j] = (bf16)W2[j];
    }
}

// ---------------- fused input conv + RMSNorm(norm_w[0]) ----------------
__global__ __launch_bounds__(512, 4) void in_conv_kernel(
    const float* __restrict__ x, const bf16* __restrict__ winb,
    const float* __restrict__ b_in, const float* __restrict__ nw0,
    uint32* __restrict__ zs, bf16* __restrict__ znout) {
    __shared__ __align__(16) char smem[65536];
    char* cW  = smem + 32768;                 // window tile
    char* cZn = smem;                         // zn staging
    float* rsq = (float*)(smem + 32768);      // alias cW after GEMM reads
    const int tid = threadIdx.x;
    const int g0 = blockIdx.x * 64;
    const int tl0 = g0 & (T - 1);
    const size_t pr0 = (size_t)(g0 >> 12) * TPB + PAD + tl0;
    for (int i = 0; i < 4; ++i) {
        int ch = tid + i * 512;
        int r = ch >> 5, c16 = ch & 31;
        int tok = tl0 + r - 31 + c16;
        bf16 t8[8] = {};
        if (tok >= 0) {
            const float* xr = x + (size_t)(g0 + r - 31 + c16) * 8;
            float4 xa = ((const float4*)xr)[0];
            float4 xb4 = ((const float4*)xr)[1];
            t8[0]=(bf16)xa.x; t8[1]=(bf16)xa.y; t8[2]=(bf16)xa.z; t8[3]=(bf16)xa.w;
            t8[4]=(bf16)xb4.x; t8[5]=(bf16)xb4.y; t8[6]=(bf16)xb4.z; t8[7]=(bf16)xb4.w;
        }
        *(uint4*)(cW + swz512(r, c16 * 16)) = *(uint4*)t8;
    }
    __syncthreads();
    const int lane = tid & 63, w = tid >> 6;
    const int wm = w >> 2, wn = w & 3;
    const int l15 = lane & 15, l4 = lane >> 4;
    const int r0 = wm * 32, c0 = wn * 64;
    const size_t gbase = (size_t)(g0 + r0 + l4*4) * 256 + c0 + l15;
    float p8[2][4] = {};
    uint32 zpk[2][4][2] = {};
    #pragma unroll
    for (int half = 0; half < 2; ++half) {
        v4f acc[2][2] = {};
        #pragma unroll
        for (int ks = 0; ks < 8; ++ks) {
            v8bf a[2];
            #pragma unroll
            for (int m = 0; m < 2; ++m)
                a[m] = *(const v8bf*)(cW + swz512(r0 + m*16 + l15, ks*64 + l4*16));
            #pragma unroll
            for (int nh = 0; nh < 2; ++nh) {
                int nf = half*2 + nh;
                v8bf b = *(const v8bf*)(winb + (size_t)(c0 + nf*16 + l15)*256 + ks*32 + l4*8);
                #pragma unroll
                for (int m = 0; m < 2; ++m) acc[m][nh] = MFMA(a[m], b, acc[m][nh]);
            }
        }
        #pragma unroll
        for (int m = 0; m < 2; ++m)
            #pragma unroll
            for (int nh = 0; nh < 2; ++nh) {
                int nf = half*2 + nh;
                float bv = b_in[c0 + nf*16 + l15];
                #pragma unroll
                for (int j = 0; j < 4; ++j) {
                    float zf = acc[m][nh][j] + bv;
                    zs[gbase + (size_t)(m*16 + j)*256 + nf*16] = pack2(zf, 0.f);
                    p8[m][j] += zf * zf;
                    zpk[m][nf][j>>1] |= (uint32)bfbits(zf) << ((j&1)*16);
                }
            }
    }
    __syncthreads();                                  // window reads done
    #pragma unroll
    for (int m = 0; m < 2; ++m)
        #pragma unroll
        for (int j = 0; j < 4; ++j) {
            float p = p8[m][j];
            p += __shfl_xor(p,1); p += __shfl_xor(p,2); p += __shfl_xor(p,4); p += __shfl_xor(p,8);
            if (l15 == 0) rsq[(r0 + m*16 + l4*4 + j)*5 + wn] = p;
        }
    __syncthreads();                                  // rsq ready
    #pragma unroll
    for (int m = 0; m < 2; ++m)
        #pragma unroll
        for (int j = 0; j < 4; ++j) {
            int row = r0 + m*16 + l4*4 + j;
            float iv = rsqrtf((rsq[row*5]+rsq[row*5+1]+rsq[row*5+2]+rsq[row*5+3])*(1.f/256.f) + 1e-6f);
            #pragma unroll
            for (int nf = 0; nf < 4; ++nf) {
                int col = c0 + nf*16 + l15;
                float zf = sel_f(zpk[m][nf][j>>1], j);
                *(bf16*)(cZn + swz512(row, col*2)) = (bf16)(zf * iv * nw0[col]);
            }
        }
    __syncthreads();
    #pragma unroll
    for (int k = 0; k < 4; ++k) {
        int idx = tid + k * 512;
        int row = idx >> 5, d = idx & 31;
        uint4 v = *(uint4*)(cZn + swz512(row, d*16));
        *((uint4*)(znout + (pr0 + row) * 256) + d) = v;
    }
}

// ---------------- fused gated-residual layer + next-layer RMSNorm ----------------
// mode: 1 = normal, 2 = last (no z update; relu+head-norm -> on)
__global__ __launch_bounds__(512, 4) void layer_kernel(
    const bf16* __restrict__ znin, bf16* __restrict__ znout, uint32* __restrict__ zs,
    const bf16* __restrict__ wf0, const bf16* __restrict__ wf1,
    const bf16* __restrict__ wg0, const bf16* __restrict__ wg1,
    const bf16* __restrict__ wr, const bf16* __restrict__ wsm,
    const float* __restrict__ bfp, const float* __restrict__ bgp,
    const float* __restrict__ brp, const float* __restrict__ bsp,
    const float* __restrict__ nw, int dil, int mode) {
    __shared__ __align__(16) char smem[65536];
    char* cA0 = smem;                     // zn[t-d] tile -> U tile -> zn-out staging
    char* cA1 = smem + 32768;             // zn[t] tile
    float* rsq = (float*)(smem + 32768);  // alias cA1 (dead after GEMM1)
    const int tid = threadIdx.x;
    const int lane = tid & 63, w = tid >> 6;
    const int g0 = blockIdx.x * 64;
    const size_t pr0 = (size_t)(g0 >> 12) * TPB + PAD + (g0 & (T - 1));

    // async stage zn[t]->cA1, zn[t-dil]->cA0 with pre-swizzled global source
    {
        int rl = w * 8 + (lane >> 5);
        int d = lane & 31;
        #pragma unroll
        for (int j = 0; j < 4; ++j) {
            int r = rl + j * 2;
            int s = d ^ (r & 7);
            gload16(znin + (pr0 + r) * 256 + s * 8,       cA1 + (w*8 + j*2) * 512);
            gload16(znin + (pr0 + r - dil) * 256 + s * 8, cA0 + (w*8 + j*2) * 512);
        }
    }

    const int wm = w >> 2, wn = w & 3;
    const int l15 = lane & 15, l4 = lane >> 4;
    const int r0 = wm * 32, c0 = wn * 64;
    const size_t gbase = (size_t)(g0 + r0 + l4*4) * 256 + c0 + l15;

    __syncthreads();                               // S1

    // ---- GEMM1 in two nf-halves: f-pass then g-pass per half; U kept packed in regs ----
    uint32 upk[2][4][2];                           // [m][nf][jpair] packed bf16 u
    #pragma unroll
    for (int half = 0; half < 2; ++half) {
        uint32 thp[2][2][2];                       // tanh(f) packed, this half
        {
            v4f accf[2][2] = {};
            #pragma unroll
            for (int ks = 0; ks < 8; ++ks) {
                v8bf a0[2], a1[2];
                #pragma unroll
                for (int m = 0; m < 2; ++m) {
                    int off = swz512(r0 + m*16 + l15, ks*64 + l4*16);
                    a0[m] = *(const v8bf*)(cA0 + off);
                    a1[m] = *(const v8bf*)(cA1 + off);
                }
                #pragma unroll
                for (int nh = 0; nh < 2; ++nh) {
                    int nf = half*2 + nh;
                    size_t bo = (size_t)(c0 + nf*16 + l15) * 256 + ks*32 + l4*8;
                    v8bf b0 = *(const v8bf*)(wf0 + bo);
                    v8bf b1 = *(const v8bf*)(wf1 + bo);
                    #pragma unroll
                    for (int m = 0; m < 2; ++m) {
                        accf[m][nh] = MFMA(a0[m], b0, accf[m][nh]);
                        accf[m][nh] = MFMA(a1[m], b1, accf[m][nh]);
                    }
                }
            }
            #pragma unroll
            for (int m = 0; m < 2; ++m)
                #pragma unroll
                for (int nh = 0; nh < 2; ++nh) {
                    float bfv = bfp[c0 + (half*2 + nh)*16 + l15];
                    #pragma unroll
                    for (int jp = 0; jp < 2; ++jp) {
                        uint32 v = (uint32)bfbits(tanh_clamped(accf[m][nh][jp*2]   + bfv));
                        v |= (uint32)bfbits(tanh_clamped(accf[m][nh][jp*2+1] + bfv)) << 16;
                        thp[m][nh][jp] = v;
                    }
                }
        }
        {
            v4f accg[2][2] = {};
            #pragma unroll
            for (int ks = 0; ks < 8; ++ks) {
                v8bf a0[2], a1[2];
                #pragma unroll
                for (int m = 0; m < 2; ++m) {
                    int off = swz512(r0 + m*16 + l15, ks*64 + l4*16);
                    a0[m] = *(const v8bf*)(cA0 + off);
                    a1[m] = *(const v8bf*)(cA1 + off);
                }
                #pragma unroll
                for (int nh = 0; nh < 2; ++nh) {
                    int nf = half*2 + nh;
                    size_t bo = (size_t)(c0 + nf*16 + l15) * 256 + ks*32 + l4*8;
                    v8bf b2 = *(const v8bf*)(wg0 + bo);
                    v8bf b3 = *(const v8bf*)(wg1 + bo);
                    #pragma unroll
                    for (int m = 0; m < 2; ++m) {
                        accg[m][nh] = MFMA(a0[m], b2, accg[m][nh]);
                        accg[m][nh] = MFMA(a1[m], b3, accg[m][nh]);
                    }
                }
            }
            #pragma unroll
            for (int m = 0; m < 2; ++m)
                #pragma unroll
                for (int nh = 0; nh < 2; ++nh) {
                    int nf = half*2 + nh;
                    float bgv = bgp[c0 + nf*16 + l15];
                    #pragma unroll
                    for (int jp = 0; jp < 2; ++jp) {
                        float sg0 = 1.f / (1.f + __expf(-(accg[m][nh][jp*2]   + bgv)));
                        float sg1 = 1.f / (1.f + __expf(-(accg[m][nh][jp*2+1] + bgv)));
                        uint32 v = (uint32)bfbits(sel_f(thp[m][nh][jp], 0) * sg0);
                        v |= (uint32)bfbits(sel_f(thp[m][nh][jp], 1) * sg1) << 16;
                        upk[m][nf][jp] = v;
                    }
                }
        }
    }
    __syncthreads();                               // S2: all GEMM1 tile reads done

    // write U tile (bf16, swizzled) into cA0
    #pragma unroll
    for (int m = 0; m < 2; ++m)
        #pragma unroll
        for (int nf = 0; nf < 4; ++nf) {
            int col = c0 + nf*16 + l15;
            #pragma unroll
            for (int j = 0; j < 4; ++j) {
                int row = r0 + m*16 + l4*4 + j;
                *(bf16*)(cA0 + swz512(row, col*2)) = (bf16)sel_f(upk[m][nf][j>>1], j);
            }
        }
    __syncthreads();                               // S3

    // ---- GEMM2 in two nf-halves, zs old prefetched per half ----
    float p8[2][4] = {};
    uint32 zpk[2][4][2] = {};
    #pragma unroll
    for (int half = 0; half < 2; ++half) {
        uint32 old[2][2][4];
        #pragma unroll
        for (int m = 0; m < 2; ++m)
            #pragma unroll
            for (int nh = 0; nh < 2; ++nh)
                #pragma unroll
                for (int j = 0; j < 4; ++j)
                    old[m][nh][j] = zs[gbase + (size_t)(m*16 + j)*256 + (half*2 + nh)*16];
        v4f accr[2][2] = {}, accs[2][2] = {};
        if (mode != 2) {
            #pragma unroll
            for (int ks = 0; ks < 8; ++ks) {
                v8bf a[2];
                #pragma unroll
                for (int m = 0; m < 2; ++m)
                    a[m] = *(const v8bf*)(cA0 + swz512(r0 + m*16 + l15, ks*64 + l4*16));
                #pragma unroll
                for (int nh = 0; nh < 2; ++nh) {
                    int nf = half*2 + nh;
                    size_t bo = (size_t)(c0 + nf*16 + l15) * 256 + ks*32 + l4*8;
                    v8bf br_ = *(const v8bf*)(wr + bo);
                    v8bf bs_ = *(const v8bf*)(wsm + bo);
                    #pragma unroll
                    for (int m = 0; m < 2; ++m) {
                        accr[m][nh] = MFMA(a[m], br_, accr[m][nh]);
                        accs[m][nh] = MFMA(a[m], bs_, accs[m][nh]);
                    }
                }
            }
        } else {
            #pragma unroll
            for (int ks = 0; ks < 8; ++ks) {
                v8bf a[2];
                #pragma unroll
                for (int m = 0; m < 2; ++m)
                    a[m] = *(const v8bf*)(cA0 + swz512(r0 + m*16 + l15, ks*64 + l4*16));
                #pragma unroll
                for (int nh = 0; nh < 2; ++nh) {
                    int nf = half*2 + nh;
                    size_t bo = (size_t)(c0 + nf*16 + l15) * 256 + ks*32 + l4*8;
                    v8bf bs_ = *(const v8bf*)(wsm + bo);
                    #pragma unroll
                    for (int m = 0; m < 2; ++m)
                        accs[m][nh] = MFMA(a[m], bs_, accs[m][nh]);
                }
            }
        }
        if (mode != 2) {
            #pragma unroll
            for (int m = 0; m < 2; ++m)
                #pragma unroll
                for (int nh = 0; nh < 2; ++nh) {
                    int nf = half*2 + nh;
                    int col = c0 + nf*16 + l15;
                    float brv = brp[col], bsv = bsp[col];
                    #pragma unroll
                    for (int j = 0; j < 4; ++j) {
                        size_t idx = gbase + (size_t)(m*16 + j)*256 + nf*16;
                        float zf = lo_f(old[m][nh][j]) + accr[m][nh][j] + brv;
                        float sf = hi_f(old[m][nh][j]) + accs[m][nh][j] + bsv;
                        zs[idx] = pack2(zf, sf);
                        p8[m][j] += zf * zf;
                        zpk[m][nf][j>>1] |= (uint32)bfbits(zf) << ((j&1)*16);
                    }
                }
        } else {
            #pragma unroll
            for (int m = 0; m < 2; ++m)
                #pragma unroll
                for (int nh = 0; nh < 2; ++nh) {
                    int nf = half*2 + nh;
                    int col = c0 + nf*16 + l15;
                    float bsv = bsp[col];
                    #pragma unroll
                    for (int j = 0; j < 4; ++j) {
                        float of = fmaxf(hi_f(old[m][nh][j]) + accs[m][nh][j] + bsv, 0.f);
                        p8[m][j] += of * of;
                        zpk[m][nf][j>>1] |= (uint32)bfbits(of) << ((j&1)*16);
                    }
                }
        }
    }
    #pragma unroll
    for (int m = 0; m < 2; ++m)
        #pragma unroll
        for (int j = 0; j < 4; ++j) {
            float p = p8[m][j];
            p += __shfl_xor(p,1); p += __shfl_xor(p,2); p += __shfl_xor(p,4); p += __shfl_xor(p,8);
            if (l15 == 0) rsq[(r0 + m*16 + l4*4 + j)*5 + wn] = p;
        }
    __syncthreads();                               // S4: GEMM2 reads + rsq done

    // zn staging (bf16, swizzled) into cA0
    #pragma unroll
    for (int m = 0; m < 2; ++m)
        #pragma unroll
        for (int j = 0; j < 4; ++j) {
            int row = r0 + m*16 + l4*4 + j;
            float iv = rsqrtf((rsq[row*5]+rsq[row*5+1]+rsq[row*5+2]+rsq[row*5+3])*(1.f/256.f) + 1e-6f);
            #pragma unroll
            for (int nf = 0; nf < 4; ++nf) {
                int col = c0 + nf*16 + l15;
                float zf = sel_f(zpk[m][nf][j>>1], j);
                *(bf16*)(cA0 + swz512(row, col*2)) = (bf16)(zf * iv * nw[col]);
            }
        }
    __syncthreads();                               // S5

    // coalesced zn copyout (padded layout)
    #pragma unroll
    for (int k = 0; k < 4; ++k) {
        int idx = tid + k * 512;
        int row = idx >> 5, d = idx & 31;
        uint4 v = *(uint4*)(cA0 + swz512(row, d*16));
        *((uint4*)(znout + (pr0 + row) * 256) + d) = v;
    }
}

// ---------------- fused head: on @ W1 -> relu -> @ W2 (8 waves) ----------------
__global__ __launch_bounds__(512, 4) void head_kernel(
    const bf16* __restrict__ on, const bf16* __restrict__ w1b, const float* __restrict__ b1,
    const bf16* __restrict__ w2b, const float* __restrict__ b2, float* __restrict__ out) {
    __shared__ __align__(16) char smem[65536];
    char* cOn = smem;
    char* cH  = smem + 32768;
    const int tid = threadIdx.x;
    const int g0 = blockIdx.x * 64;
    const size_t pr0 = (size_t)(g0 >> 12) * TPB + PAD + (g0 & (T - 1));
    for (int i = 0; i < 4; ++i) {
        int ch = tid + i * 512;
        int r = ch >> 5, c16 = ch & 31;
        *(uint4*)(cOn + swz512(r, c16 * 16)) = *((const uint4*)(on + (pr0 + r) * 256) + c16);
    }
    __syncthreads();
    const int lane = tid & 63, w = tid >> 6;
    const int wm = w >> 2, wn = w & 3;
    const int l15 = lane & 15, l4 = lane >> 4;
    const int r0 = wm * 32;
    v4f acc2[2][2] = {};
    for (int hc = 0; hc < 4; ++hc) {
        v4f acch[2][4] = {};
        #pragma unroll
        for (int ks = 0; ks < 8; ++ks) {
            v8bf a[2];
            #pragma unroll
            for (int m = 0; m < 2; ++m)
                a[m] = *(const v8bf*)(cOn + swz512(r0 + m*16 + l15, ks*64 + l4*16));
            #pragma unroll
            for (int nf = 0; nf < 4; ++nf) {
                int h = hc * 256 + wn * 64 + nf * 16 + l15;
                v8bf b = *(const v8bf*)(w1b + (size_t)h * 256 + ks * 32 + l4 * 8);
                #pragma unroll
                for (int m = 0; m < 2; ++m) acch[m][nf] = MFMA(a[m], b, acch[m][nf]);
            }
        }
        __syncthreads();   // previous hc's cH reads done
        #pragma unroll
        for (int m = 0; m < 2; ++m)
            #pragma unroll
            for (int nf = 0; nf < 4; ++nf) {
                int coll = wn * 64 + nf * 16 + l15;
                float b1v = b1[hc * 256 + coll];
                #pragma unroll
                for (int j = 0; j < 4; ++j) {
                    int row = r0 + m*16 + l4*4 + j;
                    float hv = fmaxf(acch[m][nf][j] + b1v, 0.f);
                    *(bf16*)(cH + swz512(row, coll * 2)) = (bf16)hv;
                }
            }
        __syncthreads();
        #pragma unroll
        for (int ks = 0; ks < 8; ++ks) {
            v8bf a[2];
            #pragma unroll
            for (int m = 0; m < 2; ++m)
                a[m] = *(const v8bf*)(cH + swz512(r0 + m*16 + l15, ks*64 + l4*16));
            #pragma unroll
            for (int nf = 0; nf < 2; ++nf) {
                int o = wn * 32 + nf * 16 + l15;
                v8bf b = *(const v8bf*)(w2b + (size_t)o * 1024 + hc * 256 + ks * 32 + l4 * 8);
                #pragma unroll
                for (int m = 0; m < 2; ++m) acc2[m][nf] = MFMA(a[m], b, acc2[m][nf]);
            }
        }
    }
    #pragma unroll
    for (int m = 0; m < 2; ++m)
        #pragma unroll
        for (int nf = 0; nf < 2; ++nf) {
            int o = wn * 32 + nf * 16 + l15;
            float b2v = b2[o];
            #pragma unroll
            for (int j = 0; j < 4; ++j) {
                int row = r0 + m*16 + l4*4 + j;
                out[(size_t)(g0 + row) * 128 + o] = acc2[m][nf][j] + b2v;
            }
        }
}

extern "C" void kernel_launch(void* const* d_in, const int* in_sizes, int n_in,
                              void* d_out, int out_size, void* d_ws, size_t ws_size,
                              hipStream_t stream) {
    const float* x      = (const float*)d_in[0];
    const float* W_in   = (const float*)d_in[1];
    const float* b_in   = (const float*)d_in[2];
    const float* W_f    = (const float*)d_in[3];
    const float* b_f    = (const float*)d_in[4];
    const float* W_g    = (const float*)d_in[5];
    const float* b_g    = (const float*)d_in[6];
    const float* W_r    = (const float*)d_in[7];
    const float* b_r    = (const float*)d_in[8];
    const float* W_s    = (const float*)d_in[9];
    const float* b_s    = (const float*)d_in[10];
    const float* norm_w = (const float*)d_in[11];
    const float* hnw    = (const float*)d_in[12];
    const float* W1     = (const float*)d_in[13];
    const float* b1     = (const float*)d_in[14];
    const float* W2     = (const float*)d_in[15];
    const float* b2     = (const float*)d_in[16];

    char* p = (char*)d_ws;
    uint32* zs  = (uint32*)p;          p += (size_t)BT * 256 * 4;
    bf16* zn_a  = (bf16*)p;            p += (size_t)16 * TPB * 256 * 2;
    bf16* zn_b  = (bf16*)p;            p += (size_t)16 * TPB * 256 * 2;
    bf16* wf0   = (bf16*)p;            p += (size_t)NL * 65536 * 2;
    bf16* wf1   = (bf16*)p;            p += (size_t)NL * 65536 * 2;
    bf16* wg0   = (bf16*)p;            p += (size_t)NL * 65536 * 2;
    bf16* wg1   = (bf16*)p;            p += (size_t)NL * 65536 * 2;
    bf16* wr    = (bf16*)p;            p += (size_t)NL * 65536 * 2;
    bf16* ws    = (bf16*)p;            p += (size_t)NL * 65536 * 2;
    bf16* winb  = (bf16*)p;            p += 65536 * 2;
    bf16* w1b   = (bf16*)p;            p += 262144 * 2;
    bf16* w2b   = (bf16*)p;            p += 131072 * 2;

    zero_pads<<<2048, 256, 0, stream>>>(zn_a, zn_b);
    prep_w2<<<NL * 256, 256, 0, stream>>>(W_f, W_g, wf0, wf1, wg0, wg1);
    prep_w1<<<NL * 256, 256, 0, stream>>>(W_r, W_s, wr, ws);
    prep_misc<<<1792, 256, 0, stream>>>(W_in, W1, W2, winb, w1b, w2b);
    in_conv_kernel<<<BT / 64, 512, 0, stream>>>(x, winb, b_in, norm_w, zs, zn_a);

    static const int dil[NL] = {1,2,4,8,16,32,64,128,256,512,
                                1,2,4,8,16,32,64,128,256,512};
    for (int i = 0; i < NL; ++i) {
        const bf16* zi = (i & 1) ? zn_b : zn_a;
        bf16* zo_      = (i & 1) ? zn_a : zn_b;
        int mode = (i == NL - 1) ? 2 : 1;
        const float* nw = (i == NL - 1) ? hnw : (norm_w + (size_t)(i + 1) * 256);
        layer_kernel<<<BT / 64, 512, 0, stream>>>(zi, zo_, zs,
            wf0 + (size_t)i * 65536, wf1 + (size_t)i * 65536,
            wg0 + (size_t)i * 65536, wg1 + (size_t)i * 65536,
            wr + (size_t)i * 65536, ws + (size_t)i * 65536,
            b_f + i * 256, b_g + i * 256, b_r + i * 256, b_s + i * 256,
            nw, dil[i], mode);
    }
    // NL=20 even: last layer wrote zn_a
    head_kernel<<<BT / 64, 512, 0, stream>>>(zn_a, w1b, b1, w2b, b2, (float*)d_out);
}

// Round 7
// 3325.898 us; speedup vs baseline: 2.1749x; 1.2970x over previous
//
#include <hip/hip_runtime.h>
#include <hip/hip_bf16.h>

#define T 4096
#define BT (16*4096)
#define NL 20
#define TPB 4608   // 512 pad + 4096 tokens per batch
#define PAD 512

typedef __bf16 bf16;
typedef __bf16 v8bf __attribute__((ext_vector_type(8)));
typedef float v4f __attribute__((ext_vector_type(4)));
typedef unsigned int uint32;
typedef unsigned short ushort16;

#define MFMA(a,b,c) __builtin_amdgcn_mfma_f32_16x16x32_bf16((a),(b),(c),0,0,0)

__device__ __forceinline__ int swz512(int row, int bc)  { return row*512  + (bc ^ ((row&7)<<4)); }

__device__ __forceinline__ void gload16(const void* g, void* l) {
    __builtin_amdgcn_global_load_lds(
        (const __attribute__((address_space(1))) void*)g,
        (__attribute__((address_space(3))) void*)l, 16, 0, 0);
}

__device__ __forceinline__ ushort16 bfbits(float v) {
    bf16 h = (bf16)v; return *(ushort16*)&h;
}
__device__ __forceinline__ uint32 pack2(float zf, float sf) {
    return (uint32)bfbits(zf) | ((uint32)bfbits(sf) << 16);
}
__device__ __forceinline__ float lo_f(uint32 v) { uint32 t = v << 16;          return *(float*)&t; }
__device__ __forceinline__ float hi_f(uint32 v) { uint32 t = v & 0xffff0000u;  return *(float*)&t; }
__device__ __forceinline__ float sel_f(uint32 pair, int j) {  // j&1: 0=lo,1=hi
    uint32 t = (j & 1) ? (pair & 0xffff0000u) : (pair << 16);
    return *(float*)&t;
}
__device__ __forceinline__ float tanh_clamped(float fv) {
    fv = fminf(fmaxf(fv, -20.f), 20.f);
    float e2 = __expf(-2.f * fv);
    return (1.f - e2) / (1.f + e2);
}
__device__ __forceinline__ float sigmoidf_(float v) {
    return 1.f / (1.f + __expf(-v));
}

// ---------------- zero the per-batch pad stripes of both zn buffers ----------------
__global__ void zero_pads(bf16* __restrict__ zn_a, bf16* __restrict__ zn_b) {
    int idx = blockIdx.x * 256 + threadIdx.x;      // 2*16*16384 uint4
    int buf = idx >> 18;
    int r = idx & 262143;
    int b = r >> 14, off = r & 16383;              // pad = 512 rows * 32 uint4
    bf16* base = buf ? zn_b : zn_a;
    ((uint4*)(base + (size_t)b * TPB * 256))[off] = make_uint4(0, 0, 0, 0);
}

// ---------------- prep kernels: cast/reorder weights to bf16 ----------------
__global__ void prep_w2(const float* __restrict__ Wf, const float* __restrict__ Wg,
                        bf16* __restrict__ wf0, bf16* __restrict__ wf1,
                        bf16* __restrict__ wg0, bf16* __restrict__ wg1) {
    int idx = blockIdx.x * 256 + threadIdx.x;       // NL*256*256
    const float* pf = Wf + (size_t)idx * 2;
    wf0[idx] = (bf16)pf[0]; wf1[idx] = (bf16)pf[1];
    const float* pg = Wg + (size_t)idx * 2;
    wg0[idx] = (bf16)pg[0]; wg1[idx] = (bf16)pg[1];
}

__global__ void prep_w1(const float* __restrict__ Wr, const float* __restrict__ Ws,
                        bf16* __restrict__ wr, bf16* __restrict__ ws) {
    int idx = blockIdx.x * 256 + threadIdx.x;       // NL*256*256
    wr[idx] = (bf16)Wr[idx]; ws[idx] = (bf16)Ws[idx];
}

__global__ void prep_misc(const float* __restrict__ W_in, const float* __restrict__ W1,
                          const float* __restrict__ W2,
                          bf16* __restrict__ winb, bf16* __restrict__ w1b, bf16* __restrict__ w2b) {
    int idx = blockIdx.x * 256 + threadIdx.x;       // 458752 total
    if (idx < 65536) {
        int c = idx >> 8, jj = idx & 255, k = jj >> 3, ci = jj & 7;
        winb[idx] = (bf16)W_in[c * 256 + ci * 32 + k];   // winb[c][k*8+ci]
    } else if (idx < 327680) {
        int j = idx - 65536; w1b[j] = (bf16)W1[j];
    } else {
        int j = idx - 327680; w2b[j] = (bf16)W2[j];
    }
}

// ---------------- fused input conv + RMSNorm(norm_w[0]) ----------------
// 8 waves; wave w owns all 64 rows x cols [w*32, w*32+32)
__global__ __launch_bounds__(512, 4) void in_conv_kernel(
    const float* __restrict__ x, const bf16* __restrict__ winb,
    const float* __restrict__ b_in, const float* __restrict__ nw0,
    uint32* __restrict__ zsb, bf16* __restrict__ znout) {
    __shared__ __align__(16) char smem[65536];
    char* cW  = smem + 32768;                 // window tile
    char* cZn = smem;                         // zn staging
    float* rsq = (float*)(smem + 32768);      // alias cW after GEMM reads
    const int tid = threadIdx.x;
    const int g0 = blockIdx.x * 64;
    const int tl0 = g0 & (T - 1);
    const size_t pr0 = (size_t)(g0 >> 12) * TPB + PAD + tl0;
    for (int i = 0; i < 4; ++i) {
        int ch = tid + i * 512;
        int r = ch >> 5, c16 = ch & 31;
        int tok = tl0 + r - 31 + c16;
        bf16 t8[8] = {};
        if (tok >= 0) {
            const float* xr = x + (size_t)(g0 + r - 31 + c16) * 8;
            float4 xa = ((const float4*)xr)[0];
            float4 xb4 = ((const float4*)xr)[1];
            t8[0]=(bf16)xa.x; t8[1]=(bf16)xa.y; t8[2]=(bf16)xa.z; t8[3]=(bf16)xa.w;
            t8[4]=(bf16)xb4.x; t8[5]=(bf16)xb4.y; t8[6]=(bf16)xb4.z; t8[7]=(bf16)xb4.w;
        }
        *(uint4*)(cW + swz512(r, c16 * 16)) = *(uint4*)t8;
    }
    __syncthreads();
    const int lane = tid & 63, w = tid >> 6;
    const int wn = w;
    const int l15 = lane & 15, l4 = lane >> 4;
    const int cbase = wn * 32 + l15;
    uint32* zb_t = zsb + ((size_t)blockIdx.x * 512 + tid) * 32;

    float p8[4][4] = {};
    uint32 zpk[2][4][2] = {};
    #pragma unroll
    for (int half = 0; half < 2; ++half) {
        v4f acc[4] = {};
        #pragma unroll
        for (int ks = 0; ks < 8; ++ks) {
            v8bf b = *(const v8bf*)(winb + (size_t)(cbase + half*16)*256 + ks*32 + l4*8);
            #pragma unroll
            for (int m = 0; m < 4; ++m) {
                v8bf a = *(const v8bf*)(cW + swz512(m*16 + l15, ks*64 + l4*16));
                acc[m] = MFMA(a, b, acc[m]);
            }
        }
        float bv = b_in[cbase + half*16];
        #pragma unroll
        for (int m = 0; m < 4; ++m) {
            uint32 st[4];
            #pragma unroll
            for (int j = 0; j < 4; ++j) {
                float zf = acc[m][j] + bv;
                st[j] = pack2(zf, 0.f);
                p8[m][j] += zf * zf;
                zpk[half][m][j>>1] |= (uint32)bfbits(zf) << ((j&1)*16);
            }
            *(uint4*)(zb_t + half*16 + m*4) = make_uint4(st[0], st[1], st[2], st[3]);
        }
    }
    __syncthreads();                                  // window reads done
    #pragma unroll
    for (int m = 0; m < 4; ++m)
        #pragma unroll
        for (int j = 0; j < 4; ++j) {
            float p = p8[m][j];
            p += __shfl_xor(p,1); p += __shfl_xor(p,2); p += __shfl_xor(p,4); p += __shfl_xor(p,8);
            if (l15 == 0) rsq[(m*16 + l4*4 + j)*9 + wn] = p;
        }
    __syncthreads();                                  // rsq ready
    #pragma unroll
    for (int m = 0; m < 4; ++m)
        #pragma unroll
        for (int j = 0; j < 4; ++j) {
            int row = m*16 + l4*4 + j;
            const float* rr = rsq + row*9;
            float s8 = rr[0]+rr[1]+rr[2]+rr[3]+rr[4]+rr[5]+rr[6]+rr[7];
            float iv = rsqrtf(s8*(1.f/256.f) + 1e-6f);
            #pragma unroll
            for (int half = 0; half < 2; ++half) {
                int col = cbase + half*16;
                float zf = sel_f(zpk[half][m][j>>1], j);
                *(bf16*)(cZn + swz512(row, col*2)) = (bf16)(zf * iv * nw0[col]);
            }
        }
    __syncthreads();
    #pragma unroll
    for (int k = 0; k < 4; ++k) {
        int idx = tid + k * 512;
        int row = idx >> 5, d = idx & 31;
        uint4 v = *(uint4*)(cZn + swz512(row, d*16));
        *((uint4*)(znout + (pr0 + row) * 256) + d) = v;
    }
}

// ---------------- fused gated-residual layer + next-layer RMSNorm ----------------
// wave w owns all 64 rows x cols [w*32, w*32+32). mode: 1=normal, 2=last
__global__ __launch_bounds__(512, 4) void layer_kernel(
    const bf16* __restrict__ znin, bf16* __restrict__ znout, uint32* __restrict__ zsb,
    const bf16* __restrict__ wf0, const bf16* __restrict__ wf1,
    const bf16* __restrict__ wg0, const bf16* __restrict__ wg1,
    const bf16* __restrict__ wr, const bf16* __restrict__ wsm,
    const float* __restrict__ bfp, const float* __restrict__ bgp,
    const float* __restrict__ brp, const float* __restrict__ bsp,
    const float* __restrict__ nw, int dil, int mode) {
    __shared__ __align__(16) char smem[65536];
    char* cA0 = smem;                     // zn[t-d] tile -> U tile -> zn-out staging
    char* cA1 = smem + 32768;             // zn[t] tile
    float* rsq = (float*)(smem + 32768);  // alias cA1 (dead after GEMM1)
    const int tid = threadIdx.x;
    const int lane = tid & 63, w = tid >> 6;
    const int g0 = blockIdx.x * 64;
    const size_t pr0 = (size_t)(g0 >> 12) * TPB + PAD + (g0 & (T - 1));

    // async stage zn[t]->cA1, zn[t-dil]->cA0 with pre-swizzled global source
    {
        int rl = w * 8 + (lane >> 5);
        int d = lane & 31;
        #pragma unroll
        for (int j = 0; j < 4; ++j) {
            int r = rl + j * 2;
            int s = d ^ (r & 7);
            gload16(znin + (pr0 + r) * 256 + s * 8,       cA1 + (w*8 + j*2) * 512);
            gload16(znin + (pr0 + r - dil) * 256 + s * 8, cA0 + (w*8 + j*2) * 512);
        }
    }

    const int wn = w;
    const int l15 = lane & 15, l4 = lane >> 4;
    const int cbase = wn * 32 + l15;
    uint32* zb_t = zsb + ((size_t)blockIdx.x * 512 + tid) * 32;

    __syncthreads();                               // S1

    // ---- GEMM1: f+g combined, per 16-col half ----
    uint32 upk[2][4][2];                           // [half][m][jpair] packed bf16 u
    #pragma unroll
    for (int half = 0; half < 2; ++half) {
        v4f accf[4] = {}, accg[4] = {};
        #pragma unroll
        for (int ks = 0; ks < 8; ++ks) {
            size_t bo = (size_t)(cbase + half*16) * 256 + ks*32 + l4*8;
            v8bf bf0 = *(const v8bf*)(wf0 + bo);
            v8bf bf1 = *(const v8bf*)(wf1 + bo);
            v8bf bg0 = *(const v8bf*)(wg0 + bo);
            v8bf bg1 = *(const v8bf*)(wg1 + bo);
            #pragma unroll
            for (int m = 0; m < 4; ++m) {
                int off = swz512(m*16 + l15, ks*64 + l4*16);
                v8bf a0 = *(const v8bf*)(cA0 + off);
                v8bf a1 = *(const v8bf*)(cA1 + off);
                accf[m] = MFMA(a0, bf0, accf[m]);
                accf[m] = MFMA(a1, bf1, accf[m]);
                accg[m] = MFMA(a0, bg0, accg[m]);
                accg[m] = MFMA(a1, bg1, accg[m]);
            }
        }
        float bfv = bfp[cbase + half*16];
        float bgv = bgp[cbase + half*16];
        #pragma unroll
        for (int m = 0; m < 4; ++m)
            #pragma unroll
            for (int jp = 0; jp < 2; ++jp) {
                float u0 = tanh_clamped(accf[m][jp*2]   + bfv) * sigmoidf_(accg[m][jp*2]   + bgv);
                float u1 = tanh_clamped(accf[m][jp*2+1] + bfv) * sigmoidf_(accg[m][jp*2+1] + bgv);
                upk[half][m][jp] = (uint32)bfbits(u0) | ((uint32)bfbits(u1) << 16);
            }
    }
    __syncthreads();                               // S2: all GEMM1 tile reads done

    // write U tile (bf16, swizzled) into cA0
    #pragma unroll
    for (int half = 0; half < 2; ++half)
        #pragma unroll
        for (int m = 0; m < 4; ++m) {
            int col = cbase + half*16;
            #pragma unroll
            for (int j = 0; j < 4; ++j) {
                int row = m*16 + l4*4 + j;
                *(bf16*)(cA0 + swz512(row, col*2)) = (bf16)sel_f(upk[half][m][j>>1], j);
            }
        }
    __syncthreads();                               // S3

    // ---- GEMM2 per half with blocked zs RMW ----
    float p8[4][4] = {};
    uint32 zpk[2][4][2] = {};
    #pragma unroll
    for (int half = 0; half < 2; ++half) {
        uint32 old_[4][4];
        #pragma unroll
        for (int m = 0; m < 4; ++m) {
            uint4 o4 = *(const uint4*)(zb_t + half*16 + m*4);
            old_[m][0] = o4.x; old_[m][1] = o4.y; old_[m][2] = o4.z; old_[m][3] = o4.w;
        }
        v4f accr[4] = {}, accs[4] = {};
        if (mode != 2) {
            #pragma unroll
            for (int ks = 0; ks < 8; ++ks) {
                size_t bo = (size_t)(cbase + half*16) * 256 + ks*32 + l4*8;
                v8bf br_ = *(const v8bf*)(wr + bo);
                v8bf bs_ = *(const v8bf*)(wsm + bo);
                #pragma unroll
                for (int m = 0; m < 4; ++m) {
                    v8bf a = *(const v8bf*)(cA0 + swz512(m*16 + l15, ks*64 + l4*16));
                    accr[m] = MFMA(a, br_, accr[m]);
                    accs[m] = MFMA(a, bs_, accs[m]);
                }
            }
        } else {
            #pragma unroll
            for (int ks = 0; ks < 8; ++ks) {
                size_t bo = (size_t)(cbase + half*16) * 256 + ks*32 + l4*8;
                v8bf bs_ = *(const v8bf*)(wsm + bo);
                #pragma unroll
                for (int m = 0; m < 4; ++m) {
                    v8bf a = *(const v8bf*)(cA0 + swz512(m*16 + l15, ks*64 + l4*16));
                    accs[m] = MFMA(a, bs_, accs[m]);
                }
            }
        }
        if (mode != 2) {
            float brv = brp[cbase + half*16];
            float bsv = bsp[cbase + half*16];
            #pragma unroll
            for (int m = 0; m < 4; ++m) {
                uint32 st[4];
                #pragma unroll
                for (int j = 0; j < 4; ++j) {
                    float zf = lo_f(old_[m][j]) + accr[m][j] + brv;
                    float sf = hi_f(old_[m][j]) + accs[m][j] + bsv;
                    st[j] = pack2(zf, sf);
                    p8[m][j] += zf * zf;
                    zpk[half][m][j>>1] |= (uint32)bfbits(zf) << ((j&1)*16);
                }
                *(uint4*)(zb_t + half*16 + m*4) = make_uint4(st[0], st[1], st[2], st[3]);
            }
        } else {
            float bsv = bsp[cbase + half*16];
            #pragma unroll
            for (int m = 0; m < 4; ++m)
                #pragma unroll
                for (int j = 0; j < 4; ++j) {
                    float of = fmaxf(hi_f(old_[m][j]) + accs[m][j] + bsv, 0.f);
                    p8[m][j] += of * of;
                    zpk[half][m][j>>1] |= (uint32)bfbits(of) << ((j&1)*16);
                }
        }
    }
    #pragma unroll
    for (int m = 0; m < 4; ++m)
        #pragma unroll
        for (int j = 0; j < 4; ++j) {
            float p = p8[m][j];
            p += __shfl_xor(p,1); p += __shfl_xor(p,2); p += __shfl_xor(p,4); p += __shfl_xor(p,8);
            if (l15 == 0) rsq[(m*16 + l4*4 + j)*9 + wn] = p;
        }
    __syncthreads();                               // S4: GEMM2 reads + rsq done

    // zn staging (bf16, swizzled) into cA0
    #pragma unroll
    for (int m = 0; m < 4; ++m)
        #pragma unroll
        for (int j = 0; j < 4; ++j) {
            int row = m*16 + l4*4 + j;
            const float* rr = rsq + row*9;
            float s8 = rr[0]+rr[1]+rr[2]+rr[3]+rr[4]+rr[5]+rr[6]+rr[7];
            float iv = rsqrtf(s8*(1.f/256.f) + 1e-6f);
            #pragma unroll
            for (int half = 0; half < 2; ++half) {
                int col = cbase + half*16;
                float zf = sel_f(zpk[half][m][j>>1], j);
                *(bf16*)(cA0 + swz512(row, col*2)) = (bf16)(zf * iv * nw[col]);
            }
        }
    __syncthreads();                               // S5

    // coalesced zn copyout (padded layout)
    #pragma unroll
    for (int k = 0; k < 4; ++k) {
        int idx = tid + k * 512;
        int row = idx >> 5, d = idx & 31;
        uint4 v = *(uint4*)(cA0 + swz512(row, d*16));
        *((uint4*)(znout + (pr0 + row) * 256) + d) = v;
    }
}

// ---------------- fused head: on @ W1 -> relu -> @ W2 (8 waves) ----------------
__global__ __launch_bounds__(512, 4) void head_kernel(
    const bf16* __restrict__ on, const bf16* __restrict__ w1b, const float* __restrict__ b1,
    const bf16* __restrict__ w2b, const float* __restrict__ b2, float* __restrict__ out) {
    __shared__ __align__(16) char smem[65536];
    char* cOn = smem;
    char* cH  = smem + 32768;
    const int tid = threadIdx.x;
    const int g0 = blockIdx.x * 64;
    const size_t pr0 = (size_t)(g0 >> 12) * TPB + PAD + (g0 & (T - 1));
    for (int i = 0; i < 4; ++i) {
        int ch = tid + i * 512;
        int r = ch >> 5, c16 = ch & 31;
        *(uint4*)(cOn + swz512(r, c16 * 16)) = *((const uint4*)(on + (pr0 + r) * 256) + c16);
    }
    __syncthreads();
    const int lane = tid & 63, w = tid >> 6;
    const int wm = w >> 2, wn = w & 3;
    const int l15 = lane & 15, l4 = lane >> 4;
    const int r0 = wm * 32;
    v4f acc2[2][2] = {};
    for (int hc = 0; hc < 4; ++hc) {
        v4f acch[2][4] = {};
        #pragma unroll
        for (int ks = 0; ks < 8; ++ks) {
            v8bf a[2];
            #pragma unroll
            for (int m = 0; m < 2; ++m)
                a[m] = *(const v8bf*)(cOn + swz512(r0 + m*16 + l15, ks*64 + l4*16));
            #pragma unroll
            for (int nf = 0; nf < 4; ++nf) {
                int h = hc * 256 + wn * 64 + nf * 16 + l15;
                v8bf b = *(const v8bf*)(w1b + (size_t)h * 256 + ks * 32 + l4 * 8);
                #pragma unroll
                for (int m = 0; m < 2; ++m) acch[m][nf] = MFMA(a[m], b, acch[m][nf]);
            }
        }
        __syncthreads();   // previous hc's cH reads done
        #pragma unroll
        for (int m = 0; m < 2; ++m)
            #pragma unroll
            for (int nf = 0; nf < 4; ++nf) {
                int coll = wn * 64 + nf * 16 + l15;
                float b1v = b1[hc * 256 + coll];
                #pragma unroll
                for (int j = 0; j < 4; ++j) {
                    int row = r0 + m*16 + l4*4 + j;
                    float hv = fmaxf(acch[m][nf][j] + b1v, 0.f);
                    *(bf16*)(cH + swz512(row, coll * 2)) = (bf16)hv;
                }
            }
        __syncthreads();
        #pragma unroll
        for (int ks = 0; ks < 8; ++ks) {
            v8bf a[2];
            #pragma unroll
            for (int m = 0; m < 2; ++m)
                a[m] = *(const v8bf*)(cH + swz512(r0 + m*16 + l15, ks*64 + l4*16));
            #pragma unroll
            for (int nf = 0; nf < 2; ++nf) {
                int o = wn * 32 + nf * 16 + l15;
                v8bf b = *(const v8bf*)(w2b + (size_t)o * 1024 + hc * 256 + ks * 32 + l4 * 8);
                #pragma unroll
                for (int m = 0; m < 2; ++m) acc2[m][nf] = MFMA(a[m], b, acc2[m][nf]);
            }
        }
    }
    #pragma unroll
    for (int m = 0; m < 2; ++m)
        #pragma unroll
        for (int nf = 0; nf < 2; ++nf) {
            int o = wn * 32 + nf * 16 + l15;
            float b2v = b2[o];
            #pragma unroll
            for (int j = 0; j < 4; ++j) {
                int row = r0 + m*16 + l4*4 + j;
                out[(size_t)(g0 + row) * 128 + o] = acc2[m][nf][j] + b2v;
            }
        }
}

extern "C" void kernel_launch(void* const* d_in, const int* in_sizes, int n_in,
                              void* d_out, int out_size, void* d_ws, size_t ws_size,
                              hipStream_t stream) {
    const float* x      = (const float*)d_in[0];
    const float* W_in   = (const float*)d_in[1];
    const float* b_in   = (const float*)d_in[2];
    const float* W_f    = (const float*)d_in[3];
    const float* b_f    = (const float*)d_in[4];
    const float* W_g    = (const float*)d_in[5];
    const float* b_g    = (const float*)d_in[6];
    const float* W_r    = (const float*)d_in[7];
    const float* b_r    = (const float*)d_in[8];
    const float* W_s    = (const float*)d_in[9];
    const float* b_s    = (const float*)d_in[10];
    const float* norm_w = (const float*)d_in[11];
    const float* hnw    = (const float*)d_in[12];
    const float* W1     = (const float*)d_in[13];
    const float* b1     = (const float*)d_in[14];
    const float* W2     = (const float*)d_in[15];
    const float* b2     = (const float*)d_in[16];

    char* p = (char*)d_ws;
    uint32* zsb = (uint32*)p;          p += (size_t)BT * 256 * 4;
    bf16* zn_a  = (bf16*)p;            p += (size_t)16 * TPB * 256 * 2;
    bf16* zn_b  = (bf16*)p;            p += (size_t)16 * TPB * 256 * 2;
    bf16* wf0   = (bf16*)p;            p += (size_t)NL * 65536 * 2;
    bf16* wf1   = (bf16*)p;            p += (size_t)NL * 65536 * 2;
    bf16* wg0   = (bf16*)p;            p += (size_t)NL * 65536 * 2;
    bf16* wg1   = (bf16*)p;            p += (size_t)NL * 65536 * 2;
    bf16* wr    = (bf16*)p;            p += (size_t)NL * 65536 * 2;
    bf16* ws    = (bf16*)p;            p += (size_t)NL * 65536 * 2;
    bf16* winb  = (bf16*)p;            p += 65536 * 2;
    bf16* w1b   = (bf16*)p;            p += 262144 * 2;
    bf16* w2b   = (bf16*)p;            p += 131072 * 2;

    zero_pads<<<2048, 256, 0, stream>>>(zn_a, zn_b);
    prep_w2<<<NL * 256, 256, 0, stream>>>(W_f, W_g, wf0, wf1, wg0, wg1);
    prep_w1<<<NL * 256, 256, 0, stream>>>(W_r, W_s, wr, ws);
    prep_misc<<<1792, 256, 0, stream>>>(W_in, W1, W2, winb, w1b, w2b);
    in_conv_kernel<<<BT / 64, 512, 0, stream>>>(x, winb, b_in, norm_w, zsb, zn_a);

    static const int dil[NL] = {1,2,4,8,16,32,64,128,256,512,
                                1,2,4,8,16,32,64,128,256,512};
    for (int i = 0; i < NL; ++i) {
        const bf16* zi = (i & 1) ? zn_b : zn_a;
        bf16* zo_      = (i & 1) ? zn_a : zn_b;
        int mode = (i == NL - 1) ? 2 : 1;
        const float* nw = (i == NL - 1) ? hnw : (norm_w + (size_t)(i + 1) * 256);
        layer_kernel<<<BT / 64, 512, 0, stream>>>(zi, zo_, zsb,
            wf0 + (size_t)i * 65536, wf1 + (size_t)i * 65536,
            wg0 + (size_t)i * 65536, wg1 + (size_t)i * 65536,
            wr + (size_t)i * 65536, ws + (size_t)i * 65536,
            b_f + i * 256, b_g + i * 256, b_r + i * 256, b_s + i * 256,
            nw, dil[i], mode);
    }
    // NL=20 even: last layer wrote zn_a
    head_kernel<<<BT / 64, 512, 0, stream>>>(zn_a, w1b, b1, w2b, b2, (float*)d_out);
}

// Round 8
// 3214.341 us; speedup vs baseline: 2.2504x; 1.0347x over previous
//
#include <hip/hip_runtime.h>
#include <hip/hip_bf16.h>

#define T 4096
#define BT (16*4096)
#define NL 20
#define TPB 4608   // 512 pad + 4096 tokens per batch
#define PAD 512

typedef __bf16 bf16;
typedef __bf16 v8bf __attribute__((ext_vector_type(8)));
typedef float v4f __attribute__((ext_vector_type(4)));
typedef unsigned int uint32;
typedef unsigned short ushort16;

#define MFMA(a,b,c) __builtin_amdgcn_mfma_f32_16x16x32_bf16((a),(b),(c),0,0,0)

__device__ __forceinline__ int swz512(int row, int bc)  { return row*512  + (bc ^ ((row&7)<<4)); }

__device__ __forceinline__ void gload16(const void* g, void* l) {
    __builtin_amdgcn_global_load_lds(
        (const __attribute__((address_space(1))) void*)g,
        (__attribute__((address_space(3))) void*)l, 16, 0, 0);
}

__device__ __forceinline__ ushort16 bfbits(float v) {
    bf16 h = (bf16)v; return *(ushort16*)&h;
}
__device__ __forceinline__ uint32 pack2(float zf, float sf) {
    return (uint32)bfbits(zf) | ((uint32)bfbits(sf) << 16);
}
__device__ __forceinline__ float lo_f(uint32 v) { uint32 t = v << 16;          return *(float*)&t; }
__device__ __forceinline__ float hi_f(uint32 v) { uint32 t = v & 0xffff0000u;  return *(float*)&t; }
__device__ __forceinline__ float sel_f(uint32 pair, int j) {  // j&1: 0=lo,1=hi
    uint32 t = (j & 1) ? (pair & 0xffff0000u) : (pair << 16);
    return *(float*)&t;
}
__device__ __forceinline__ float tanh_clamped(float fv) {
    fv = fminf(fmaxf(fv, -20.f), 20.f);
    float e2 = __expf(-2.f * fv);
    return (1.f - e2) / (1.f + e2);
}
__device__ __forceinline__ float sigmoidf_(float v) {
    return 1.f / (1.f + __expf(-v));
}

// ---------------- zero the per-batch pad stripes of both zn buffers ----------------
__global__ void zero_pads(bf16* __restrict__ zn_a, bf16* __restrict__ zn_b) {
    int idx = blockIdx.x * 256 + threadIdx.x;      // 2*16*16384 uint4
    int buf = idx >> 18;
    int r = idx & 262143;
    int b = r >> 14, off = r & 16383;              // pad = 512 rows * 32 uint4
    bf16* base = buf ? zn_b : zn_a;
    ((uint4*)(base + (size_t)b * TPB * 256))[off] = make_uint4(0, 0, 0, 0);
}

// ---------------- prep kernels: cast/reorder weights to bf16 ----------------
__global__ void prep_w2(const float* __restrict__ Wf, const float* __restrict__ Wg,
                        bf16* __restrict__ wf0, bf16* __restrict__ wf1,
                        bf16* __restrict__ wg0, bf16* __restrict__ wg1) {
    int idx = blockIdx.x * 256 + threadIdx.x;       // NL*256*256
    const float* pf = Wf + (size_t)idx * 2;
    wf0[idx] = (bf16)pf[0]; wf1[idx] = (bf16)pf[1];
    const float* pg = Wg + (size_t)idx * 2;
    wg0[idx] = (bf16)pg[0]; wg1[idx] = (bf16)pg[1];
}

__global__ void prep_w1(const float* __restrict__ Wr, const float* __restrict__ Ws,
                        bf16* __restrict__ wr, bf16* __restrict__ ws) {
    int idx = blockIdx.x * 256 + threadIdx.x;       // NL*256*256
    wr[idx] = (bf16)Wr[idx]; ws[idx] = (bf16)Ws[idx];
}

__global__ void prep_misc(const float* __restrict__ W_in, const float* __restrict__ W1,
                          const float* __restrict__ W2,
                          bf16* __restrict__ winb, bf16* __restrict__ w1b, bf16* __restrict__ w2b) {
    int idx = blockIdx.x * 256 + threadIdx.x;       // 458752 total
    if (idx < 65536) {
        int c = idx >> 8, jj = idx & 255, k = jj >> 3, ci = jj & 7;
        winb[idx] = (bf16)W_in[c * 256 + ci * 32 + k];   // winb[c][k*8+ci]
    } else if (idx < 327680) {
        int j = idx - 65536; w1b[j] = (bf16)W1[j];
    } else {
        int j = idx - 327680; w2b[j] = (bf16)W2[j];
    }
}

// ---------------- fused input conv + RMSNorm(norm_w[0]) ----------------
// 8 waves; wave w owns all 64 rows x cols [w*32, w*32+32)
__global__ __launch_bounds__(512, 4) void in_conv_kernel(
    const float* __restrict__ x, const bf16* __restrict__ winb,
    const float* __restrict__ b_in, const float* __restrict__ nw0,
    uint32* __restrict__ zsb, bf16* __restrict__ znout) {
    __shared__ __align__(16) char smem[65536];
    char* cW  = smem + 32768;                 // window tile
    char* cZn = smem;                         // zn staging
    float* rsq = (float*)(smem + 32768);      // alias cW after GEMM reads
    const int tid = threadIdx.x;
    const int g0 = blockIdx.x * 64;
    const int tl0 = g0 & (T - 1);
    const size_t pr0 = (size_t)(g0 >> 12) * TPB + PAD + tl0;
    for (int i = 0; i < 4; ++i) {
        int ch = tid + i * 512;
        int r = ch >> 5, c16 = ch & 31;
        int tok = tl0 + r - 31 + c16;
        bf16 t8[8] = {};
        if (tok >= 0) {
            const float* xr = x + (size_t)(g0 + r - 31 + c16) * 8;
            float4 xa = ((const float4*)xr)[0];
            float4 xb4 = ((const float4*)xr)[1];
            t8[0]=(bf16)xa.x; t8[1]=(bf16)xa.y; t8[2]=(bf16)xa.z; t8[3]=(bf16)xa.w;
            t8[4]=(bf16)xb4.x; t8[5]=(bf16)xb4.y; t8[6]=(bf16)xb4.z; t8[7]=(bf16)xb4.w;
        }
        *(uint4*)(cW + swz512(r, c16 * 16)) = *(uint4*)t8;
    }
    __syncthreads();
    const int lane = tid & 63, w = tid >> 6;
    const int wn = w;
    const int l15 = lane & 15, l4 = lane >> 4;
    const int cbase = wn * 32 + l15;
    uint32* zb_t = zsb + ((size_t)blockIdx.x * 512 + tid) * 32;

    float p8[4][4] = {};
    uint32 zpk[2][4][2] = {};
    #pragma unroll
    for (int half = 0; half < 2; ++half) {
        v4f acc[4] = {};
        __builtin_amdgcn_s_setprio(1);
        #pragma unroll
        for (int ks = 0; ks < 8; ++ks) {
            v8bf b = *(const v8bf*)(winb + (size_t)(cbase + half*16)*256 + ks*32 + l4*8);
            #pragma unroll
            for (int m = 0; m < 4; ++m) {
                v8bf a = *(const v8bf*)(cW + swz512(m*16 + l15, ks*64 + l4*16));
                acc[m] = MFMA(a, b, acc[m]);
            }
        }
        __builtin_amdgcn_s_setprio(0);
        float bv = b_in[cbase + half*16];
        #pragma unroll
        for (int m = 0; m < 4; ++m) {
            uint32 st[4];
            #pragma unroll
            for (int j = 0; j < 4; ++j) {
                float zf = acc[m][j] + bv;
                st[j] = pack2(zf, 0.f);
                p8[m][j] += zf * zf;
                zpk[half][m][j>>1] |= (uint32)bfbits(zf) << ((j&1)*16);
            }
            *(uint4*)(zb_t + half*16 + m*4) = make_uint4(st[0], st[1], st[2], st[3]);
        }
    }
    __syncthreads();                                  // window reads done
    #pragma unroll
    for (int m = 0; m < 4; ++m)
        #pragma unroll
        for (int j = 0; j < 4; ++j) {
            float p = p8[m][j];
            p += __shfl_xor(p,1); p += __shfl_xor(p,2); p += __shfl_xor(p,4); p += __shfl_xor(p,8);
            if (l15 == 0) rsq[(m*16 + l4*4 + j)*9 + wn] = p;
        }
    __syncthreads();                                  // rsq ready
    #pragma unroll
    for (int m = 0; m < 4; ++m)
        #pragma unroll
        for (int j = 0; j < 4; ++j) {
            int row = m*16 + l4*4 + j;
            const float* rr = rsq + row*9;
            float s8 = rr[0]+rr[1]+rr[2]+rr[3]+rr[4]+rr[5]+rr[6]+rr[7];
            float iv = rsqrtf(s8*(1.f/256.f) + 1e-6f);
            #pragma unroll
            for (int half = 0; half < 2; ++half) {
                int col = cbase + half*16;
                float zf = sel_f(zpk[half][m][j>>1], j);
                *(bf16*)(cZn + swz512(row, col*2)) = (bf16)(zf * iv * nw0[col]);
            }
        }
    __syncthreads();
    #pragma unroll
    for (int k = 0; k < 4; ++k) {
        int idx = tid + k * 512;
        int row = idx >> 5, d = idx & 31;
        uint4 v = *(uint4*)(cZn + swz512(row, d*16));
        *((uint4*)(znout + (pr0 + row) * 256) + d) = v;
    }
}

// ---------------- fused gated-residual layer + next-layer RMSNorm ----------------
// wave w owns all 64 rows x cols [w*32, w*32+32). mode: 1=normal, 2=last
__global__ __launch_bounds__(512, 4) void layer_kernel(
    const bf16* __restrict__ znin, bf16* __restrict__ znout, uint32* __restrict__ zsb,
    const bf16* __restrict__ wf0, const bf16* __restrict__ wf1,
    const bf16* __restrict__ wg0, const bf16* __restrict__ wg1,
    const bf16* __restrict__ wr, const bf16* __restrict__ wsm,
    const float* __restrict__ bfp, const float* __restrict__ bgp,
    const float* __restrict__ brp, const float* __restrict__ bsp,
    const float* __restrict__ nw, int dil, int mode) {
    __shared__ __align__(16) char smem[65536];
    char* cA0 = smem;                     // zn[t-d] tile -> U tile -> zn-out staging
    char* cA1 = smem + 32768;             // zn[t] tile
    float* rsq = (float*)(smem + 32768);  // alias cA1 (dead after GEMM1)
    const int tid = threadIdx.x;
    const int lane = tid & 63, w = tid >> 6;
    const int g0 = blockIdx.x * 64;
    const size_t pr0 = (size_t)(g0 >> 12) * TPB + PAD + (g0 & (T - 1));

    // async stage zn[t]->cA1, zn[t-dil]->cA0 with pre-swizzled global source
    {
        int rl = w * 8 + (lane >> 5);
        int d = lane & 31;
        #pragma unroll
        for (int j = 0; j < 4; ++j) {
            int r = rl + j * 2;
            int s = d ^ (r & 7);
            gload16(znin + (pr0 + r) * 256 + s * 8,       cA1 + (w*8 + j*2) * 512);
            gload16(znin + (pr0 + r - dil) * 256 + s * 8, cA0 + (w*8 + j*2) * 512);
        }
    }

    const int wn = w;
    const int l15 = lane & 15, l4 = lane >> 4;
    const int cbase = wn * 32 + l15;
    uint32* zb_t = zsb + ((size_t)blockIdx.x * 512 + tid) * 32;

    __syncthreads();                               // S1

    // prefetch zsb old (half 0) — latency hides under GEMM1
    uint4 old0[4];
    #pragma unroll
    for (int m = 0; m < 4; ++m) old0[m] = *(const uint4*)(zb_t + m*4);

    // ---- GEMM1: f+g combined, per 16-col half ----
    uint32 upk[2][4][2];                           // [half][m][jpair] packed bf16 u
    #pragma unroll
    for (int half = 0; half < 2; ++half) {
        v4f accf[4] = {}, accg[4] = {};
        __builtin_amdgcn_s_setprio(1);
        #pragma unroll
        for (int ks = 0; ks < 8; ++ks) {
            size_t bo = (size_t)(cbase + half*16) * 256 + ks*32 + l4*8;
            v8bf bf0 = *(const v8bf*)(wf0 + bo);
            v8bf bf1 = *(const v8bf*)(wf1 + bo);
            v8bf bg0 = *(const v8bf*)(wg0 + bo);
            v8bf bg1 = *(const v8bf*)(wg1 + bo);
            #pragma unroll
            for (int m = 0; m < 4; ++m) {
                int off = swz512(m*16 + l15, ks*64 + l4*16);
                v8bf a0 = *(const v8bf*)(cA0 + off);
                v8bf a1 = *(const v8bf*)(cA1 + off);
                accf[m] = MFMA(a0, bf0, accf[m]);
                accf[m] = MFMA(a1, bf1, accf[m]);
                accg[m] = MFMA(a0, bg0, accg[m]);
                accg[m] = MFMA(a1, bg1, accg[m]);
            }
        }
        __builtin_amdgcn_s_setprio(0);
        float bfv = bfp[cbase + half*16];
        float bgv = bgp[cbase + half*16];
        #pragma unroll
        for (int m = 0; m < 4; ++m)
            #pragma unroll
            for (int jp = 0; jp < 2; ++jp) {
                float u0 = tanh_clamped(accf[m][jp*2]   + bfv) * sigmoidf_(accg[m][jp*2]   + bgv);
                float u1 = tanh_clamped(accf[m][jp*2+1] + bfv) * sigmoidf_(accg[m][jp*2+1] + bgv);
                upk[half][m][jp] = (uint32)bfbits(u0) | ((uint32)bfbits(u1) << 16);
            }
    }
    __syncthreads();                               // S2: all GEMM1 tile reads done

    // prefetch zsb old (half 1) — latency hides under U-write + GEMM2 half0
    uint4 old1[4];
    #pragma unroll
    for (int m = 0; m < 4; ++m) old1[m] = *(const uint4*)(zb_t + 16 + m*4);

    // write U tile (bf16, swizzled) into cA0
    #pragma unroll
    for (int half = 0; half < 2; ++half)
        #pragma unroll
        for (int m = 0; m < 4; ++m) {
            int col = cbase + half*16;
            #pragma unroll
            for (int j = 0; j < 4; ++j) {
                int row = m*16 + l4*4 + j;
                *(bf16*)(cA0 + swz512(row, col*2)) = (bf16)sel_f(upk[half][m][j>>1], j);
            }
        }
    __syncthreads();                               // S3

    // ---- GEMM2 per half with blocked zs RMW ----
    float p8[4][4] = {};
    uint32 zpk[2][4][2] = {};
    #pragma unroll
    for (int half = 0; half < 2; ++half) {
        uint32 old_[4][4];
        #pragma unroll
        for (int m = 0; m < 4; ++m) {
            uint4 o4 = half ? old1[m] : old0[m];
            old_[m][0] = o4.x; old_[m][1] = o4.y; old_[m][2] = o4.z; old_[m][3] = o4.w;
        }
        v4f accr[4] = {}, accs[4] = {};
        if (mode != 2) {
            __builtin_amdgcn_s_setprio(1);
            #pragma unroll
            for (int ks = 0; ks < 8; ++ks) {
                size_t bo = (size_t)(cbase + half*16) * 256 + ks*32 + l4*8;
                v8bf br_ = *(const v8bf*)(wr + bo);
                v8bf bs_ = *(const v8bf*)(wsm + bo);
                #pragma unroll
                for (int m = 0; m < 4; ++m) {
                    v8bf a = *(const v8bf*)(cA0 + swz512(m*16 + l15, ks*64 + l4*16));
                    accr[m] = MFMA(a, br_, accr[m]);
                    accs[m] = MFMA(a, bs_, accs[m]);
                }
            }
            __builtin_amdgcn_s_setprio(0);
        } else {
            __builtin_amdgcn_s_setprio(1);
            #pragma unroll
            for (int ks = 0; ks < 8; ++ks) {
                size_t bo = (size_t)(cbase + half*16) * 256 + ks*32 + l4*8;
                v8bf bs_ = *(const v8bf*)(wsm + bo);
                #pragma unroll
                for (int m = 0; m < 4; ++m) {
                    v8bf a = *(const v8bf*)(cA0 + swz512(m*16 + l15, ks*64 + l4*16));
                    accs[m] = MFMA(a, bs_, accs[m]);
                }
            }
            __builtin_amdgcn_s_setprio(0);
        }
        if (mode != 2) {
            float brv = brp[cbase + half*16];
            float bsv = bsp[cbase + half*16];
            #pragma unroll
            for (int m = 0; m < 4; ++m) {
                uint32 st[4];
                #pragma unroll
                for (int j = 0; j < 4; ++j) {
                    float zf = lo_f(old_[m][j]) + accr[m][j] + brv;
                    float sf = hi_f(old_[m][j]) + accs[m][j] + bsv;
                    st[j] = pack2(zf, sf);
                    p8[m][j] += zf * zf;
                    zpk[half][m][j>>1] |= (uint32)bfbits(zf) << ((j&1)*16);
                }
                *(uint4*)(zb_t + half*16 + m*4) = make_uint4(st[0], st[1], st[2], st[3]);
            }
        } else {
            float bsv = bsp[cbase + half*16];
            #pragma unroll
            for (int m = 0; m < 4; ++m)
                #pragma unroll
                for (int j = 0; j < 4; ++j) {
                    float of = fmaxf(hi_f(old_[m][j]) + accs[m][j] + bsv, 0.f);
                    p8[m][j] += of * of;
                    zpk[half][m][j>>1] |= (uint32)bfbits(of) << ((j&1)*16);
                }
        }
    }
    #pragma unroll
    for (int m = 0; m < 4; ++m)
        #pragma unroll
        for (int j = 0; j < 4; ++j) {
            float p = p8[m][j];
            p += __shfl_xor(p,1); p += __shfl_xor(p,2); p += __shfl_xor(p,4); p += __shfl_xor(p,8);
            if (l15 == 0) rsq[(m*16 + l4*4 + j)*9 + wn] = p;
        }
    __syncthreads();                               // S4: GEMM2 reads + rsq done

    // zn staging (bf16, swizzled) into cA0
    #pragma unroll
    for (int m = 0; m < 4; ++m)
        #pragma unroll
        for (int j = 0; j < 4; ++j) {
            int row = m*16 + l4*4 + j;
            const float* rr = rsq + row*9;
            float s8 = rr[0]+rr[1]+rr[2]+rr[3]+rr[4]+rr[5]+rr[6]+rr[7];
            float iv = rsqrtf(s8*(1.f/256.f) + 1e-6f);
            #pragma unroll
            for (int half = 0; half < 2; ++half) {
                int col = cbase + half*16;
                float zf = sel_f(zpk[half][m][j>>1], j);
                *(bf16*)(cA0 + swz512(row, col*2)) = (bf16)(zf * iv * nw[col]);
            }
        }
    __syncthreads();                               // S5

    // coalesced zn copyout (padded layout)
    #pragma unroll
    for (int k = 0; k < 4; ++k) {
        int idx = tid + k * 512;
        int row = idx >> 5, d = idx & 31;
        uint4 v = *(uint4*)(cA0 + swz512(row, d*16));
        *((uint4*)(znout + (pr0 + row) * 256) + d) = v;
    }
}

// ---------------- fused head: on @ W1 -> relu -> @ W2 (8 waves) ----------------
__global__ __launch_bounds__(512, 4) void head_kernel(
    const bf16* __restrict__ on, const bf16* __restrict__ w1b, const float* __restrict__ b1,
    const bf16* __restrict__ w2b, const float* __restrict__ b2, float* __restrict__ out) {
    __shared__ __align__(16) char smem[65536];
    char* cOn = smem;
    char* cH  = smem + 32768;
    const int tid = threadIdx.x;
    const int g0 = blockIdx.x * 64;
    const size_t pr0 = (size_t)(g0 >> 12) * TPB + PAD + (g0 & (T - 1));
    for (int i = 0; i < 4; ++i) {
        int ch = tid + i * 512;
        int r = ch >> 5, c16 = ch & 31;
        *(uint4*)(cOn + swz512(r, c16 * 16)) = *((const uint4*)(on + (pr0 + r) * 256) + c16);
    }
    __syncthreads();
    const int lane = tid & 63, w = tid >> 6;
    const int wm = w >> 2, wn = w & 3;
    const int l15 = lane & 15, l4 = lane >> 4;
    const int r0 = wm * 32;
    v4f acc2[2][2] = {};
    for (int hc = 0; hc < 4; ++hc) {
        v4f acch[2][4] = {};
        __builtin_amdgcn_s_setprio(1);
        #pragma unroll
        for (int ks = 0; ks < 8; ++ks) {
            v8bf a[2];
            #pragma unroll
            for (int m = 0; m < 2; ++m)
                a[m] = *(const v8bf*)(cOn + swz512(r0 + m*16 + l15, ks*64 + l4*16));
            #pragma unroll
            for (int nf = 0; nf < 4; ++nf) {
                int h = hc * 256 + wn * 64 + nf * 16 + l15;
                v8bf b = *(const v8bf*)(w1b + (size_t)h * 256 + ks * 32 + l4 * 8);
                #pragma unroll
                for (int m = 0; m < 2; ++m) acch[m][nf] = MFMA(a[m], b, acch[m][nf]);
            }
        }
        __builtin_amdgcn_s_setprio(0);
        __syncthreads();   // previous hc's cH reads done
        #pragma unroll
        for (int m = 0; m < 2; ++m)
            #pragma unroll
            for (int nf = 0; nf < 4; ++nf) {
                int coll = wn * 64 + nf * 16 + l15;
                float b1v = b1[hc * 256 + coll];
                #pragma unroll
                for (int j = 0; j < 4; ++j) {
                    int row = r0 + m*16 + l4*4 + j;
                    float hv = fmaxf(acch[m][nf][j] + b1v, 0.f);
                    *(bf16*)(cH + swz512(row, coll * 2)) = (bf16)hv;
                }
            }
        __syncthreads();
        __builtin_amdgcn_s_setprio(1);
        #pragma unroll
        for (int ks = 0; ks < 8; ++ks) {
            v8bf a[2];
            #pragma unroll
            for (int m = 0; m < 2; ++m)
                a[m] = *(const v8bf*)(cH + swz512(r0 + m*16 + l15, ks*64 + l4*16));
            #pragma unroll
            for (int nf = 0; nf < 2; ++nf) {
                int o = wn * 32 + nf * 16 + l15;
                v8bf b = *(const v8bf*)(w2b + (size_t)o * 1024 + hc * 256 + ks * 32 + l4 * 8);
                #pragma unroll
                for (int m = 0; m < 2; ++m) acc2[m][nf] = MFMA(a[m], b, acc2[m][nf]);
            }
        }
        __builtin_amdgcn_s_setprio(0);
    }
    #pragma unroll
    for (int m = 0; m < 2; ++m)
        #pragma unroll
        for (int nf = 0; nf < 2; ++nf) {
            int o = wn * 32 + nf * 16 + l15;
            float b2v = b2[o];
            #pragma unroll
            for (int j = 0; j < 4; ++j) {
                int row = r0 + m*16 + l4*4 + j;
                out[(size_t)(g0 + row) * 128 + o] = acc2[m][nf][j] + b2v;
            }
        }
}

extern "C" void kernel_launch(void* const* d_in, const int* in_sizes, int n_in,
                              void* d_out, int out_size, void* d_ws, size_t ws_size,
                              hipStream_t stream) {
    const float* x      = (const float*)d_in[0];
    const float* W_in   = (const float*)d_in[1];
    const float* b_in   = (const float*)d_in[2];
    const float* W_f    = (const float*)d_in[3];
    const float* b_f    = (const float*)d_in[4];
    const float* W_g    = (const float*)d_in[5];
    const float* b_g    = (const float*)d_in[6];
    const float* W_r    = (const float*)d_in[7];
    const float* b_r    = (const float*)d_in[8];
    const float* W_s    = (const float*)d_in[9];
    const float* b_s    = (const float*)d_in[10];
    const float* norm_w = (const float*)d_in[11];
    const float* hnw    = (const float*)d_in[12];
    const float* W1     = (const float*)d_in[13];
    const float* b1     = (const float*)d_in[14];
    const float* W2     = (const float*)d_in[15];
    const float* b2     = (const float*)d_in[16];

    char* p = (char*)d_ws;
    uint32* zsb = (uint32*)p;          p += (size_t)BT * 256 * 4;
    bf16* zn_a  = (bf16*)p;            p += (size_t)16 * TPB * 256 * 2;
    bf16* zn_b  = (bf16*)p;            p += (size_t)16 * TPB * 256 * 2;
    bf16* wf0   = (bf16*)p;            p += (size_t)NL * 65536 * 2;
    bf16* wf1   = (bf16*)p;            p += (size_t)NL * 65536 * 2;
    bf16* wg0   = (bf16*)p;            p += (size_t)NL * 65536 * 2;
    bf16* wg1   = (bf16*)p;            p += (size_t)NL * 65536 * 2;
    bf16* wr    = (bf16*)p;            p += (size_t)NL * 65536 * 2;
    bf16* ws    = (bf16*)p;            p += (size_t)NL * 65536 * 2;
    bf16* winb  = (bf16*)p;            p += 65536 * 2;
    bf16* w1b   = (bf16*)p;            p += 262144 * 2;
    bf16* w2b   = (bf16*)p;            p += 131072 * 2;

    zero_pads<<<2048, 256, 0, stream>>>(zn_a, zn_b);
    prep_w2<<<NL * 256, 256, 0, stream>>>(W_f, W_g, wf0, wf1, wg0, wg1);
    prep_w1<<<NL * 256, 256, 0, stream>>>(W_r, W_s, wr, ws);
    prep_misc<<<1792, 256, 0, stream>>>(W_in, W1, W2, winb, w1b, w2b);
    in_conv_kernel<<<BT / 64, 512, 0, stream>>>(x, winb, b_in, norm_w, zsb, zn_a);

    static const int dil[NL] = {1,2,4,8,16,32,64,128,256,512,
                                1,2,4,8,16,32,64,128,256,512};
    for (int i = 0; i < NL; ++i) {
        const bf16* zi = (i & 1) ? zn_b : zn_a;
        bf16* zo_      = (i & 1) ? zn_a : zn_b;
        int mode = (i == NL - 1) ? 2 : 1;
        const float* nw = (i == NL - 1) ? hnw : (norm_w + (size_t)(i + 1) * 256);
        layer_kernel<<<BT / 64, 512, 0, stream>>>(zi, zo_, zsb,
            wf0 + (size_t)i * 65536, wf1 + (size_t)i * 65536,
            wg0 + (size_t)i * 65536, wg1 + (size_t)i * 65536,
            wr + (size_t)i * 65536, ws + (size_t)i * 65536,
            b_f + i * 256, b_g + i * 256, b_r + i * 256, b_s + i * 256,
            nw, dil[i], mode);
    }
    // NL=20 even: last layer wrote zn_a
    head_kernel<<<BT / 64, 512, 0, stream>>>(zn_a, w1b, b1, w2b, b2, (float*)d_out);
}